// Round 1
// baseline (4113.136 us; speedup 1.0000x reference)
//
#include <hip/hip_runtime.h>
#include <hip/hip_bf16.h>
#include <math.h>

#define QLEN 1024
#define MLEN 1024
#define KLEN 2048
#define BSZ 4
#define NH 8
#define DH 64
#define DM 512
#define SCALE 0.125f
#define LN_EPS 1e-5f

// ---------------------------------------------------------------------------
// Projection GEMMs: C[M,N] = A[M,512] @ W[512,N], custom gather + epilogue.
// MODE 0: A=w [4096x512], W=Wq [512x512]  -> qw/qr [b][n][i][d] (+biases)
// MODE 1: A=cat gather [8192x512], W=Wkv [512x1024] -> kh/vh [b][n][pos][d]
// MODE 2: A=r [2048x512], W=Wr [512x512] -> rk [n][j][d]
// ---------------------------------------------------------------------------
template <int MODE>
__global__ __launch_bounds__(256) void proj_gemm(
    const float* __restrict__ A0, const float* __restrict__ A1,
    const float* __restrict__ W,
    const float* __restrict__ bias0, const float* __restrict__ bias1,
    float* __restrict__ O0, float* __restrict__ O1, int N) {
  __shared__ float As[32][33];
  __shared__ float Bs[32][33];
  const int tx = threadIdx.x, ty = threadIdx.y;   // 16x16
  const int tid = ty * 16 + tx;
  const int m0 = blockIdx.x * 32, n0 = blockIdx.y * 32;
  float acc00 = 0.f, acc01 = 0.f, acc10 = 0.f, acc11 = 0.f;
  for (int k0 = 0; k0 < DM; k0 += 32) {
#pragma unroll
    for (int t = 0; t < 4; ++t) {
      int idx = tid + t * 256;
      int rr = idx >> 5, cc = idx & 31;
      int m = m0 + rr;
      float a;
      if (MODE == 1)
        a = (m < QLEN * BSZ) ? A0[(size_t)m * DM + k0 + cc]
                             : A1[(size_t)(m - QLEN * BSZ) * DM + k0 + cc];
      else
        a = A0[(size_t)m * DM + k0 + cc];
      As[rr][cc] = a;
      Bs[rr][cc] = W[(size_t)(k0 + rr) * N + n0 + cc];
    }
    __syncthreads();
#pragma unroll
    for (int k = 0; k < 32; ++k) {
      float a0 = As[ty * 2 + 0][k], a1 = As[ty * 2 + 1][k];
      float b0 = Bs[k][tx * 2 + 0], b1 = Bs[k][tx * 2 + 1];
      acc00 += a0 * b0; acc01 += a0 * b1;
      acc10 += a1 * b0; acc11 += a1 * b1;
    }
    __syncthreads();
  }
  float accs[2][2] = {{acc00, acc01}, {acc10, acc11}};
#pragma unroll
  for (int dr = 0; dr < 2; ++dr) {
#pragma unroll
    for (int dc = 0; dc < 2; ++dc) {
      int mm = m0 + ty * 2 + dr;
      int nn = n0 + tx * 2 + dc;
      float acc = accs[dr][dc];
      if (MODE == 0) {
        int i = mm >> 2, b = mm & 3;
        int n = nn >> 6, d = nn & 63;
        size_t idx = (((size_t)(b * NH + n)) * QLEN + i) * DH + d;
        O0[idx] = acc + bias0[nn];
        O1[idx] = acc + bias1[nn];
      } else if (MODE == 1) {
        int pos = mm >> 2, b = mm & 3;
        if (nn < DM) {
          int n = nn >> 6, d = nn & 63;
          O0[(((size_t)(b * NH + n)) * KLEN + pos) * DH + d] = acc;
        } else {
          int cc2 = nn - DM;
          int n = cc2 >> 6, d = cc2 & 63;
          O1[(((size_t)(b * NH + n)) * KLEN + pos) * DH + d] = acc;
        }
      } else {
        int n = nn >> 6, d = nn & 63;
        O0[((size_t)n * KLEN + mm) * DH + d] = acc;
      }
    }
  }
}

// ---------------------------------------------------------------------------
// Attention: one wave per (query row i, head n, batch b). lane == d (DH==64).
// S[i,j] = SCALE * (qw . K[j]  +  qr . RK[j - i + 1023]),  j in [0, i+MLEN].
// Online softmax; accumulator acc[d] per lane.
// ---------------------------------------------------------------------------
__global__ __launch_bounds__(64) void attn_rowwave(
    const float* __restrict__ qw, const float* __restrict__ qr,
    const float* __restrict__ kh, const float* __restrict__ vh,
    const float* __restrict__ rk, float* __restrict__ av) {
  const int i = blockIdx.x;
  const int n = blockIdx.y;
  const int b = blockIdx.z;
  const int lane = threadIdx.x;
  const int bn = b * NH + n;
  const float* __restrict__ K = kh + (size_t)bn * KLEN * DH;
  const float* __restrict__ V = vh + (size_t)bn * KLEN * DH;
  // R[j*DH + lane] yields rk[n][j + (QLEN-1) - i][lane]
  const float* __restrict__ R = rk + ((size_t)n * KLEN + (QLEN - 1 - i)) * DH;
  const float qwd = qw[((size_t)bn * QLEN + i) * DH + lane];
  const float qrd = qr[((size_t)bn * QLEN + i) * DH + lane];
  const int jmax = i + MLEN;  // inclusive; <= KLEN-1 always
  float m = -INFINITY, l = 0.f, acc = 0.f;
  for (int j = 0; j <= jmax; ++j) {
    float part = qwd * K[(size_t)j * DH + lane] + qrd * R[(size_t)j * DH + lane];
#pragma unroll
    for (int off = 32; off >= 1; off >>= 1) part += __shfl_xor(part, off, 64);
    float s = part * SCALE;
    float mn = fmaxf(m, s);
    float alpha = __expf(m - mn);   // first iter: exp(-inf) = 0
    float pp = __expf(s - mn);
    l = l * alpha + pp;
    acc = acc * alpha + pp * V[(size_t)j * DH + lane];
    m = mn;
  }
  // av layout: [i][b][n*64+d]  (row m = i*BSZ+b of a [4096 x 512] matrix)
  av[((size_t)i * BSZ + b) * DM + n * DH + lane] = acc / l;
}

// ---------------------------------------------------------------------------
// Output: y = av @ Wo; out = LayerNorm(w + y) * g + b. 4 rows per block.
// ---------------------------------------------------------------------------
__global__ __launch_bounds__(256) void out_ln(
    const float* __restrict__ av, const float* __restrict__ Wo,
    const float* __restrict__ wres, const float* __restrict__ g,
    const float* __restrict__ bb, float* __restrict__ out) {
  __shared__ float avs[4][DM];
  __shared__ float red1[256];
  __shared__ float red2[256];
  const int tid = threadIdx.x;
  const int m0 = blockIdx.x * 4;
  for (int idx = tid; idx < 4 * DM; idx += 256)
    avs[idx >> 9][idx & 511] = av[(size_t)m0 * DM + idx];
  __syncthreads();
  float y0[4] = {0.f, 0.f, 0.f, 0.f};
  float y1[4] = {0.f, 0.f, 0.f, 0.f};
  const int c0 = tid, c1 = tid + 256;
  for (int k = 0; k < DM; ++k) {
    float w0 = Wo[(size_t)k * DM + c0];
    float w1 = Wo[(size_t)k * DM + c1];
#pragma unroll
    for (int r2 = 0; r2 < 4; ++r2) {
      float a = avs[r2][k];
      y0[r2] += a * w0;
      y1[r2] += a * w1;
    }
  }
  for (int r2 = 0; r2 < 4; ++r2) {
    size_t m = m0 + r2;
    float x0 = wres[m * DM + c0] + y0[r2];
    float x1 = wres[m * DM + c1] + y1[r2];
    red1[tid] = x0 + x1;
    red2[tid] = x0 * x0 + x1 * x1;
    __syncthreads();
    for (int st = 128; st >= 1; st >>= 1) {
      if (tid < st) {
        red1[tid] += red1[tid + st];
        red2[tid] += red2[tid + st];
      }
      __syncthreads();
    }
    float mu = red1[0] * (1.f / DM);
    float var = red2[0] * (1.f / DM) - mu * mu;
    float rstd = rsqrtf(var + LN_EPS);
    out[m * DM + c0] = (x0 - mu) * rstd * g[c0] + bb[c0];
    out[m * DM + c1] = (x1 - mu) * rstd * g[c1] + bb[c1];
    __syncthreads();
  }
}

extern "C" void kernel_launch(void* const* d_in, const int* in_sizes, int n_in,
                              void* d_out, int out_size, void* d_ws, size_t ws_size,
                              hipStream_t stream) {
  const float* w    = (const float*)d_in[0];
  const float* r    = (const float*)d_in[1];
  const float* rwb  = (const float*)d_in[2];
  const float* rrb  = (const float*)d_in[3];
  const float* mems = (const float*)d_in[4];
  const float* Wq   = (const float*)d_in[5];
  const float* Wkv  = (const float*)d_in[6];
  const float* Wr   = (const float*)d_in[7];
  const float* Wo   = (const float*)d_in[8];
  const float* ln_g = (const float*)d_in[9];
  const float* ln_b = (const float*)d_in[10];
  // d_in[11] (attn_mask) is deterministic (j > i + MLEN): computed analytically.
  float* out = (float*)d_out;

  float* p = (float*)d_ws;
  float* qw = p; p += (size_t)BSZ * NH * QLEN * DH;   //  8 MB
  float* qr = p; p += (size_t)BSZ * NH * QLEN * DH;   //  8 MB
  float* kh = p; p += (size_t)BSZ * NH * KLEN * DH;   // 16 MB
  float* vh = p; p += (size_t)BSZ * NH * KLEN * DH;   // 16 MB
  float* rk = p; p += (size_t)NH * KLEN * DH;         //  4 MB
  float* av = p; p += (size_t)QLEN * BSZ * DM;        //  8 MB

  dim3 blk(16, 16);
  proj_gemm<0><<<dim3(128, 16), blk, 0, stream>>>(w, nullptr, Wq, rwb, rrb, qw, qr, DM);
  proj_gemm<1><<<dim3(256, 32), blk, 0, stream>>>(mems, w, Wkv, nullptr, nullptr, kh, vh, 2 * DM);
  proj_gemm<2><<<dim3(64, 16), blk, 0, stream>>>(r, nullptr, Wr, nullptr, nullptr, rk, nullptr, DM);
  attn_rowwave<<<dim3(QLEN, NH, BSZ), dim3(64), 0, stream>>>(qw, qr, kh, vh, rk, av);
  out_ln<<<dim3(QLEN * BSZ / 4), dim3(256), 0, stream>>>(av, Wo, w, ln_g, ln_b, out);
}

// Round 3
// 736.036 us; speedup vs baseline: 5.5882x; 5.5882x over previous
//
#include <hip/hip_runtime.h>
#include <hip/hip_bf16.h>
#include <math.h>

#define QLEN 1024
#define MLEN 1024
#define KLEN 2048
#define BSZ 4
#define NH 8
#define DH 64
#define DM 512
#define SCALE 0.125f
#define LN_EPS 1e-5f

typedef __attribute__((ext_vector_type(8))) short short8;   // 8 bf16 (4 VGPRs)
typedef __attribute__((ext_vector_type(4))) float float4_;  // MFMA C/D

__device__ inline ushort to_bf16(float x) {
  __hip_bfloat16 h = __float2bfloat16(x);
  return *reinterpret_cast<ushort*>(&h);
}

// ---------------------------------------------------------------------------
// Projection GEMMs (f32 compute, bf16 outputs in MFMA layouts).
// MODE 0: w[4096x512] @ Wq -> qw/qr bf16 [bn][i][d] (+r_w_bias / +r_r_bias)
// MODE 1: cat[8192x512] @ Wkv -> kh bf16 [bn][j][d], vt bf16 [bn][d][j]
// MODE 2: r[2048x512] @ Wr -> rk bf16 [n][t][d]
// ---------------------------------------------------------------------------
template <int MODE>
__global__ __launch_bounds__(256) void proj_gemm(
    const float* __restrict__ A0, const float* __restrict__ A1,
    const float* __restrict__ W,
    const float* __restrict__ bias0, const float* __restrict__ bias1,
    ushort* __restrict__ O0, ushort* __restrict__ O1, int N) {
  __shared__ float As[32][33];
  __shared__ float Bs[32][33];
  __shared__ ushort Vs[4][32][8];  // [b][d_off][pos_off] staging for vt
  const int tx = threadIdx.x, ty = threadIdx.y;   // 16x16
  const int tid = ty * 16 + tx;
  const int m0 = blockIdx.x * 32, n0 = blockIdx.y * 32;
  float acc00 = 0.f, acc01 = 0.f, acc10 = 0.f, acc11 = 0.f;
  for (int k0 = 0; k0 < DM; k0 += 32) {
#pragma unroll
    for (int t = 0; t < 4; ++t) {
      int idx = tid + t * 256;
      int rr = idx >> 5, cc = idx & 31;
      int m = m0 + rr;
      float a;
      if (MODE == 1)
        a = (m < QLEN * BSZ) ? A0[(size_t)m * DM + k0 + cc]
                             : A1[(size_t)(m - QLEN * BSZ) * DM + k0 + cc];
      else
        a = A0[(size_t)m * DM + k0 + cc];
      As[rr][cc] = a;
      Bs[rr][cc] = W[(size_t)(k0 + rr) * N + n0 + cc];
    }
    __syncthreads();
#pragma unroll
    for (int k = 0; k < 32; ++k) {
      float a0 = As[ty * 2 + 0][k], a1 = As[ty * 2 + 1][k];
      float b0 = Bs[k][tx * 2 + 0], b1 = Bs[k][tx * 2 + 1];
      acc00 += a0 * b0; acc01 += a0 * b1;
      acc10 += a1 * b0; acc11 += a1 * b1;
    }
    __syncthreads();
  }
  float accs[2][2] = {{acc00, acc01}, {acc10, acc11}};
  if (MODE == 1 && n0 >= DM) {
    // V half -> vt [bn][d][KLEN] via LDS staging (coalesced 16B stores)
    const int cc2_0 = n0 - DM;
    const int n = cc2_0 >> 6, d0 = cc2_0 & 63;
    const int pos0 = m0 >> 2;
#pragma unroll
    for (int dr = 0; dr < 2; ++dr)
#pragma unroll
      for (int dc = 0; dc < 2; ++dc) {
        int mr = ty * 2 + dr;            // 0..31
        int b = mr & 3, pos_off = mr >> 2;
        int d_off = tx * 2 + dc;         // 0..31
        Vs[b][d_off][pos_off] = to_bf16(accs[dr][dc]);
      }
    __syncthreads();
    if (tid < 128) {
      int b = tid >> 5, dd = tid & 31;
      int bn = b * NH + n;
      ushort* dst = O1 + ((size_t)bn * DH + d0 + dd) * KLEN + pos0;
      *reinterpret_cast<uint4*>(dst) = *reinterpret_cast<uint4*>(&Vs[b][dd][0]);
    }
    return;
  }
#pragma unroll
  for (int dr = 0; dr < 2; ++dr) {
#pragma unroll
    for (int dc = 0; dc < 2; ++dc) {
      int mm = m0 + ty * 2 + dr;
      int nn = n0 + tx * 2 + dc;
      float acc = accs[dr][dc];
      if (MODE == 0) {
        int i = mm >> 2, b = mm & 3;
        int n = nn >> 6, d = nn & 63;
        size_t idx = (((size_t)(b * NH + n)) * QLEN + i) * DH + d;
        O0[idx] = to_bf16(acc + bias0[nn]);
        O1[idx] = to_bf16(acc + bias1[nn]);
      } else if (MODE == 1) {
        // K half only (V handled above)
        int pos = mm >> 2, b = mm & 3;
        int n = nn >> 6, d = nn & 63;
        O0[(((size_t)(b * NH + n)) * KLEN + pos) * DH + d] = to_bf16(acc);
      } else {
        int n = nn >> 6, d = nn & 63;
        O0[((size_t)n * KLEN + mm) * DH + d] = to_bf16(acc);
      }
    }
  }
}

// ---------------------------------------------------------------------------
// MFMA flash attention. One wave per (16-row Q tile, head n, batch b).
// S[i,j] = SCALE*(qw_i.K_j + D[i, j-i+1023]),  D[i,t] = qr_i . rk[t]
// 32 keys per iteration: AC (2 C-tiles), D band of 48 (3 C-tiles -> LDS,
// rel-shift gather), online softmax (exp2 domain), P -> LDS -> PV MFMA.
// ---------------------------------------------------------------------------
__global__ __launch_bounds__(64) void attn_mfma(
    const ushort* __restrict__ qw, const ushort* __restrict__ qr,
    const ushort* __restrict__ kh, const ushort* __restrict__ vt,
    const ushort* __restrict__ rk, float* __restrict__ av) {
  const int i0 = (gridDim.x - 1 - blockIdx.x) * 16;  // longest blocks first
  const int n = blockIdx.y, b = blockIdx.z;
  const int bn = b * NH + n;
  const int lane = threadIdx.x;
  const int l16 = lane & 15, quad = lane >> 4;

  __shared__ float Dlds[16][49];
  __shared__ ushort Plds[16][32];

  const ushort* __restrict__ Kp = kh + (size_t)bn * KLEN * DH;
  const ushort* __restrict__ Vt = vt + (size_t)bn * DH * KLEN;
  const ushort* __restrict__ Rk = rk + (size_t)n * KLEN * DH;

  // A-layout Q fragments: A[m=l16][k=quad*8+jj], halves k in [0,32),[32,64)
  short8 aqw0, aqw1, aqr0, aqr1;
  {
    const ushort* qwp = qw + (((size_t)bn * QLEN) + i0 + l16) * DH + quad * 8;
    const ushort* qrp = qr + (((size_t)bn * QLEN) + i0 + l16) * DH + quad * 8;
    aqw0 = *(const short8*)(qwp);
    aqw1 = *(const short8*)(qwp + 32);
    aqr0 = *(const short8*)(qrp);
    aqr1 = *(const short8*)(qrp + 32);
  }

  float4_ O[4];
#pragma unroll
  for (int t = 0; t < 4; ++t) O[t] = float4_{0.f, 0.f, 0.f, 0.f};
  float mrow[4] = {-INFINITY, -INFINITY, -INFINITY, -INFINITY};
  float lrow[4] = {0.f, 0.f, 0.f, 0.f};
  const float SL2E = SCALE * 1.44269504088896f;  // scores in exp2 domain

  const int jmax = i0 + 15 + MLEN;  // inclusive last key for any row in tile
  for (int j0 = 0; j0 <= jmax; j0 += 32) {
    const int tb = j0 - i0 + 1008;  // t_base (>= 0 always)
    // ---- D band: 3 tiles of 16 -> Dlds ----
#pragma unroll
    for (int tt = 0; tt < 3; ++tt) {
      int t = tb + tt * 16 + l16;
      t = (t > KLEN - 1) ? (KLEN - 1) : t;  // clamp (masked region anyway)
      const ushort* rp = Rk + (size_t)t * DH + quad * 8;
      short8 b0 = *(const short8*)rp;
      short8 b1 = *(const short8*)(rp + 32);
      float4_ d = {0.f, 0.f, 0.f, 0.f};
      d = __builtin_amdgcn_mfma_f32_16x16x32_bf16(aqr0, b0, d, 0, 0, 0);
      d = __builtin_amdgcn_mfma_f32_16x16x32_bf16(aqr1, b1, d, 0, 0, 0);
#pragma unroll
      for (int rg = 0; rg < 4; ++rg)
        Dlds[quad * 4 + rg][tt * 16 + l16] = d[rg];
    }
    // ---- AC: 2 tiles of 16 keys ----
    float4_ ac[2];
#pragma unroll
    for (int half = 0; half < 2; ++half) {
      int j = j0 + half * 16 + l16;
      int jc = (j > KLEN - 1) ? (KLEN - 1) : j;
      const ushort* kp = Kp + (size_t)jc * DH + quad * 8;
      short8 b0 = *(const short8*)kp;
      short8 b1 = *(const short8*)(kp + 32);
      float4_ c = {0.f, 0.f, 0.f, 0.f};
      c = __builtin_amdgcn_mfma_f32_16x16x32_bf16(aqw0, b0, c, 0, 0, 0);
      c = __builtin_amdgcn_mfma_f32_16x16x32_bf16(aqw1, b1, c, 0, 0, 0);
      ac[half] = c;
    }
    __syncthreads();  // Dlds ready
    // ---- scores (exp2 domain) + rel-shift gather + mask ----
    float s[2][4];
#pragma unroll
    for (int half = 0; half < 2; ++half) {
#pragma unroll
      for (int rg = 0; rg < 4; ++rg) {
        int row = quad * 4 + rg;
        int jloc = half * 16 + l16;
        int j = j0 + jloc;
        float bd = Dlds[row][jloc - row + 15];
        float sv = (ac[half][rg] + bd) * SL2E;
        s[half][rg] = (j > i0 + row + MLEN) ? -INFINITY : sv;
      }
    }
    // ---- online softmax (rows live in 16-lane quads) ----
#pragma unroll
    for (int rg = 0; rg < 4; ++rg) {
      float mx = fmaxf(s[0][rg], s[1][rg]);
#pragma unroll
      for (int off = 1; off <= 8; off <<= 1) mx = fmaxf(mx, __shfl_xor(mx, off, 64));
      float mn = fmaxf(mrow[rg], mx);
      float alpha = __builtin_amdgcn_exp2f(mrow[rg] - mn);  // first iter: exp2(-inf)=0
      float p0 = __builtin_amdgcn_exp2f(s[0][rg] - mn);
      float p1 = __builtin_amdgcn_exp2f(s[1][rg] - mn);
      float ls = p0 + p1;
#pragma unroll
      for (int off = 1; off <= 8; off <<= 1) ls += __shfl_xor(ls, off, 64);
      lrow[rg] = lrow[rg] * alpha + ls;
      mrow[rg] = mn;
#pragma unroll
      for (int t = 0; t < 4; ++t) O[t][rg] *= alpha;
      int row = quad * 4 + rg;
      Plds[row][l16] = to_bf16(p0);
      Plds[row][16 + l16] = to_bf16(p1);
    }
    __syncthreads();  // Plds ready
    // ---- PV: P(16x32) @ V(32x64) -> 4 output tiles ----
    short8 pfrag = *(const short8*)&Plds[l16][quad * 8];
#pragma unroll
    for (int t = 0; t < 4; ++t) {
      const ushort* vp = Vt + (size_t)(t * 16 + l16) * KLEN + j0 + quad * 8;
      short8 vfrag = *(const short8*)vp;  // padded alloc covers tail overread
      O[t] = __builtin_amdgcn_mfma_f32_16x16x32_bf16(pfrag, vfrag, O[t], 0, 0, 0);
    }
    __syncthreads();  // protect Dlds/Plds rewrite next iter
  }
  // ---- epilogue: O / l -> av[i*BSZ+b][n*64+d] ----
  float rl[4];
#pragma unroll
  for (int rg = 0; rg < 4; ++rg) rl[rg] = 1.f / lrow[rg];
#pragma unroll
  for (int t = 0; t < 4; ++t) {
#pragma unroll
    for (int rg = 0; rg < 4; ++rg) {
      int row = quad * 4 + rg;
      int d = t * 16 + l16;
      av[((size_t)(i0 + row) * BSZ + b) * DM + n * DH + d] = O[t][rg] * rl[rg];
    }
  }
}

// ---------------------------------------------------------------------------
// Output: y = av @ Wo; out = LayerNorm(w + y) * g + b. 4 rows per block.
// ---------------------------------------------------------------------------
__global__ __launch_bounds__(256) void out_ln(
    const float* __restrict__ av, const float* __restrict__ Wo,
    const float* __restrict__ wres, const float* __restrict__ g,
    const float* __restrict__ bb, float* __restrict__ out) {
  __shared__ float avs[4][DM];
  __shared__ float red1[256];
  __shared__ float red2[256];
  const int tid = threadIdx.x;
  const int m0 = blockIdx.x * 4;
  for (int idx = tid; idx < 4 * DM; idx += 256)
    avs[idx >> 9][idx & 511] = av[(size_t)m0 * DM + idx];
  __syncthreads();
  float y0[4] = {0.f, 0.f, 0.f, 0.f};
  float y1[4] = {0.f, 0.f, 0.f, 0.f};
  const int c0 = tid, c1 = tid + 256;
  for (int k = 0; k < DM; ++k) {
    float w0 = Wo[(size_t)k * DM + c0];
    float w1 = Wo[(size_t)k * DM + c1];
#pragma unroll
    for (int r2 = 0; r2 < 4; ++r2) {
      float a = avs[r2][k];
      y0[r2] += a * w0;
      y1[r2] += a * w1;
    }
  }
  for (int r2 = 0; r2 < 4; ++r2) {
    size_t m = m0 + r2;
    float x0 = wres[m * DM + c0] + y0[r2];
    float x1 = wres[m * DM + c1] + y1[r2];
    red1[tid] = x0 + x1;
    red2[tid] = x0 * x0 + x1 * x1;
    __syncthreads();
    for (int st = 128; st >= 1; st >>= 1) {
      if (tid < st) {
        red1[tid] += red1[tid + st];
        red2[tid] += red2[tid + st];
      }
      __syncthreads();
    }
    float mu = red1[0] * (1.f / DM);
    float var = red2[0] * (1.f / DM) - mu * mu;
    float rstd = rsqrtf(var + LN_EPS);
    out[m * DM + c0] = (x0 - mu) * rstd * g[c0] + bb[c0];
    out[m * DM + c1] = (x1 - mu) * rstd * g[c1] + bb[c1];
    __syncthreads();
  }
}

extern "C" void kernel_launch(void* const* d_in, const int* in_sizes, int n_in,
                              void* d_out, int out_size, void* d_ws, size_t ws_size,
                              hipStream_t stream) {
  const float* w    = (const float*)d_in[0];
  const float* r    = (const float*)d_in[1];
  const float* rwb  = (const float*)d_in[2];
  const float* rrb  = (const float*)d_in[3];
  const float* mems = (const float*)d_in[4];
  const float* Wq   = (const float*)d_in[5];
  const float* Wkv  = (const float*)d_in[6];
  const float* Wr   = (const float*)d_in[7];
  const float* Wo   = (const float*)d_in[8];
  const float* ln_g = (const float*)d_in[9];
  const float* ln_b = (const float*)d_in[10];
  float* out = (float*)d_out;

  char* p = (char*)d_ws;
  auto alloc = [&](size_t bytes) {
    char* q = p;
    p += (bytes + 255) & ~(size_t)255;
    return q;
  };
  ushort* qw = (ushort*)alloc((size_t)BSZ * NH * QLEN * DH * 2);
  ushort* qr = (ushort*)alloc((size_t)BSZ * NH * QLEN * DH * 2);
  ushort* kh = (ushort*)alloc((size_t)BSZ * NH * KLEN * DH * 2);
  ushort* vt = (ushort*)alloc((size_t)BSZ * NH * DH * KLEN * 2 + 4096);  // pad: PV tail frag overread
  ushort* rk = (ushort*)alloc((size_t)NH * KLEN * DH * 2);
  float*  av = (float*)alloc((size_t)QLEN * BSZ * DM * 4);

  dim3 blk(16, 16);
  proj_gemm<0><<<dim3(128, 16), blk, 0, stream>>>(w, nullptr, Wq, rwb, rrb, qw, qr, DM);
  proj_gemm<1><<<dim3(256, 32), blk, 0, stream>>>(mems, w, Wkv, nullptr, nullptr, kh, vt, 2 * DM);
  proj_gemm<2><<<dim3(64, 16), blk, 0, stream>>>(r, nullptr, Wr, nullptr, nullptr, rk, nullptr, DM);
  attn_mfma<<<dim3(QLEN / 16, NH, BSZ), dim3(64), 0, stream>>>(qw, qr, kh, vt, rk, av);
  out_ln<<<dim3(QLEN * BSZ / 4), dim3(256), 0, stream>>>(av, Wo, w, ln_g, ln_b, out);
}

// Round 5
// 439.906 us; speedup vs baseline: 9.3500x; 1.6732x over previous
//
#include <hip/hip_runtime.h>
#include <hip/hip_bf16.h>
#include <math.h>

#define QLEN 1024
#define MLEN 1024
#define KLEN 2048
#define BSZ 4
#define NH 8
#define DH 64
#define DM 512
#define SCALE 0.125f
#define LN_EPS 1e-5f

typedef __attribute__((ext_vector_type(8))) short short8;   // 8 bf16 (4 VGPRs)
typedef __attribute__((ext_vector_type(4))) float float4_;  // MFMA C/D

__device__ inline ushort to_bf16(float x) {
  __hip_bfloat16 h = __float2bfloat16(x);
  return *reinterpret_cast<ushort*>(&h);
}

// ---------------------------------------------------------------------------
// f32 -> bf16 flat convert (4 elements/thread).
// ---------------------------------------------------------------------------
__global__ __launch_bounds__(256) void cvt_bf16(const float* __restrict__ src,
                                                ushort* __restrict__ dst, int n) {
  int i = (blockIdx.x * 256 + threadIdx.x) * 4;
  if (i >= n) return;
  float4 v = *reinterpret_cast<const float4*>(src + i);
  ushort4 o;
  o.x = to_bf16(v.x); o.y = to_bf16(v.y); o.z = to_bf16(v.z); o.w = to_bf16(v.w);
  *reinterpret_cast<ushort4*>(dst + i) = o;
}

// ---------------------------------------------------------------------------
// Weight transpose+convert: W[512][N] f32 -> WT[N][512] bf16. 32x32 LDS tiles.
// ---------------------------------------------------------------------------
__global__ __launch_bounds__(256) void wtrans(const float* __restrict__ W,
                                              ushort* __restrict__ WT, int N) {
  __shared__ ushort tile[32][33];
  const int k0 = blockIdx.x * 32, n0 = blockIdx.y * 32;
  const int tid = threadIdx.x;
#pragma unroll
  for (int it = 0; it < 4; ++it) {
    int idx = tid + it * 256;
    int r = idx >> 5, c = idx & 31;
    tile[r][c] = to_bf16(W[(size_t)(k0 + r) * N + n0 + c]);
  }
  __syncthreads();
#pragma unroll
  for (int it = 0; it < 4; ++it) {
    int idx = tid + it * 256;
    int r = idx >> 5, c = idx & 31;
    WT[(size_t)(n0 + r) * DM + k0 + c] = tile[c][r];
  }
}

// ---------------------------------------------------------------------------
// V transpose: vrow[bn][j][d] -> vt[bn][d][j]. 64x64 LDS tiles.
// ---------------------------------------------------------------------------
__global__ __launch_bounds__(256) void vtrans(const ushort* __restrict__ vrow,
                                              ushort* __restrict__ vt) {
  __shared__ ushort t[64][65];
  const int j0 = blockIdx.x * 64;
  const int bn = blockIdx.y;
  const int tid = threadIdx.x;
  const ushort* src = vrow + (size_t)bn * KLEN * DH;
  ushort* dst = vt + (size_t)bn * DH * KLEN;
#pragma unroll
  for (int it = 0; it < 16; ++it) {
    int idx = tid + it * 256;
    int r = idx >> 6, c = idx & 63;
    t[r][c] = src[(size_t)(j0 + r) * DH + c];
  }
  __syncthreads();
#pragma unroll
  for (int it = 0; it < 16; ++it) {
    int idx = tid + it * 256;
    int d = idx >> 6, jj = idx & 63;
    dst[(size_t)d * KLEN + j0 + jj] = t[jj][d];
  }
}

// ---------------------------------------------------------------------------
// MFMA projection GEMM. C[M,N] = A[M,512] @ W[512,N] with WT[N][512] bf16.
// Block tile 128x128, 4 waves (2x2) x 64x64 wave tile, BK=32, 16x16x32 bf16.
// Staging: thread t covers row t>>1, ushorts [(t&1)*16, (t&1)*16+16) -- the
// FULL 64B row between the two threads (round-4 bug: only half was written).
// ---------------------------------------------------------------------------
template <int MODE>
__global__ __launch_bounds__(256) void mfma_proj(
    const ushort* __restrict__ A0, const ushort* __restrict__ A1,
    const ushort* __restrict__ BT,
    const float* __restrict__ bias0, const float* __restrict__ bias1,
    ushort* __restrict__ O0, ushort* __restrict__ O1) {
  __shared__ ushort As[128 * 32];
  __shared__ ushort Bs[128 * 32];
  const int tid = threadIdx.x;
  const int m0 = blockIdx.x * 128, n0 = blockIdx.y * 128;
  const int wv = tid >> 6, lane = tid & 63;
  const int wm = wv >> 1, wn = wv & 1;
  const int l16 = lane & 15, quad = lane >> 4;

  const int arow = tid >> 1;            // 0..127
  const int acol = (tid & 1) * 16;      // 0 or 16 (ushort index)
  const ushort* asrc;
  {
    int m = m0 + arow;
    if (MODE == 1)
      asrc = (m < QLEN * BSZ) ? A0 + (size_t)m * DM : A1 + (size_t)(m - QLEN * BSZ) * DM;
    else
      asrc = A0 + (size_t)m * DM;
    asrc += acol;
  }
  const ushort* bsrc = BT + (size_t)(n0 + arow) * DM + acol;

  float4_ acc[4][4];
#pragma unroll
  for (int a = 0; a < 4; ++a)
#pragma unroll
    for (int b = 0; b < 4; ++b) acc[a][b] = float4_{0.f, 0.f, 0.f, 0.f};

  for (int k0 = 0; k0 < DM; k0 += 32) {
    *reinterpret_cast<uint4*>(&As[arow * 32 + acol]) =
        *reinterpret_cast<const uint4*>(asrc + k0);
    *reinterpret_cast<uint4*>(&As[arow * 32 + acol + 8]) =
        *reinterpret_cast<const uint4*>(asrc + k0 + 8);
    *reinterpret_cast<uint4*>(&Bs[arow * 32 + acol]) =
        *reinterpret_cast<const uint4*>(bsrc + k0);
    *reinterpret_cast<uint4*>(&Bs[arow * 32 + acol + 8]) =
        *reinterpret_cast<const uint4*>(bsrc + k0 + 8);
    __syncthreads();
    short8 af[4], bf[4];
#pragma unroll
    for (int f = 0; f < 4; ++f) {
      af[f] = *reinterpret_cast<const short8*>(&As[(wm * 64 + f * 16 + l16) * 32 + quad * 8]);
      bf[f] = *reinterpret_cast<const short8*>(&Bs[(wn * 64 + f * 16 + l16) * 32 + quad * 8]);
    }
#pragma unroll
    for (int fm = 0; fm < 4; ++fm)
#pragma unroll
      for (int fn = 0; fn < 4; ++fn)
        acc[fm][fn] = __builtin_amdgcn_mfma_f32_16x16x32_bf16(af[fm], bf[fn], acc[fm][fn], 0, 0, 0);
    __syncthreads();
  }

#pragma unroll
  for (int fm = 0; fm < 4; ++fm) {
#pragma unroll
    for (int fn = 0; fn < 4; ++fn) {
#pragma unroll
      for (int reg = 0; reg < 4; ++reg) {
        int mm = m0 + wm * 64 + fm * 16 + quad * 4 + reg;
        int nn = n0 + wn * 64 + fn * 16 + l16;
        float v = acc[fm][fn][reg];
        if (MODE == 0) {
          int i = mm >> 2, b = mm & 3;
          int n = nn >> 6, d = nn & 63;
          size_t idx = (((size_t)(b * NH + n)) * QLEN + i) * DH + d;
          O0[idx] = to_bf16(v + bias0[nn]);
          O1[idx] = to_bf16(v + bias1[nn]);
        } else if (MODE == 1) {
          int pos = mm >> 2, b = mm & 3;
          int nn2 = nn & 511;
          int n = nn2 >> 6, d = nn2 & 63;
          size_t idx = (((size_t)(b * NH + n)) * KLEN + pos) * DH + d;
          if (nn < DM) O0[idx] = to_bf16(v);
          else         O1[idx] = to_bf16(v);
        } else {
          int n = nn >> 6, d = nn & 63;
          O0[((size_t)n * KLEN + mm) * DH + d] = to_bf16(v);
        }
      }
    }
  }
}

// ---------------------------------------------------------------------------
// MFMA flash attention. One wave per (16-row Q tile, head n, batch b).
// S[i,j] = SCALE*(qw_i.K_j + D[i, j-i+1023]),  D[i,t] = qr_i . rk[t]
// ---------------------------------------------------------------------------
__global__ __launch_bounds__(64) void attn_mfma(
    const ushort* __restrict__ qw, const ushort* __restrict__ qr,
    const ushort* __restrict__ kh, const ushort* __restrict__ vt,
    const ushort* __restrict__ rk, float* __restrict__ av) {
  const int i0 = (gridDim.x - 1 - blockIdx.x) * 16;  // longest blocks first
  const int n = blockIdx.y, b = blockIdx.z;
  const int bn = b * NH + n;
  const int lane = threadIdx.x;
  const int l16 = lane & 15, quad = lane >> 4;

  __shared__ float Dlds[16][49];
  __shared__ ushort Plds[16][32];

  const ushort* __restrict__ Kp = kh + (size_t)bn * KLEN * DH;
  const ushort* __restrict__ Vt = vt + (size_t)bn * DH * KLEN;
  const ushort* __restrict__ Rk = rk + (size_t)n * KLEN * DH;

  short8 aqw0, aqw1, aqr0, aqr1;
  {
    const ushort* qwp = qw + (((size_t)bn * QLEN) + i0 + l16) * DH + quad * 8;
    const ushort* qrp = qr + (((size_t)bn * QLEN) + i0 + l16) * DH + quad * 8;
    aqw0 = *(const short8*)(qwp);
    aqw1 = *(const short8*)(qwp + 32);
    aqr0 = *(const short8*)(qrp);
    aqr1 = *(const short8*)(qrp + 32);
  }

  float4_ O[4];
#pragma unroll
  for (int t = 0; t < 4; ++t) O[t] = float4_{0.f, 0.f, 0.f, 0.f};
  float mrow[4] = {-INFINITY, -INFINITY, -INFINITY, -INFINITY};
  float lrow[4] = {0.f, 0.f, 0.f, 0.f};
  const float SL2E = SCALE * 1.44269504088896f;  // scores in exp2 domain

  const int jmax = i0 + 15 + MLEN;
  for (int j0 = 0; j0 <= jmax; j0 += 32) {
    const int tb = j0 - i0 + 1008;
#pragma unroll
    for (int tt = 0; tt < 3; ++tt) {
      int t = tb + tt * 16 + l16;
      t = (t > KLEN - 1) ? (KLEN - 1) : t;
      const ushort* rp = Rk + (size_t)t * DH + quad * 8;
      short8 b0 = *(const short8*)rp;
      short8 b1 = *(const short8*)(rp + 32);
      float4_ d = {0.f, 0.f, 0.f, 0.f};
      d = __builtin_amdgcn_mfma_f32_16x16x32_bf16(aqr0, b0, d, 0, 0, 0);
      d = __builtin_amdgcn_mfma_f32_16x16x32_bf16(aqr1, b1, d, 0, 0, 0);
#pragma unroll
      for (int rg = 0; rg < 4; ++rg)
        Dlds[quad * 4 + rg][tt * 16 + l16] = d[rg];
    }
    float4_ ac[2];
#pragma unroll
    for (int half = 0; half < 2; ++half) {
      int j = j0 + half * 16 + l16;
      int jc = (j > KLEN - 1) ? (KLEN - 1) : j;
      const ushort* kp = Kp + (size_t)jc * DH + quad * 8;
      short8 b0 = *(const short8*)kp;
      short8 b1 = *(const short8*)(kp + 32);
      float4_ c = {0.f, 0.f, 0.f, 0.f};
      c = __builtin_amdgcn_mfma_f32_16x16x32_bf16(aqw0, b0, c, 0, 0, 0);
      c = __builtin_amdgcn_mfma_f32_16x16x32_bf16(aqw1, b1, c, 0, 0, 0);
      ac[half] = c;
    }
    __syncthreads();
    float s[2][4];
#pragma unroll
    for (int half = 0; half < 2; ++half) {
#pragma unroll
      for (int rg = 0; rg < 4; ++rg) {
        int row = quad * 4 + rg;
        int jloc = half * 16 + l16;
        int j = j0 + jloc;
        float bd = Dlds[row][jloc - row + 15];
        float sv = (ac[half][rg] + bd) * SL2E;
        s[half][rg] = (j > i0 + row + MLEN) ? -INFINITY : sv;
      }
    }
#pragma unroll
    for (int rg = 0; rg < 4; ++rg) {
      float mx = fmaxf(s[0][rg], s[1][rg]);
#pragma unroll
      for (int off = 1; off <= 8; off <<= 1) mx = fmaxf(mx, __shfl_xor(mx, off, 64));
      float mn = fmaxf(mrow[rg], mx);
      float alpha = __builtin_amdgcn_exp2f(mrow[rg] - mn);
      float p0 = __builtin_amdgcn_exp2f(s[0][rg] - mn);
      float p1 = __builtin_amdgcn_exp2f(s[1][rg] - mn);
      float ls = p0 + p1;
#pragma unroll
      for (int off = 1; off <= 8; off <<= 1) ls += __shfl_xor(ls, off, 64);
      lrow[rg] = lrow[rg] * alpha + ls;
      mrow[rg] = mn;
#pragma unroll
      for (int t = 0; t < 4; ++t) O[t][rg] *= alpha;
      int row = quad * 4 + rg;
      Plds[row][l16] = to_bf16(p0);
      Plds[row][16 + l16] = to_bf16(p1);
    }
    __syncthreads();
    short8 pfrag = *(const short8*)&Plds[l16][quad * 8];
#pragma unroll
    for (int t = 0; t < 4; ++t) {
      const ushort* vp = Vt + (size_t)(t * 16 + l16) * KLEN + j0 + quad * 8;
      short8 vfrag = *(const short8*)vp;
      O[t] = __builtin_amdgcn_mfma_f32_16x16x32_bf16(pfrag, vfrag, O[t], 0, 0, 0);
    }
    __syncthreads();
  }
  float rl[4];
#pragma unroll
  for (int rg = 0; rg < 4; ++rg) rl[rg] = 1.f / lrow[rg];
#pragma unroll
  for (int t = 0; t < 4; ++t) {
#pragma unroll
    for (int rg = 0; rg < 4; ++rg) {
      int row = quad * 4 + rg;
      int d = t * 16 + l16;
      av[((size_t)(i0 + row) * BSZ + b) * DM + n * DH + d] = O[t][rg] * rl[rg];
    }
  }
}

// ---------------------------------------------------------------------------
// Output: y = av @ Wo; out = LayerNorm(w + y) * g + b. 4 rows per block.
// ---------------------------------------------------------------------------
__global__ __launch_bounds__(256) void out_ln(
    const float* __restrict__ av, const float* __restrict__ Wo,
    const float* __restrict__ wres, const float* __restrict__ g,
    const float* __restrict__ bb, float* __restrict__ out) {
  __shared__ float avs[4][DM];
  __shared__ float red1[256];
  __shared__ float red2[256];
  const int tid = threadIdx.x;
  const int m0 = blockIdx.x * 4;
  for (int idx = tid; idx < 4 * DM; idx += 256)
    avs[idx >> 9][idx & 511] = av[(size_t)m0 * DM + idx];
  __syncthreads();
  float y0[4] = {0.f, 0.f, 0.f, 0.f};
  float y1[4] = {0.f, 0.f, 0.f, 0.f};
  const int c0 = tid, c1 = tid + 256;
  for (int k = 0; k < DM; ++k) {
    float w0 = Wo[(size_t)k * DM + c0];
    float w1 = Wo[(size_t)k * DM + c1];
#pragma unroll
    for (int r2 = 0; r2 < 4; ++r2) {
      float a = avs[r2][k];
      y0[r2] += a * w0;
      y1[r2] += a * w1;
    }
  }
  for (int r2 = 0; r2 < 4; ++r2) {
    size_t m = m0 + r2;
    float x0 = wres[m * DM + c0] + y0[r2];
    float x1 = wres[m * DM + c1] + y1[r2];
    red1[tid] = x0 + x1;
    red2[tid] = x0 * x0 + x1 * x1;
    __syncthreads();
    for (int st = 128; st >= 1; st >>= 1) {
      if (tid < st) {
        red1[tid] += red1[tid + st];
        red2[tid] += red2[tid + st];
      }
      __syncthreads();
    }
    float mu = red1[0] * (1.f / DM);
    float var = red2[0] * (1.f / DM) - mu * mu;
    float rstd = rsqrtf(var + LN_EPS);
    out[m * DM + c0] = (x0 - mu) * rstd * g[c0] + bb[c0];
    out[m * DM + c1] = (x1 - mu) * rstd * g[c1] + bb[c1];
    __syncthreads();
  }
}

extern "C" void kernel_launch(void* const* d_in, const int* in_sizes, int n_in,
                              void* d_out, int out_size, void* d_ws, size_t ws_size,
                              hipStream_t stream) {
  const float* w    = (const float*)d_in[0];
  const float* r    = (const float*)d_in[1];
  const float* rwb  = (const float*)d_in[2];
  const float* rrb  = (const float*)d_in[3];
  const float* mems = (const float*)d_in[4];
  const float* Wq   = (const float*)d_in[5];
  const float* Wkv  = (const float*)d_in[6];
  const float* Wr   = (const float*)d_in[7];
  const float* Wo   = (const float*)d_in[8];
  const float* ln_g = (const float*)d_in[9];
  const float* ln_b = (const float*)d_in[10];
  float* out = (float*)d_out;

  char* p = (char*)d_ws;
  auto alloc = [&](size_t bytes) {
    char* q = p;
    p += (bytes + 255) & ~(size_t)255;
    return q;
  };
  ushort* wbf   = (ushort*)alloc((size_t)QLEN * BSZ * DM * 2);   // 4 MB
  ushort* membf = (ushort*)alloc((size_t)MLEN * BSZ * DM * 2);   // 4 MB
  ushort* rbf   = (ushort*)alloc((size_t)KLEN * DM * 2);
  ushort* WqT   = (ushort*)alloc((size_t)DM * DM * 2);
  ushort* WkvT  = (ushort*)alloc((size_t)2 * DM * DM * 2);
  ushort* WrT   = (ushort*)alloc((size_t)DM * DM * 2);
  ushort* qw    = (ushort*)alloc((size_t)BSZ * NH * QLEN * DH * 2);
  ushort* qr    = (ushort*)alloc((size_t)BSZ * NH * QLEN * DH * 2);
  ushort* kh    = (ushort*)alloc((size_t)BSZ * NH * KLEN * DH * 2);
  ushort* vrow  = (ushort*)alloc((size_t)BSZ * NH * KLEN * DH * 2);
  ushort* vt    = (ushort*)alloc((size_t)BSZ * NH * DH * KLEN * 2 + 4096);
  ushort* rk    = (ushort*)alloc((size_t)NH * KLEN * DH * 2);
  // av (8 MB f32) aliases wbf+membf (8 MB): attn_mfma writes it only after
  // mfma_proj<0/1> (stream-ordered) have consumed wbf/membf. out_ln reads
  // the original f32 `w`, not wbf.
  float* av = (float*)wbf;

  // prep: bf16 activations + transposed bf16 weights
  cvt_bf16<<<dim3(QLEN * BSZ * DM / 1024), dim3(256), 0, stream>>>(w, wbf, QLEN * BSZ * DM);
  cvt_bf16<<<dim3(MLEN * BSZ * DM / 1024), dim3(256), 0, stream>>>(mems, membf, MLEN * BSZ * DM);
  cvt_bf16<<<dim3(KLEN * DM / 1024), dim3(256), 0, stream>>>(r, rbf, KLEN * DM);
  wtrans<<<dim3(16, 16), dim3(256), 0, stream>>>(Wq, WqT, DM);
  wtrans<<<dim3(16, 32), dim3(256), 0, stream>>>(Wkv, WkvT, 2 * DM);
  wtrans<<<dim3(16, 16), dim3(256), 0, stream>>>(Wr, WrT, DM);

  // projections (MFMA)
  mfma_proj<0><<<dim3(32, 4), dim3(256), 0, stream>>>(wbf, nullptr, WqT, rwb, rrb, qw, qr);
  mfma_proj<1><<<dim3(64, 8), dim3(256), 0, stream>>>(membf, wbf, WkvT, nullptr, nullptr, kh, vrow);
  mfma_proj<2><<<dim3(16, 4), dim3(256), 0, stream>>>(rbf, nullptr, WrT, nullptr, nullptr, rk, nullptr);
  vtrans<<<dim3(32, 32), dim3(256), 0, stream>>>(vrow, vt);

  attn_mfma<<<dim3(QLEN / 16, NH, BSZ), dim3(64), 0, stream>>>(qw, qr, kh, vt, rk, av);
  out_ln<<<dim3(QLEN * BSZ / 4), dim3(256), 0, stream>>>(av, Wo, w, ln_g, ln_b, out);
}

// Round 6
// 399.819 us; speedup vs baseline: 10.2875x; 1.1003x over previous
//
#include <hip/hip_runtime.h>
#include <hip/hip_bf16.h>
#include <math.h>

#define QLEN 1024
#define MLEN 1024
#define KLEN 2048
#define BSZ 4
#define NH 8
#define DH 64
#define DM 512
#define SCALE 0.125f
#define LN_EPS 1e-5f

typedef __attribute__((ext_vector_type(8))) short short8;   // 8 bf16 (4 VGPRs)
typedef __attribute__((ext_vector_type(4))) float float4_;  // MFMA C/D

__device__ inline ushort to_bf16(float x) {
  __hip_bfloat16 h = __float2bfloat16(x);
  return *reinterpret_cast<ushort*>(&h);
}

// ---------------------------------------------------------------------------
// f32 -> bf16 flat convert (4 elements/thread).
// ---------------------------------------------------------------------------
__global__ __launch_bounds__(256) void cvt_bf16(const float* __restrict__ src,
                                                ushort* __restrict__ dst, int n) {
  int i = (blockIdx.x * 256 + threadIdx.x) * 4;
  if (i >= n) return;
  float4 v = *reinterpret_cast<const float4*>(src + i);
  ushort4 o;
  o.x = to_bf16(v.x); o.y = to_bf16(v.y); o.z = to_bf16(v.z); o.w = to_bf16(v.w);
  *reinterpret_cast<ushort4*>(dst + i) = o;
}

// ---------------------------------------------------------------------------
// Weight transpose+convert: W[512][N] f32 -> WT[N][512] bf16. 32x32 LDS tiles.
// ---------------------------------------------------------------------------
__global__ __launch_bounds__(256) void wtrans(const float* __restrict__ W,
                                              ushort* __restrict__ WT, int N) {
  __shared__ ushort tile[32][33];
  const int k0 = blockIdx.x * 32, n0 = blockIdx.y * 32;
  const int tid = threadIdx.x;
#pragma unroll
  for (int it = 0; it < 4; ++it) {
    int idx = tid + it * 256;
    int r = idx >> 5, c = idx & 31;
    tile[r][c] = to_bf16(W[(size_t)(k0 + r) * N + n0 + c]);
  }
  __syncthreads();
#pragma unroll
  for (int it = 0; it < 4; ++it) {
    int idx = tid + it * 256;
    int r = idx >> 5, c = idx & 31;
    WT[(size_t)(n0 + r) * DM + k0 + c] = tile[c][r];
  }
}

// ---------------------------------------------------------------------------
// V transpose: vrow[bn][j][d] -> vt[bn][d][j]. 64x64 LDS tiles.
// ---------------------------------------------------------------------------
__global__ __launch_bounds__(256) void vtrans(const ushort* __restrict__ vrow,
                                              ushort* __restrict__ vt) {
  __shared__ ushort t[64][65];
  const int j0 = blockIdx.x * 64;
  const int bn = blockIdx.y;
  const int tid = threadIdx.x;
  const ushort* src = vrow + (size_t)bn * KLEN * DH;
  ushort* dst = vt + (size_t)bn * DH * KLEN;
#pragma unroll
  for (int it = 0; it < 16; ++it) {
    int idx = tid + it * 256;
    int r = idx >> 6, c = idx & 63;
    t[r][c] = src[(size_t)(j0 + r) * DH + c];
  }
  __syncthreads();
#pragma unroll
  for (int it = 0; it < 16; ++it) {
    int idx = tid + it * 256;
    int d = idx >> 6, jj = idx & 63;
    dst[(size_t)d * KLEN + j0 + jj] = t[jj][d];
  }
}

// ---------------------------------------------------------------------------
// MFMA projection GEMM. C[M,N] = A[M,512] @ W[512,N] with WT[N][512] bf16.
// Block tile 128x128, 4 waves (2x2) x 64x64 wave tile, BK=32, 16x16x32 bf16.
// ---------------------------------------------------------------------------
template <int MODE>
__global__ __launch_bounds__(256) void mfma_proj(
    const ushort* __restrict__ A0, const ushort* __restrict__ A1,
    const ushort* __restrict__ BT,
    const float* __restrict__ bias0, const float* __restrict__ bias1,
    ushort* __restrict__ O0, ushort* __restrict__ O1) {
  __shared__ ushort As[128 * 32];
  __shared__ ushort Bs[128 * 32];
  const int tid = threadIdx.x;
  const int m0 = blockIdx.x * 128, n0 = blockIdx.y * 128;
  const int wv = tid >> 6, lane = tid & 63;
  const int wm = wv >> 1, wn = wv & 1;
  const int l16 = lane & 15, quad = lane >> 4;

  const int arow = tid >> 1;            // 0..127
  const int acol = (tid & 1) * 16;      // 0 or 16 (ushort index)
  const ushort* asrc;
  {
    int m = m0 + arow;
    if (MODE == 1)
      asrc = (m < QLEN * BSZ) ? A0 + (size_t)m * DM : A1 + (size_t)(m - QLEN * BSZ) * DM;
    else
      asrc = A0 + (size_t)m * DM;
    asrc += acol;
  }
  const ushort* bsrc = BT + (size_t)(n0 + arow) * DM + acol;

  float4_ acc[4][4];
#pragma unroll
  for (int a = 0; a < 4; ++a)
#pragma unroll
    for (int b = 0; b < 4; ++b) acc[a][b] = float4_{0.f, 0.f, 0.f, 0.f};

  for (int k0 = 0; k0 < DM; k0 += 32) {
    *reinterpret_cast<uint4*>(&As[arow * 32 + acol]) =
        *reinterpret_cast<const uint4*>(asrc + k0);
    *reinterpret_cast<uint4*>(&As[arow * 32 + acol + 8]) =
        *reinterpret_cast<const uint4*>(asrc + k0 + 8);
    *reinterpret_cast<uint4*>(&Bs[arow * 32 + acol]) =
        *reinterpret_cast<const uint4*>(bsrc + k0);
    *reinterpret_cast<uint4*>(&Bs[arow * 32 + acol + 8]) =
        *reinterpret_cast<const uint4*>(bsrc + k0 + 8);
    __syncthreads();
    short8 af[4], bf[4];
#pragma unroll
    for (int f = 0; f < 4; ++f) {
      af[f] = *reinterpret_cast<const short8*>(&As[(wm * 64 + f * 16 + l16) * 32 + quad * 8]);
      bf[f] = *reinterpret_cast<const short8*>(&Bs[(wn * 64 + f * 16 + l16) * 32 + quad * 8]);
    }
#pragma unroll
    for (int fm = 0; fm < 4; ++fm)
#pragma unroll
      for (int fn = 0; fn < 4; ++fn)
        acc[fm][fn] = __builtin_amdgcn_mfma_f32_16x16x32_bf16(af[fm], bf[fn], acc[fm][fn], 0, 0, 0);
    __syncthreads();
  }

#pragma unroll
  for (int fm = 0; fm < 4; ++fm) {
#pragma unroll
    for (int fn = 0; fn < 4; ++fn) {
#pragma unroll
      for (int reg = 0; reg < 4; ++reg) {
        int mm = m0 + wm * 64 + fm * 16 + quad * 4 + reg;
        int nn = n0 + wn * 64 + fn * 16 + l16;
        float v = acc[fm][fn][reg];
        if (MODE == 0) {
          int i = mm >> 2, b = mm & 3;
          int n = nn >> 6, d = nn & 63;
          size_t idx = (((size_t)(b * NH + n)) * QLEN + i) * DH + d;
          O0[idx] = to_bf16(v + bias0[nn]);
          O1[idx] = to_bf16(v + bias1[nn]);
        } else if (MODE == 1) {
          int pos = mm >> 2, b = mm & 3;
          int nn2 = nn & 511;
          int n = nn2 >> 6, d = nn2 & 63;
          size_t idx = (((size_t)(b * NH + n)) * KLEN + pos) * DH + d;
          if (nn < DM) O0[idx] = to_bf16(v);
          else         O1[idx] = to_bf16(v);
        } else {
          int n = nn >> 6, d = nn & 63;
          O0[((size_t)n * KLEN + mm) * DH + d] = to_bf16(v);
        }
      }
    }
  }
}

// ---------------------------------------------------------------------------
// MFMA flash attention, 4 waves/block on ONE 16-row Q tile, j-split x4.
// Wave wv handles chunks j0 = wv*32 + 128k. No barriers in the loop (wave-
// private LDS slices); flash-combine of (m,l,O) across waves at the end.
// D stored diagonally shifted (col = c+row, stride 66) -> conflict-free read.
// P stored in A-fragment order -> sequential ds_read_b128.
// ---------------------------------------------------------------------------
__global__ __launch_bounds__(256) void attn_mfma(
    const ushort* __restrict__ qw, const ushort* __restrict__ qr,
    const ushort* __restrict__ kh, const ushort* __restrict__ vt,
    const ushort* __restrict__ rk, float* __restrict__ av) {
  const int i0 = (gridDim.x - 1 - blockIdx.x) * 16;  // longest blocks first
  const int n = blockIdx.y, b = blockIdx.z;
  const int bn = b * NH + n;
  const int tid = threadIdx.x;
  const int wv = tid >> 6;
  const int lane = tid & 63;
  const int l16 = lane & 15, quad = lane >> 4;

  union SharedU {
    struct { float D[4][16 * 66]; ushort P[4][16 * 32]; } loop;
    struct { float O[4][16][64]; float m[4][16]; float l[4][16]; } mg;
  };
  __shared__ SharedU sh;
  float* __restrict__ Dw = sh.loop.D[wv];
  ushort* __restrict__ Pw = sh.loop.P[wv];

  const ushort* __restrict__ Kp = kh + (size_t)bn * KLEN * DH;
  const ushort* __restrict__ Vt = vt + (size_t)bn * DH * KLEN;
  const ushort* __restrict__ Rk = rk + (size_t)n * KLEN * DH;

  // A-layout Q fragments: A[m=l16][k=quad*8+jj]
  short8 aqw0, aqw1, aqr0, aqr1;
  {
    const ushort* qwp = qw + (((size_t)bn * QLEN) + i0 + l16) * DH + quad * 8;
    const ushort* qrp = qr + (((size_t)bn * QLEN) + i0 + l16) * DH + quad * 8;
    aqw0 = *(const short8*)(qwp);
    aqw1 = *(const short8*)(qwp + 32);
    aqr0 = *(const short8*)(qrp);
    aqr1 = *(const short8*)(qrp + 32);
  }

  float4_ O[4];
#pragma unroll
  for (int t = 0; t < 4; ++t) O[t] = float4_{0.f, 0.f, 0.f, 0.f};
  float mrow[4] = {-INFINITY, -INFINITY, -INFINITY, -INFINITY};
  float lrow[4] = {0.f, 0.f, 0.f, 0.f};
  const float SL2E = SCALE * 1.44269504088896f;  // scores in exp2 domain

  const int jmax = i0 + 15 + MLEN;  // inclusive last key for any row in tile
  // wave wv's first chunk j0 = wv*32 <= 96 < 1024 is unmasked for ALL rows,
  // so mrow becomes finite on the first iteration (no -inf - -inf NaN).
  for (int j0 = wv * 32; j0 <= jmax; j0 += 128) {
    const int tb = j0 - i0 + 1008;  // >= 0 always
    // ---- D band (48 wide): diagonal-shifted store, stride 66 ----
#pragma unroll
    for (int tt = 0; tt < 3; ++tt) {
      int t = tb + tt * 16 + l16;
      t = (t > KLEN - 1) ? (KLEN - 1) : t;  // clamped region is masked anyway
      const ushort* rp = Rk + (size_t)t * DH + quad * 8;
      short8 b0 = *(const short8*)rp;
      short8 b1 = *(const short8*)(rp + 32);
      float4_ d = {0.f, 0.f, 0.f, 0.f};
      d = __builtin_amdgcn_mfma_f32_16x16x32_bf16(aqr0, b0, d, 0, 0, 0);
      d = __builtin_amdgcn_mfma_f32_16x16x32_bf16(aqr1, b1, d, 0, 0, 0);
#pragma unroll
      for (int rg = 0; rg < 4; ++rg) {
        int row = quad * 4 + rg;
        Dw[row * 66 + tt * 16 + l16 + row] = d[rg];  // D[row][c] at col c+row
      }
    }
    // ---- AC: 2 tiles of 16 keys ----
    float4_ ac[2];
#pragma unroll
    for (int half = 0; half < 2; ++half) {
      int j = j0 + half * 16 + l16;
      int jc = (j > KLEN - 1) ? (KLEN - 1) : j;
      const ushort* kp = Kp + (size_t)jc * DH + quad * 8;
      short8 b0 = *(const short8*)kp;
      short8 b1 = *(const short8*)(kp + 32);
      float4_ c = {0.f, 0.f, 0.f, 0.f};
      c = __builtin_amdgcn_mfma_f32_16x16x32_bf16(aqw0, b0, c, 0, 0, 0);
      c = __builtin_amdgcn_mfma_f32_16x16x32_bf16(aqw1, b1, c, 0, 0, 0);
      ac[half] = c;
    }
    // ---- scores + rel-shift gather (conflict-free: bank = 8q + l16) ----
    float s[2][4];
#pragma unroll
    for (int half = 0; half < 2; ++half) {
#pragma unroll
      for (int rg = 0; rg < 4; ++rg) {
        int row = quad * 4 + rg;
        int jloc = half * 16 + l16;
        int j = j0 + jloc;
        float bd = Dw[row * 66 + jloc + 15];  // = D[row][jloc - row + 15]
        float sv = (ac[half][rg] + bd) * SL2E;
        s[half][rg] = (j > i0 + row + MLEN) ? -INFINITY : sv;
      }
    }
    // ---- online softmax (rows live in 16-lane groups) ----
#pragma unroll
    for (int rg = 0; rg < 4; ++rg) {
      float mx = fmaxf(s[0][rg], s[1][rg]);
#pragma unroll
      for (int off = 1; off <= 8; off <<= 1) mx = fmaxf(mx, __shfl_xor(mx, off, 64));
      float mn = fmaxf(mrow[rg], mx);
      float alpha = __builtin_amdgcn_exp2f(mrow[rg] - mn);
      float p0 = __builtin_amdgcn_exp2f(s[0][rg] - mn);
      float p1 = __builtin_amdgcn_exp2f(s[1][rg] - mn);
      float ls = p0 + p1;
#pragma unroll
      for (int off = 1; off <= 8; off <<= 1) ls += __shfl_xor(ls, off, 64);
      lrow[rg] = lrow[rg] * alpha + ls;
      mrow[rg] = mn;
#pragma unroll
      for (int t = 0; t < 4; ++t) O[t][rg] *= alpha;
      // P in A-frag order: flat = reader_lane*8 + jj, value P[r=l16'][c]
      int row = quad * 4 + rg;
      int idx0 = (l16 >> 3) * 128 + row * 8 + (l16 & 7);  // c = l16
      Pw[idx0] = to_bf16(p0);
      Pw[idx0 + 256] = to_bf16(p1);                        // c = 16 + l16
    }
    // ---- PV: sequential 16B ds_read_b128 per lane ----
    short8 pfrag = *(const short8*)&Pw[lane * 8];
#pragma unroll
    for (int t = 0; t < 4; ++t) {
      const ushort* vp = Vt + (size_t)(t * 16 + l16) * KLEN + j0 + quad * 8;
      short8 vfrag = *(const short8*)vp;  // padded alloc covers tail overread
      O[t] = __builtin_amdgcn_mfma_f32_16x16x32_bf16(pfrag, vfrag, O[t], 0, 0, 0);
    }
  }

  // ---- flash-combine across the 4 waves ----
  __syncthreads();  // all waves done with loop LDS (merge area aliases it)
#pragma unroll
  for (int t = 0; t < 4; ++t)
#pragma unroll
    for (int rg = 0; rg < 4; ++rg)
      sh.mg.O[wv][quad * 4 + rg][t * 16 + l16] = O[t][rg];
  if (l16 == 0) {
#pragma unroll
    for (int rg = 0; rg < 4; ++rg) {
      sh.mg.m[wv][quad * 4 + rg] = mrow[rg];
      sh.mg.l[wv][quad * 4 + rg] = lrow[rg];
    }
  }
  __syncthreads();
  {
    const int row = tid >> 4;          // 0..15
    const int c0 = (tid & 15) * 4;     // 0..60
    float m0v = sh.mg.m[0][row], m1v = sh.mg.m[1][row];
    float m2v = sh.mg.m[2][row], m3v = sh.mg.m[3][row];
    float mstar = fmaxf(fmaxf(m0v, m1v), fmaxf(m2v, m3v));
    float c0w = __builtin_amdgcn_exp2f(m0v - mstar);
    float c1w = __builtin_amdgcn_exp2f(m1v - mstar);
    float c2w = __builtin_amdgcn_exp2f(m2v - mstar);
    float c3w = __builtin_amdgcn_exp2f(m3v - mstar);
    float lstar = c0w * sh.mg.l[0][row] + c1w * sh.mg.l[1][row] +
                  c2w * sh.mg.l[2][row] + c3w * sh.mg.l[3][row];
    float inv = 1.f / lstar;
    float4 o;
    float* op = &o.x;
#pragma unroll
    for (int u = 0; u < 4; ++u) {
      int c = c0 + u;
      op[u] = (c0w * sh.mg.O[0][row][c] + c1w * sh.mg.O[1][row][c] +
               c2w * sh.mg.O[2][row][c] + c3w * sh.mg.O[3][row][c]) * inv;
    }
    *reinterpret_cast<float4*>(
        &av[((size_t)(i0 + row) * BSZ + b) * DM + n * DH + c0]) = o;
  }
}

// ---------------------------------------------------------------------------
// Output: y = av @ Wo; out = LayerNorm(w + y) * g + b. 4 rows per block.
// ---------------------------------------------------------------------------
__global__ __launch_bounds__(256) void out_ln(
    const float* __restrict__ av, const float* __restrict__ Wo,
    const float* __restrict__ wres, const float* __restrict__ g,
    const float* __restrict__ bb, float* __restrict__ out) {
  __shared__ float avs[4][DM];
  __shared__ float red1[256];
  __shared__ float red2[256];
  const int tid = threadIdx.x;
  const int m0 = blockIdx.x * 4;
  for (int idx = tid; idx < 4 * DM; idx += 256)
    avs[idx >> 9][idx & 511] = av[(size_t)m0 * DM + idx];
  __syncthreads();
  float y0[4] = {0.f, 0.f, 0.f, 0.f};
  float y1[4] = {0.f, 0.f, 0.f, 0.f};
  const int c0 = tid, c1 = tid + 256;
  for (int k = 0; k < DM; ++k) {
    float w0 = Wo[(size_t)k * DM + c0];
    float w1 = Wo[(size_t)k * DM + c1];
#pragma unroll
    for (int r2 = 0; r2 < 4; ++r2) {
      float a = avs[r2][k];
      y0[r2] += a * w0;
      y1[r2] += a * w1;
    }
  }
  for (int r2 = 0; r2 < 4; ++r2) {
    size_t m = m0 + r2;
    float x0 = wres[m * DM + c0] + y0[r2];
    float x1 = wres[m * DM + c1] + y1[r2];
    red1[tid] = x0 + x1;
    red2[tid] = x0 * x0 + x1 * x1;
    __syncthreads();
    for (int st = 128; st >= 1; st >>= 1) {
      if (tid < st) {
        red1[tid] += red1[tid + st];
        red2[tid] += red2[tid + st];
      }
      __syncthreads();
    }
    float mu = red1[0] * (1.f / DM);
    float var = red2[0] * (1.f / DM) - mu * mu;
    float rstd = rsqrtf(var + LN_EPS);
    out[m * DM + c0] = (x0 - mu) * rstd * g[c0] + bb[c0];
    out[m * DM + c1] = (x1 - mu) * rstd * g[c1] + bb[c1];
    __syncthreads();
  }
}

extern "C" void kernel_launch(void* const* d_in, const int* in_sizes, int n_in,
                              void* d_out, int out_size, void* d_ws, size_t ws_size,
                              hipStream_t stream) {
  const float* w    = (const float*)d_in[0];
  const float* r    = (const float*)d_in[1];
  const float* rwb  = (const float*)d_in[2];
  const float* rrb  = (const float*)d_in[3];
  const float* mems = (const float*)d_in[4];
  const float* Wq   = (const float*)d_in[5];
  const float* Wkv  = (const float*)d_in[6];
  const float* Wr   = (const float*)d_in[7];
  const float* Wo   = (const float*)d_in[8];
  const float* ln_g = (const float*)d_in[9];
  const float* ln_b = (const float*)d_in[10];
  float* out = (float*)d_out;

  char* p = (char*)d_ws;
  auto alloc = [&](size_t bytes) {
    char* q = p;
    p += (bytes + 255) & ~(size_t)255;
    return q;
  };
  ushort* wbf   = (ushort*)alloc((size_t)QLEN * BSZ * DM * 2);   // 4 MB
  ushort* membf = (ushort*)alloc((size_t)MLEN * BSZ * DM * 2);   // 4 MB
  ushort* rbf   = (ushort*)alloc((size_t)KLEN * DM * 2);
  ushort* WqT   = (ushort*)alloc((size_t)DM * DM * 2);
  ushort* WkvT  = (ushort*)alloc((size_t)2 * DM * DM * 2);
  ushort* WrT   = (ushort*)alloc((size_t)DM * DM * 2);
  ushort* qw    = (ushort*)alloc((size_t)BSZ * NH * QLEN * DH * 2);
  ushort* qr    = (ushort*)alloc((size_t)BSZ * NH * QLEN * DH * 2);
  ushort* kh    = (ushort*)alloc((size_t)BSZ * NH * KLEN * DH * 2);
  ushort* vrow  = (ushort*)alloc((size_t)BSZ * NH * KLEN * DH * 2);
  ushort* vt    = (ushort*)alloc((size_t)BSZ * NH * DH * KLEN * 2 + 4096);
  ushort* rk    = (ushort*)alloc((size_t)NH * KLEN * DH * 2);
  // av (8 MB f32) aliases wbf+membf (8 MB): attn_mfma writes it only after
  // mfma_proj<0/1> (stream-ordered) have consumed wbf/membf. out_ln reads
  // the original f32 `w`, not wbf.
  float* av = (float*)wbf;

  // prep: bf16 activations + transposed bf16 weights
  cvt_bf16<<<dim3(QLEN * BSZ * DM / 1024), dim3(256), 0, stream>>>(w, wbf, QLEN * BSZ * DM);
  cvt_bf16<<<dim3(MLEN * BSZ * DM / 1024), dim3(256), 0, stream>>>(mems, membf, MLEN * BSZ * DM);
  cvt_bf16<<<dim3(KLEN * DM / 1024), dim3(256), 0, stream>>>(r, rbf, KLEN * DM);
  wtrans<<<dim3(16, 16), dim3(256), 0, stream>>>(Wq, WqT, DM);
  wtrans<<<dim3(16, 32), dim3(256), 0, stream>>>(Wkv, WkvT, 2 * DM);
  wtrans<<<dim3(16, 16), dim3(256), 0, stream>>>(Wr, WrT, DM);

  // projections (MFMA)
  mfma_proj<0><<<dim3(32, 4), dim3(256), 0, stream>>>(wbf, nullptr, WqT, rwb, rrb, qw, qr);
  mfma_proj<1><<<dim3(64, 8), dim3(256), 0, stream>>>(membf, wbf, WkvT, nullptr, nullptr, kh, vrow);
  mfma_proj<2><<<dim3(16, 4), dim3(256), 0, stream>>>(rbf, nullptr, WrT, nullptr, nullptr, rk, nullptr);
  vtrans<<<dim3(32, 32), dim3(256), 0, stream>>>(vrow, vt);

  attn_mfma<<<dim3(QLEN / 16, NH, BSZ), dim3(256), 0, stream>>>(qw, qr, kh, vt, rk, av);
  out_ln<<<dim3(QLEN * BSZ / 4), dim3(256), 0, stream>>>(av, Wo, w, ln_g, ln_b, out);
}

// Round 7
// 379.797 us; speedup vs baseline: 10.8298x; 1.0527x over previous
//
#include <hip/hip_runtime.h>
#include <hip/hip_bf16.h>
#include <math.h>

#define QLEN 1024
#define MLEN 1024
#define KLEN 2048
#define BSZ 4
#define NH 8
#define DH 64
#define DM 512
#define SCALE 0.125f
#define LN_EPS 1e-5f

typedef __attribute__((ext_vector_type(8))) short short8;   // 8 bf16 (4 VGPRs)
typedef __attribute__((ext_vector_type(4))) float float4_;  // MFMA C/D

__device__ inline ushort to_bf16(float x) {
  __hip_bfloat16 h = __float2bfloat16(x);
  return *reinterpret_cast<ushort*>(&h);
}

// 16-lane (row) reductions on the VALU pipe via DPP: quad_perm xor1 (0xB1),
// xor2 (0x4E), row_ror:4 (0x124), row_ror:8 (0x128). All 16 lanes end with
// the row-wide result. No LDS-pipe traffic.
__device__ inline float row_max16(float v) {
  int x = __builtin_bit_cast(int, v);
  v = fmaxf(v, __builtin_bit_cast(float, __builtin_amdgcn_update_dpp(x, x, 0xB1, 0xF, 0xF, false)));
  x = __builtin_bit_cast(int, v);
  v = fmaxf(v, __builtin_bit_cast(float, __builtin_amdgcn_update_dpp(x, x, 0x4E, 0xF, 0xF, false)));
  x = __builtin_bit_cast(int, v);
  v = fmaxf(v, __builtin_bit_cast(float, __builtin_amdgcn_update_dpp(x, x, 0x124, 0xF, 0xF, false)));
  x = __builtin_bit_cast(int, v);
  v = fmaxf(v, __builtin_bit_cast(float, __builtin_amdgcn_update_dpp(x, x, 0x128, 0xF, 0xF, false)));
  return v;
}
__device__ inline float row_sum16(float v) {
  int x = __builtin_bit_cast(int, v);
  v += __builtin_bit_cast(float, __builtin_amdgcn_update_dpp(x, x, 0xB1, 0xF, 0xF, false));
  x = __builtin_bit_cast(int, v);
  v += __builtin_bit_cast(float, __builtin_amdgcn_update_dpp(x, x, 0x4E, 0xF, 0xF, false));
  x = __builtin_bit_cast(int, v);
  v += __builtin_bit_cast(float, __builtin_amdgcn_update_dpp(x, x, 0x124, 0xF, 0xF, false));
  x = __builtin_bit_cast(int, v);
  v += __builtin_bit_cast(float, __builtin_amdgcn_update_dpp(x, x, 0x128, 0xF, 0xF, false));
  return v;
}

// ---------------------------------------------------------------------------
// f32 -> bf16 flat convert (4 elements/thread).
// ---------------------------------------------------------------------------
__global__ __launch_bounds__(256) void cvt_bf16(const float* __restrict__ src,
                                                ushort* __restrict__ dst, int n) {
  int i = (blockIdx.x * 256 + threadIdx.x) * 4;
  if (i >= n) return;
  float4 v = *reinterpret_cast<const float4*>(src + i);
  ushort4 o;
  o.x = to_bf16(v.x); o.y = to_bf16(v.y); o.z = to_bf16(v.z); o.w = to_bf16(v.w);
  *reinterpret_cast<ushort4*>(dst + i) = o;
}

// ---------------------------------------------------------------------------
// Weight transpose+convert: W[512][N] f32 -> WT[N][512] bf16. 32x32 LDS tiles.
// ---------------------------------------------------------------------------
__global__ __launch_bounds__(256) void wtrans(const float* __restrict__ W,
                                              ushort* __restrict__ WT, int N) {
  __shared__ ushort tile[32][33];
  const int k0 = blockIdx.x * 32, n0 = blockIdx.y * 32;
  const int tid = threadIdx.x;
#pragma unroll
  for (int it = 0; it < 4; ++it) {
    int idx = tid + it * 256;
    int r = idx >> 5, c = idx & 31;
    tile[r][c] = to_bf16(W[(size_t)(k0 + r) * N + n0 + c]);
  }
  __syncthreads();
#pragma unroll
  for (int it = 0; it < 4; ++it) {
    int idx = tid + it * 256;
    int r = idx >> 5, c = idx & 31;
    WT[(size_t)(n0 + r) * DM + k0 + c] = tile[c][r];
  }
}

// ---------------------------------------------------------------------------
// V transpose: vrow[bn][j][d] -> vt[bn][d][j]. 64x64 LDS tiles.
// ---------------------------------------------------------------------------
__global__ __launch_bounds__(256) void vtrans(const ushort* __restrict__ vrow,
                                              ushort* __restrict__ vt) {
  __shared__ ushort t[64][65];
  const int j0 = blockIdx.x * 64;
  const int bn = blockIdx.y;
  const int tid = threadIdx.x;
  const ushort* src = vrow + (size_t)bn * KLEN * DH;
  ushort* dst = vt + (size_t)bn * DH * KLEN;
#pragma unroll
  for (int it = 0; it < 16; ++it) {
    int idx = tid + it * 256;
    int r = idx >> 6, c = idx & 63;
    t[r][c] = src[(size_t)(j0 + r) * DH + c];
  }
  __syncthreads();
#pragma unroll
  for (int it = 0; it < 16; ++it) {
    int idx = tid + it * 256;
    int d = idx >> 6, jj = idx & 63;
    dst[(size_t)d * KLEN + j0 + jj] = t[jj][d];
  }
}

// ---------------------------------------------------------------------------
// MFMA projection GEMM. C[M,N] = A[M,512] @ W[512,N] with WT[N][512] bf16.
// Block tile 128x128, 4 waves (2x2) x 64x64 wave tile, BK=32, 16x16x32 bf16.
// ---------------------------------------------------------------------------
template <int MODE>
__global__ __launch_bounds__(256) void mfma_proj(
    const ushort* __restrict__ A0, const ushort* __restrict__ A1,
    const ushort* __restrict__ BT,
    const float* __restrict__ bias0, const float* __restrict__ bias1,
    ushort* __restrict__ O0, ushort* __restrict__ O1) {
  __shared__ ushort As[128 * 32];
  __shared__ ushort Bs[128 * 32];
  const int tid = threadIdx.x;
  const int m0 = blockIdx.x * 128, n0 = blockIdx.y * 128;
  const int wv = tid >> 6, lane = tid & 63;
  const int wm = wv >> 1, wn = wv & 1;
  const int l16 = lane & 15, quad = lane >> 4;

  const int arow = tid >> 1;            // 0..127
  const int acol = (tid & 1) * 16;      // 0 or 16 (ushort index)
  const ushort* asrc;
  {
    int m = m0 + arow;
    if (MODE == 1)
      asrc = (m < QLEN * BSZ) ? A0 + (size_t)m * DM : A1 + (size_t)(m - QLEN * BSZ) * DM;
    else
      asrc = A0 + (size_t)m * DM;
    asrc += acol;
  }
  const ushort* bsrc = BT + (size_t)(n0 + arow) * DM + acol;

  float4_ acc[4][4];
#pragma unroll
  for (int a = 0; a < 4; ++a)
#pragma unroll
    for (int b = 0; b < 4; ++b) acc[a][b] = float4_{0.f, 0.f, 0.f, 0.f};

  for (int k0 = 0; k0 < DM; k0 += 32) {
    *reinterpret_cast<uint4*>(&As[arow * 32 + acol]) =
        *reinterpret_cast<const uint4*>(asrc + k0);
    *reinterpret_cast<uint4*>(&As[arow * 32 + acol + 8]) =
        *reinterpret_cast<const uint4*>(asrc + k0 + 8);
    *reinterpret_cast<uint4*>(&Bs[arow * 32 + acol]) =
        *reinterpret_cast<const uint4*>(bsrc + k0);
    *reinterpret_cast<uint4*>(&Bs[arow * 32 + acol + 8]) =
        *reinterpret_cast<const uint4*>(bsrc + k0 + 8);
    __syncthreads();
    short8 af[4], bf[4];
#pragma unroll
    for (int f = 0; f < 4; ++f) {
      af[f] = *reinterpret_cast<const short8*>(&As[(wm * 64 + f * 16 + l16) * 32 + quad * 8]);
      bf[f] = *reinterpret_cast<const short8*>(&Bs[(wn * 64 + f * 16 + l16) * 32 + quad * 8]);
    }
#pragma unroll
    for (int fm = 0; fm < 4; ++fm)
#pragma unroll
      for (int fn = 0; fn < 4; ++fn)
        acc[fm][fn] = __builtin_amdgcn_mfma_f32_16x16x32_bf16(af[fm], bf[fn], acc[fm][fn], 0, 0, 0);
    __syncthreads();
  }

#pragma unroll
  for (int fm = 0; fm < 4; ++fm) {
#pragma unroll
    for (int fn = 0; fn < 4; ++fn) {
#pragma unroll
      for (int reg = 0; reg < 4; ++reg) {
        int mm = m0 + wm * 64 + fm * 16 + quad * 4 + reg;
        int nn = n0 + wn * 64 + fn * 16 + l16;
        float v = acc[fm][fn][reg];
        if (MODE == 0) {
          int i = mm >> 2, b = mm & 3;
          int n = nn >> 6, d = nn & 63;
          size_t idx = (((size_t)(b * NH + n)) * QLEN + i) * DH + d;
          O0[idx] = to_bf16(v + bias0[nn]);
          O1[idx] = to_bf16(v + bias1[nn]);
        } else if (MODE == 1) {
          int pos = mm >> 2, b = mm & 3;
          int nn2 = nn & 511;
          int n = nn2 >> 6, d = nn2 & 63;
          size_t idx = (((size_t)(b * NH + n)) * KLEN + pos) * DH + d;
          if (nn < DM) O0[idx] = to_bf16(v);
          else         O1[idx] = to_bf16(v);
        } else {
          int n = nn >> 6, d = nn & 63;
          O0[((size_t)n * KLEN + mm) * DH + d] = to_bf16(v);
        }
      }
    }
  }
}

// ---------------------------------------------------------------------------
// Output GEMM: y[4096x512] = avbf @ WoT (f32 out, no epilogue fusion).
// ---------------------------------------------------------------------------
__global__ __launch_bounds__(256) void mfma_out(
    const ushort* __restrict__ A, const ushort* __restrict__ BT,
    float* __restrict__ Y) {
  __shared__ ushort As[128 * 32];
  __shared__ ushort Bs[128 * 32];
  const int tid = threadIdx.x;
  const int m0 = blockIdx.x * 128, n0 = blockIdx.y * 128;
  const int wv = tid >> 6, lane = tid & 63;
  const int wm = wv >> 1, wn = wv & 1;
  const int l16 = lane & 15, quad = lane >> 4;
  const int arow = tid >> 1;
  const int acol = (tid & 1) * 16;
  const ushort* asrc = A + (size_t)(m0 + arow) * DM + acol;
  const ushort* bsrc = BT + (size_t)(n0 + arow) * DM + acol;

  float4_ acc[4][4];
#pragma unroll
  for (int a = 0; a < 4; ++a)
#pragma unroll
    for (int b = 0; b < 4; ++b) acc[a][b] = float4_{0.f, 0.f, 0.f, 0.f};

  for (int k0 = 0; k0 < DM; k0 += 32) {
    *reinterpret_cast<uint4*>(&As[arow * 32 + acol]) = *reinterpret_cast<const uint4*>(asrc + k0);
    *reinterpret_cast<uint4*>(&As[arow * 32 + acol + 8]) = *reinterpret_cast<const uint4*>(asrc + k0 + 8);
    *reinterpret_cast<uint4*>(&Bs[arow * 32 + acol]) = *reinterpret_cast<const uint4*>(bsrc + k0);
    *reinterpret_cast<uint4*>(&Bs[arow * 32 + acol + 8]) = *reinterpret_cast<const uint4*>(bsrc + k0 + 8);
    __syncthreads();
    short8 af[4], bf[4];
#pragma unroll
    for (int f = 0; f < 4; ++f) {
      af[f] = *reinterpret_cast<const short8*>(&As[(wm * 64 + f * 16 + l16) * 32 + quad * 8]);
      bf[f] = *reinterpret_cast<const short8*>(&Bs[(wn * 64 + f * 16 + l16) * 32 + quad * 8]);
    }
#pragma unroll
    for (int fm = 0; fm < 4; ++fm)
#pragma unroll
      for (int fn = 0; fn < 4; ++fn)
        acc[fm][fn] = __builtin_amdgcn_mfma_f32_16x16x32_bf16(af[fm], bf[fn], acc[fm][fn], 0, 0, 0);
    __syncthreads();
  }
#pragma unroll
  for (int fm = 0; fm < 4; ++fm)
#pragma unroll
    for (int fn = 0; fn < 4; ++fn)
#pragma unroll
      for (int reg = 0; reg < 4; ++reg) {
        int mm = m0 + wm * 64 + fm * 16 + quad * 4 + reg;
        int nn = n0 + wn * 64 + fn * 16 + l16;
        Y[(size_t)mm * DM + nn] = acc[fm][fn][reg];
      }
}

// ---------------------------------------------------------------------------
// Residual + LayerNorm: one wave per row (8 cols/lane).
// ---------------------------------------------------------------------------
__global__ __launch_bounds__(256) void ln_fuse(
    const float* __restrict__ y, const float* __restrict__ wres,
    const float* __restrict__ g, const float* __restrict__ bb,
    float* __restrict__ out) {
  const int row = blockIdx.x * 4 + (threadIdx.x >> 6);
  const int lane = threadIdx.x & 63;
  const float* yr = y + (size_t)row * DM + lane * 4;
  const float* wr = wres + (size_t)row * DM + lane * 4;
  float4 x0 = *(const float4*)yr;
  float4 x1 = *(const float4*)(yr + 256);
  float4 w0 = *(const float4*)wr;
  float4 w1 = *(const float4*)(wr + 256);
  x0.x += w0.x; x0.y += w0.y; x0.z += w0.z; x0.w += w0.w;
  x1.x += w1.x; x1.y += w1.y; x1.z += w1.z; x1.w += w1.w;
  float s = x0.x + x0.y + x0.z + x0.w + x1.x + x1.y + x1.z + x1.w;
  float ss = x0.x * x0.x + x0.y * x0.y + x0.z * x0.z + x0.w * x0.w +
             x1.x * x1.x + x1.y * x1.y + x1.z * x1.z + x1.w * x1.w;
#pragma unroll
  for (int off = 1; off <= 32; off <<= 1) {
    s += __shfl_xor(s, off, 64);
    ss += __shfl_xor(ss, off, 64);
  }
  float mu = s * (1.f / DM);
  float var = ss * (1.f / DM) - mu * mu;
  float rstd = rsqrtf(var + LN_EPS);
  float4 g0 = *(const float4*)(g + lane * 4);
  float4 g1 = *(const float4*)(g + lane * 4 + 256);
  float4 b0 = *(const float4*)(bb + lane * 4);
  float4 b1 = *(const float4*)(bb + lane * 4 + 256);
  float4 o0, o1;
  o0.x = (x0.x - mu) * rstd * g0.x + b0.x;
  o0.y = (x0.y - mu) * rstd * g0.y + b0.y;
  o0.z = (x0.z - mu) * rstd * g0.z + b0.z;
  o0.w = (x0.w - mu) * rstd * g0.w + b0.w;
  o1.x = (x1.x - mu) * rstd * g1.x + b1.x;
  o1.y = (x1.y - mu) * rstd * g1.y + b1.y;
  o1.z = (x1.z - mu) * rstd * g1.z + b1.z;
  o1.w = (x1.w - mu) * rstd * g1.w + b1.w;
  float* orow = out + (size_t)row * DM + lane * 4;
  *reinterpret_cast<float4*>(orow) = o0;
  *reinterpret_cast<float4*>(orow + 256) = o1;
}

// ---------------------------------------------------------------------------
// MFMA flash attention, 4 waves/block on ONE 16-row Q tile, j-split x4.
// In-loop cross-lane work on the VALU pipe only (DPP max; l-sum deferred).
// ---------------------------------------------------------------------------
__global__ __launch_bounds__(256) void attn_mfma(
    const ushort* __restrict__ qw, const ushort* __restrict__ qr,
    const ushort* __restrict__ kh, const ushort* __restrict__ vt,
    const ushort* __restrict__ rk, ushort* __restrict__ avbf) {
  const int i0 = (gridDim.x - 1 - blockIdx.x) * 16;  // longest blocks first
  const int n = blockIdx.y, b = blockIdx.z;
  const int bn = b * NH + n;
  const int tid = threadIdx.x;
  const int wv = tid >> 6;
  const int lane = tid & 63;
  const int l16 = lane & 15, quad = lane >> 4;

  union SharedU {
    struct { float D[4][16 * 66]; ushort P[4][16 * 32]; } loop;
    struct { float O[4][16][64]; float m[4][16]; float l[4][16]; } mg;
  };
  __shared__ SharedU sh;
  float* __restrict__ Dw = sh.loop.D[wv];
  ushort* __restrict__ Pw = sh.loop.P[wv];

  const ushort* __restrict__ Kp = kh + (size_t)bn * KLEN * DH;
  const ushort* __restrict__ Vt = vt + (size_t)bn * DH * KLEN;
  const ushort* __restrict__ Rk = rk + (size_t)n * KLEN * DH;

  // A-layout Q fragments: A[m=l16][k=quad*8+jj]
  short8 aqw0, aqw1, aqr0, aqr1;
  {
    const ushort* qwp = qw + (((size_t)bn * QLEN) + i0 + l16) * DH + quad * 8;
    const ushort* qrp = qr + (((size_t)bn * QLEN) + i0 + l16) * DH + quad * 8;
    aqw0 = *(const short8*)(qwp);
    aqw1 = *(const short8*)(qwp + 32);
    aqr0 = *(const short8*)(qrp);
    aqr1 = *(const short8*)(qrp + 32);
  }

  float4_ O[4];
#pragma unroll
  for (int t = 0; t < 4; ++t) O[t] = float4_{0.f, 0.f, 0.f, 0.f};
  float mrow[4] = {-INFINITY, -INFINITY, -INFINITY, -INFINITY};
  float lpart[4] = {0.f, 0.f, 0.f, 0.f};  // per-lane partial sums
  const float SL2E = SCALE * 1.44269504088896f;  // scores in exp2 domain

  const int jmax = i0 + 15 + MLEN;  // inclusive last key for any row in tile
  // wave wv's first chunk j0 = wv*32 <= 96 < 1024 is unmasked for ALL rows,
  // so mrow becomes finite on the first iteration.
  for (int j0 = wv * 32; j0 <= jmax; j0 += 128) {
    const int tb = j0 - i0 + 1008;  // >= 0 always
    // ---- D band (48 wide): diagonal-shifted store, stride 66 ----
#pragma unroll
    for (int tt = 0; tt < 3; ++tt) {
      int t = tb + tt * 16 + l16;
      t = (t > KLEN - 1) ? (KLEN - 1) : t;  // clamped region is masked anyway
      const ushort* rp = Rk + (size_t)t * DH + quad * 8;
      short8 b0 = *(const short8*)rp;
      short8 b1 = *(const short8*)(rp + 32);
      float4_ d = {0.f, 0.f, 0.f, 0.f};
      d = __builtin_amdgcn_mfma_f32_16x16x32_bf16(aqr0, b0, d, 0, 0, 0);
      d = __builtin_amdgcn_mfma_f32_16x16x32_bf16(aqr1, b1, d, 0, 0, 0);
#pragma unroll
      for (int rg = 0; rg < 4; ++rg) {
        int row = quad * 4 + rg;
        Dw[row * 66 + tt * 16 + l16 + row] = d[rg];  // D[row][c] at col c+row
      }
    }
    // ---- AC: 2 tiles of 16 keys ----
    float4_ ac[2];
#pragma unroll
    for (int half = 0; half < 2; ++half) {
      int j = j0 + half * 16 + l16;
      int jc = (j > KLEN - 1) ? (KLEN - 1) : j;
      const ushort* kp = Kp + (size_t)jc * DH + quad * 8;
      short8 b0 = *(const short8*)kp;
      short8 b1 = *(const short8*)(kp + 32);
      float4_ c = {0.f, 0.f, 0.f, 0.f};
      c = __builtin_amdgcn_mfma_f32_16x16x32_bf16(aqw0, b0, c, 0, 0, 0);
      c = __builtin_amdgcn_mfma_f32_16x16x32_bf16(aqw1, b1, c, 0, 0, 0);
      ac[half] = c;
    }
    // ---- scores + rel-shift gather (2-way read = free) ----
    float s[2][4];
#pragma unroll
    for (int half = 0; half < 2; ++half) {
#pragma unroll
      for (int rg = 0; rg < 4; ++rg) {
        int row = quad * 4 + rg;
        int jloc = half * 16 + l16;
        int j = j0 + jloc;
        float bd = Dw[row * 66 + jloc + 15];  // = D[row][jloc - row + 15]
        float sv = (ac[half][rg] + bd) * SL2E;
        s[half][rg] = (j > i0 + row + MLEN) ? -INFINITY : sv;
      }
    }
    // ---- online softmax: DPP max, per-lane deferred sum ----
#pragma unroll
    for (int rg = 0; rg < 4; ++rg) {
      float mx = row_max16(fmaxf(s[0][rg], s[1][rg]));
      float mn = fmaxf(mrow[rg], mx);
      float alpha = __builtin_amdgcn_exp2f(mrow[rg] - mn);  // first iter: 0
      float p0 = __builtin_amdgcn_exp2f(s[0][rg] - mn);
      float p1 = __builtin_amdgcn_exp2f(s[1][rg] - mn);
      lpart[rg] = lpart[rg] * alpha + (p0 + p1);
      mrow[rg] = mn;
#pragma unroll
      for (int t = 0; t < 4; ++t) O[t][rg] *= alpha;
      // P in A-frag order: flat = reader_lane*8 + jj
      int row = quad * 4 + rg;
      int idx0 = (l16 >> 3) * 128 + row * 8 + (l16 & 7);  // c = l16
      Pw[idx0] = to_bf16(p0);
      Pw[idx0 + 256] = to_bf16(p1);                        // c = 16 + l16
    }
    // ---- PV: sequential 16B ds_read_b128 per lane ----
    short8 pfrag = *(const short8*)&Pw[lane * 8];
#pragma unroll
    for (int t = 0; t < 4; ++t) {
      const ushort* vp = Vt + (size_t)(t * 16 + l16) * KLEN + j0 + quad * 8;
      short8 vfrag = *(const short8*)vp;  // padded alloc covers tail overread
      O[t] = __builtin_amdgcn_mfma_f32_16x16x32_bf16(pfrag, vfrag, O[t], 0, 0, 0);
    }
  }

  // finalize per-wave l (single cross-lane reduction after the loop)
  float lrow[4];
#pragma unroll
  for (int rg = 0; rg < 4; ++rg) lrow[rg] = row_sum16(lpart[rg]);

  // ---- flash-combine across the 4 waves ----
  __syncthreads();  // all waves done with loop LDS (merge area aliases it)
#pragma unroll
  for (int t = 0; t < 4; ++t)
#pragma unroll
    for (int rg = 0; rg < 4; ++rg)
      sh.mg.O[wv][quad * 4 + rg][t * 16 + l16] = O[t][rg];
  if (l16 == 0) {
#pragma unroll
    for (int rg = 0; rg < 4; ++rg) {
      sh.mg.m[wv][quad * 4 + rg] = mrow[rg];
      sh.mg.l[wv][quad * 4 + rg] = lrow[rg];
    }
  }
  __syncthreads();
  {
    const int row = tid >> 4;          // 0..15
    const int c0 = (tid & 15) * 4;     // 0..60
    float m0v = sh.mg.m[0][row], m1v = sh.mg.m[1][row];
    float m2v = sh.mg.m[2][row], m3v = sh.mg.m[3][row];
    float mstar = fmaxf(fmaxf(m0v, m1v), fmaxf(m2v, m3v));
    float c0w = __builtin_amdgcn_exp2f(m0v - mstar);
    float c1w = __builtin_amdgcn_exp2f(m1v - mstar);
    float c2w = __builtin_amdgcn_exp2f(m2v - mstar);
    float c3w = __builtin_amdgcn_exp2f(m3v - mstar);
    float lstar = c0w * sh.mg.l[0][row] + c1w * sh.mg.l[1][row] +
                  c2w * sh.mg.l[2][row] + c3w * sh.mg.l[3][row];
    float inv = 1.f / lstar;
    ushort4 o4;
    ushort* op = &o4.x;
#pragma unroll
    for (int u = 0; u < 4; ++u) {
      int c = c0 + u;
      float val = (c0w * sh.mg.O[0][row][c] + c1w * sh.mg.O[1][row][c] +
                   c2w * sh.mg.O[2][row][c] + c3w * sh.mg.O[3][row][c]) * inv;
      op[u] = to_bf16(val);
    }
    *reinterpret_cast<ushort4*>(
        &avbf[((size_t)(i0 + row) * BSZ + b) * DM + n * DH + c0]) = o4;
  }
}

extern "C" void kernel_launch(void* const* d_in, const int* in_sizes, int n_in,
                              void* d_out, int out_size, void* d_ws, size_t ws_size,
                              hipStream_t stream) {
  const float* w    = (const float*)d_in[0];
  const float* r    = (const float*)d_in[1];
  const float* rwb  = (const float*)d_in[2];
  const float* rrb  = (const float*)d_in[3];
  const float* mems = (const float*)d_in[4];
  const float* Wq   = (const float*)d_in[5];
  const float* Wkv  = (const float*)d_in[6];
  const float* Wr   = (const float*)d_in[7];
  const float* Wo   = (const float*)d_in[8];
  const float* ln_g = (const float*)d_in[9];
  const float* ln_b = (const float*)d_in[10];
  float* out = (float*)d_out;

  char* p = (char*)d_ws;
  auto alloc = [&](size_t bytes) {
    char* q = p;
    p += (bytes + 255) & ~(size_t)255;
    return q;
  };
  ushort* wbf   = (ushort*)alloc((size_t)QLEN * BSZ * DM * 2);   // 4 MB
  ushort* membf = (ushort*)alloc((size_t)MLEN * BSZ * DM * 2);   // 4 MB
  ushort* rbf   = (ushort*)alloc((size_t)KLEN * DM * 2);
  ushort* WqT   = (ushort*)alloc((size_t)DM * DM * 2);
  ushort* WkvT  = (ushort*)alloc((size_t)2 * DM * DM * 2);
  ushort* WrT   = (ushort*)alloc((size_t)DM * DM * 2);
  ushort* WoT   = (ushort*)alloc((size_t)DM * DM * 2);
  ushort* qw    = (ushort*)alloc((size_t)BSZ * NH * QLEN * DH * 2);
  ushort* qr    = (ushort*)alloc((size_t)BSZ * NH * QLEN * DH * 2);
  ushort* kh    = (ushort*)alloc((size_t)BSZ * NH * KLEN * DH * 2);
  ushort* vrow  = (ushort*)alloc((size_t)BSZ * NH * KLEN * DH * 2);
  ushort* vt    = (ushort*)alloc((size_t)BSZ * NH * DH * KLEN * 2 + 4096);
  ushort* rk    = (ushort*)alloc((size_t)NH * KLEN * DH * 2);
  float*  y     = (float*)alloc((size_t)QLEN * BSZ * DM * 4);    // 8 MB
  // avbf (4 MB bf16) aliases wbf: attn_mfma writes it only after mfma_proj<0/1>
  // (stream-ordered) have consumed wbf. ln_fuse reads the original f32 `w`.
  ushort* avbf = wbf;

  // prep: bf16 activations + transposed bf16 weights
  cvt_bf16<<<dim3(QLEN * BSZ * DM / 1024), dim3(256), 0, stream>>>(w, wbf, QLEN * BSZ * DM);
  cvt_bf16<<<dim3(MLEN * BSZ * DM / 1024), dim3(256), 0, stream>>>(mems, membf, MLEN * BSZ * DM);
  cvt_bf16<<<dim3(KLEN * DM / 1024), dim3(256), 0, stream>>>(r, rbf, KLEN * DM);
  wtrans<<<dim3(16, 16), dim3(256), 0, stream>>>(Wq, WqT, DM);
  wtrans<<<dim3(16, 32), dim3(256), 0, stream>>>(Wkv, WkvT, 2 * DM);
  wtrans<<<dim3(16, 16), dim3(256), 0, stream>>>(Wr, WrT, DM);
  wtrans<<<dim3(16, 16), dim3(256), 0, stream>>>(Wo, WoT, DM);

  // projections (MFMA)
  mfma_proj<0><<<dim3(32, 4), dim3(256), 0, stream>>>(wbf, nullptr, WqT, rwb, rrb, qw, qr);
  mfma_proj<1><<<dim3(64, 8), dim3(256), 0, stream>>>(membf, wbf, WkvT, nullptr, nullptr, kh, vrow);
  mfma_proj<2><<<dim3(16, 4), dim3(256), 0, stream>>>(rbf, nullptr, WrT, nullptr, nullptr, rk, nullptr);
  vtrans<<<dim3(32, 32), dim3(256), 0, stream>>>(vrow, vt);

  attn_mfma<<<dim3(QLEN / 16, NH, BSZ), dim3(256), 0, stream>>>(qw, qr, kh, vt, rk, avbf);

  // output projection + residual LayerNorm
  mfma_out<<<dim3(32, 4), dim3(256), 0, stream>>>(avbf, WoT, y);
  ln_fuse<<<dim3(QLEN * BSZ / 4), dim3(256), 0, stream>>>(y, w, ln_g, ln_b, out);
}

// Round 8
// 371.573 us; speedup vs baseline: 11.0695x; 1.0221x over previous
//
#include <hip/hip_runtime.h>
#include <hip/hip_bf16.h>
#include <math.h>

#define QLEN 1024
#define MLEN 1024
#define KLEN 2048
#define BSZ 4
#define NH 8
#define DH 64
#define DM 512
#define SCALE 0.125f
#define LN_EPS 1e-5f

typedef __attribute__((ext_vector_type(8))) short short8;   // 8 bf16 (4 VGPRs)
typedef __attribute__((ext_vector_type(4))) float float4_;  // MFMA C/D

__device__ inline ushort to_bf16(float x) {
  __hip_bfloat16 h = __float2bfloat16(x);
  return *reinterpret_cast<ushort*>(&h);
}

// 16-lane (row) reductions on the VALU pipe via DPP.
__device__ inline float row_max16(float v) {
  int x = __builtin_bit_cast(int, v);
  v = fmaxf(v, __builtin_bit_cast(float, __builtin_amdgcn_update_dpp(x, x, 0xB1, 0xF, 0xF, false)));
  x = __builtin_bit_cast(int, v);
  v = fmaxf(v, __builtin_bit_cast(float, __builtin_amdgcn_update_dpp(x, x, 0x4E, 0xF, 0xF, false)));
  x = __builtin_bit_cast(int, v);
  v = fmaxf(v, __builtin_bit_cast(float, __builtin_amdgcn_update_dpp(x, x, 0x124, 0xF, 0xF, false)));
  x = __builtin_bit_cast(int, v);
  v = fmaxf(v, __builtin_bit_cast(float, __builtin_amdgcn_update_dpp(x, x, 0x128, 0xF, 0xF, false)));
  return v;
}
__device__ inline float row_sum16(float v) {
  int x = __builtin_bit_cast(int, v);
  v += __builtin_bit_cast(float, __builtin_amdgcn_update_dpp(x, x, 0xB1, 0xF, 0xF, false));
  x = __builtin_bit_cast(int, v);
  v += __builtin_bit_cast(float, __builtin_amdgcn_update_dpp(x, x, 0x4E, 0xF, 0xF, false));
  x = __builtin_bit_cast(int, v);
  v += __builtin_bit_cast(float, __builtin_amdgcn_update_dpp(x, x, 0x124, 0xF, 0xF, false));
  x = __builtin_bit_cast(int, v);
  v += __builtin_bit_cast(float, __builtin_amdgcn_update_dpp(x, x, 0x128, 0xF, 0xF, false));
  return v;
}

// ---------------------------------------------------------------------------
// f32 -> bf16 flat convert (4 elements/thread).
// ---------------------------------------------------------------------------
__global__ __launch_bounds__(256) void cvt_bf16(const float* __restrict__ src,
                                                ushort* __restrict__ dst, int n) {
  int i = (blockIdx.x * 256 + threadIdx.x) * 4;
  if (i >= n) return;
  float4 v = *reinterpret_cast<const float4*>(src + i);
  ushort4 o;
  o.x = to_bf16(v.x); o.y = to_bf16(v.y); o.z = to_bf16(v.z); o.w = to_bf16(v.w);
  *reinterpret_cast<ushort4*>(dst + i) = o;
}

// ---------------------------------------------------------------------------
// Weight transpose+convert: W[512][N] f32 -> WT[N][512] bf16. 32x32 LDS tiles.
// ---------------------------------------------------------------------------
__global__ __launch_bounds__(256) void wtrans(const float* __restrict__ W,
                                              ushort* __restrict__ WT, int N) {
  __shared__ ushort tile[32][33];
  const int k0 = blockIdx.x * 32, n0 = blockIdx.y * 32;
  const int tid = threadIdx.x;
#pragma unroll
  for (int it = 0; it < 4; ++it) {
    int idx = tid + it * 256;
    int r = idx >> 5, c = idx & 31;
    tile[r][c] = to_bf16(W[(size_t)(k0 + r) * N + n0 + c]);
  }
  __syncthreads();
#pragma unroll
  for (int it = 0; it < 4; ++it) {
    int idx = tid + it * 256;
    int r = idx >> 5, c = idx & 31;
    WT[(size_t)(n0 + r) * DM + k0 + c] = tile[c][r];
  }
}

// ---------------------------------------------------------------------------
// V transpose: vrow[bn][j][d] -> vt[bn][d][j]. 64x64 LDS tiles.
// ---------------------------------------------------------------------------
__global__ __launch_bounds__(256) void vtrans(const ushort* __restrict__ vrow,
                                              ushort* __restrict__ vt) {
  __shared__ ushort t[64][65];
  const int j0 = blockIdx.x * 64;
  const int bn = blockIdx.y;
  const int tid = threadIdx.x;
  const ushort* src = vrow + (size_t)bn * KLEN * DH;
  ushort* dst = vt + (size_t)bn * DH * KLEN;
#pragma unroll
  for (int it = 0; it < 16; ++it) {
    int idx = tid + it * 256;
    int r = idx >> 6, c = idx & 63;
    t[r][c] = src[(size_t)(j0 + r) * DH + c];
  }
  __syncthreads();
#pragma unroll
  for (int it = 0; it < 16; ++it) {
    int idx = tid + it * 256;
    int d = idx >> 6, jj = idx & 63;
    dst[(size_t)d * KLEN + j0 + jj] = t[jj][d];
  }
}

// ---------------------------------------------------------------------------
// MFMA projection GEMM. C[M,N] = A[M,512] @ W[512,N] with WT[N][512] bf16.
// Block tile 128x128, 4 waves (2x2) x 64x64 wave tile, BK=32, 16x16x32 bf16.
// ---------------------------------------------------------------------------
template <int MODE>
__global__ __launch_bounds__(256) void mfma_proj(
    const ushort* __restrict__ A0, const ushort* __restrict__ A1,
    const ushort* __restrict__ BT,
    const float* __restrict__ bias0, const float* __restrict__ bias1,
    ushort* __restrict__ O0, ushort* __restrict__ O1) {
  __shared__ ushort As[128 * 32];
  __shared__ ushort Bs[128 * 32];
  const int tid = threadIdx.x;
  const int m0 = blockIdx.x * 128, n0 = blockIdx.y * 128;
  const int wv = tid >> 6, lane = tid & 63;
  const int wm = wv >> 1, wn = wv & 1;
  const int l16 = lane & 15, quad = lane >> 4;

  const int arow = tid >> 1;            // 0..127
  const int acol = (tid & 1) * 16;      // 0 or 16 (ushort index)
  const ushort* asrc;
  {
    int m = m0 + arow;
    if (MODE == 1)
      asrc = (m < QLEN * BSZ) ? A0 + (size_t)m * DM : A1 + (size_t)(m - QLEN * BSZ) * DM;
    else
      asrc = A0 + (size_t)m * DM;
    asrc += acol;
  }
  const ushort* bsrc = BT + (size_t)(n0 + arow) * DM + acol;

  float4_ acc[4][4];
#pragma unroll
  for (int a = 0; a < 4; ++a)
#pragma unroll
    for (int b = 0; b < 4; ++b) acc[a][b] = float4_{0.f, 0.f, 0.f, 0.f};

  for (int k0 = 0; k0 < DM; k0 += 32) {
    *reinterpret_cast<uint4*>(&As[arow * 32 + acol]) =
        *reinterpret_cast<const uint4*>(asrc + k0);
    *reinterpret_cast<uint4*>(&As[arow * 32 + acol + 8]) =
        *reinterpret_cast<const uint4*>(asrc + k0 + 8);
    *reinterpret_cast<uint4*>(&Bs[arow * 32 + acol]) =
        *reinterpret_cast<const uint4*>(bsrc + k0);
    *reinterpret_cast<uint4*>(&Bs[arow * 32 + acol + 8]) =
        *reinterpret_cast<const uint4*>(bsrc + k0 + 8);
    __syncthreads();
    short8 af[4], bf[4];
#pragma unroll
    for (int f = 0; f < 4; ++f) {
      af[f] = *reinterpret_cast<const short8*>(&As[(wm * 64 + f * 16 + l16) * 32 + quad * 8]);
      bf[f] = *reinterpret_cast<const short8*>(&Bs[(wn * 64 + f * 16 + l16) * 32 + quad * 8]);
    }
#pragma unroll
    for (int fm = 0; fm < 4; ++fm)
#pragma unroll
      for (int fn = 0; fn < 4; ++fn)
        acc[fm][fn] = __builtin_amdgcn_mfma_f32_16x16x32_bf16(af[fm], bf[fn], acc[fm][fn], 0, 0, 0);
    __syncthreads();
  }

#pragma unroll
  for (int fm = 0; fm < 4; ++fm) {
#pragma unroll
    for (int fn = 0; fn < 4; ++fn) {
#pragma unroll
      for (int reg = 0; reg < 4; ++reg) {
        int mm = m0 + wm * 64 + fm * 16 + quad * 4 + reg;
        int nn = n0 + wn * 64 + fn * 16 + l16;
        float v = acc[fm][fn][reg];
        if (MODE == 0) {
          int i = mm >> 2, b = mm & 3;
          int n = nn >> 6, d = nn & 63;
          size_t idx = (((size_t)(b * NH + n)) * QLEN + i) * DH + d;
          O0[idx] = to_bf16(v + bias0[nn]);
          O1[idx] = to_bf16(v + bias1[nn]);
        } else if (MODE == 1) {
          int pos = mm >> 2, b = mm & 3;
          int nn2 = nn & 511;
          int n = nn2 >> 6, d = nn2 & 63;
          size_t idx = (((size_t)(b * NH + n)) * KLEN + pos) * DH + d;
          if (nn < DM) O0[idx] = to_bf16(v);
          else         O1[idx] = to_bf16(v);
        } else {
          int n = nn >> 6, d = nn & 63;
          O0[((size_t)n * KLEN + mm) * DH + d] = to_bf16(v);
        }
      }
    }
  }
}

// ---------------------------------------------------------------------------
// Output GEMM: y[4096x512] = avbf @ WoT (f32 out).
// ---------------------------------------------------------------------------
__global__ __launch_bounds__(256) void mfma_out(
    const ushort* __restrict__ A, const ushort* __restrict__ BT,
    float* __restrict__ Y) {
  __shared__ ushort As[128 * 32];
  __shared__ ushort Bs[128 * 32];
  const int tid = threadIdx.x;
  const int m0 = blockIdx.x * 128, n0 = blockIdx.y * 128;
  const int wv = tid >> 6, lane = tid & 63;
  const int wm = wv >> 1, wn = wv & 1;
  const int l16 = lane & 15, quad = lane >> 4;
  const int arow = tid >> 1;
  const int acol = (tid & 1) * 16;
  const ushort* asrc = A + (size_t)(m0 + arow) * DM + acol;
  const ushort* bsrc = BT + (size_t)(n0 + arow) * DM + acol;

  float4_ acc[4][4];
#pragma unroll
  for (int a = 0; a < 4; ++a)
#pragma unroll
    for (int b = 0; b < 4; ++b) acc[a][b] = float4_{0.f, 0.f, 0.f, 0.f};

  for (int k0 = 0; k0 < DM; k0 += 32) {
    *reinterpret_cast<uint4*>(&As[arow * 32 + acol]) = *reinterpret_cast<const uint4*>(asrc + k0);
    *reinterpret_cast<uint4*>(&As[arow * 32 + acol + 8]) = *reinterpret_cast<const uint4*>(asrc + k0 + 8);
    *reinterpret_cast<uint4*>(&Bs[arow * 32 + acol]) = *reinterpret_cast<const uint4*>(bsrc + k0);
    *reinterpret_cast<uint4*>(&Bs[arow * 32 + acol + 8]) = *reinterpret_cast<const uint4*>(bsrc + k0 + 8);
    __syncthreads();
    short8 af[4], bf[4];
#pragma unroll
    for (int f = 0; f < 4; ++f) {
      af[f] = *reinterpret_cast<const short8*>(&As[(wm * 64 + f * 16 + l16) * 32 + quad * 8]);
      bf[f] = *reinterpret_cast<const short8*>(&Bs[(wn * 64 + f * 16 + l16) * 32 + quad * 8]);
    }
#pragma unroll
    for (int fm = 0; fm < 4; ++fm)
#pragma unroll
      for (int fn = 0; fn < 4; ++fn)
        acc[fm][fn] = __builtin_amdgcn_mfma_f32_16x16x32_bf16(af[fm], bf[fn], acc[fm][fn], 0, 0, 0);
    __syncthreads();
  }
#pragma unroll
  for (int fm = 0; fm < 4; ++fm)
#pragma unroll
    for (int fn = 0; fn < 4; ++fn)
#pragma unroll
      for (int reg = 0; reg < 4; ++reg) {
        int mm = m0 + wm * 64 + fm * 16 + quad * 4 + reg;
        int nn = n0 + wn * 64 + fn * 16 + l16;
        Y[(size_t)mm * DM + nn] = acc[fm][fn][reg];
      }
}

// ---------------------------------------------------------------------------
// Residual + LayerNorm: one wave per row (8 cols/lane).
// ---------------------------------------------------------------------------
__global__ __launch_bounds__(256) void ln_fuse(
    const float* __restrict__ y, const float* __restrict__ wres,
    const float* __restrict__ g, const float* __restrict__ bb,
    float* __restrict__ out) {
  const int row = blockIdx.x * 4 + (threadIdx.x >> 6);
  const int lane = threadIdx.x & 63;
  const float* yr = y + (size_t)row * DM + lane * 4;
  const float* wr = wres + (size_t)row * DM + lane * 4;
  float4 x0 = *(const float4*)yr;
  float4 x1 = *(const float4*)(yr + 256);
  float4 w0 = *(const float4*)wr;
  float4 w1 = *(const float4*)(wr + 256);
  x0.x += w0.x; x0.y += w0.y; x0.z += w0.z; x0.w += w0.w;
  x1.x += w1.x; x1.y += w1.y; x1.z += w1.z; x1.w += w1.w;
  float s = x0.x + x0.y + x0.z + x0.w + x1.x + x1.y + x1.z + x1.w;
  float ss = x0.x * x0.x + x0.y * x0.y + x0.z * x0.z + x0.w * x0.w +
             x1.x * x1.x + x1.y * x1.y + x1.z * x1.z + x1.w * x1.w;
#pragma unroll
  for (int off = 1; off <= 32; off <<= 1) {
    s += __shfl_xor(s, off, 64);
    ss += __shfl_xor(ss, off, 64);
  }
  float mu = s * (1.f / DM);
  float var = ss * (1.f / DM) - mu * mu;
  float rstd = rsqrtf(var + LN_EPS);
  float4 g0 = *(const float4*)(g + lane * 4);
  float4 g1 = *(const float4*)(g + lane * 4 + 256);
  float4 b0 = *(const float4*)(bb + lane * 4);
  float4 b1 = *(const float4*)(bb + lane * 4 + 256);
  float4 o0, o1;
  o0.x = (x0.x - mu) * rstd * g0.x + b0.x;
  o0.y = (x0.y - mu) * rstd * g0.y + b0.y;
  o0.z = (x0.z - mu) * rstd * g0.z + b0.z;
  o0.w = (x0.w - mu) * rstd * g0.w + b0.w;
  o1.x = (x1.x - mu) * rstd * g1.x + b1.x;
  o1.y = (x1.y - mu) * rstd * g1.y + b1.y;
  o1.z = (x1.z - mu) * rstd * g1.z + b1.z;
  o1.w = (x1.w - mu) * rstd * g1.w + b1.w;
  float* orow = out + (size_t)row * DM + lane * 4;
  *reinterpret_cast<float4*>(orow) = o0;
  *reinterpret_cast<float4*>(orow + 256) = o1;
}

// ---------------------------------------------------------------------------
// MFMA flash attention, 4 waves/block on ONE 16-row Q tile, j-split x4.
// launch_bounds(256,2): <=128 VGPR so all 14 global loads/iter stay in
// flight (VGPR=64 serialized them -> the round-5..7 latency wall).
// Each iteration: explicit load phase (R x6, K x4, V x4 b128 loads into
// registers), then compute phase.
// ---------------------------------------------------------------------------
__global__ __launch_bounds__(256, 2) void attn_mfma(
    const ushort* __restrict__ qw, const ushort* __restrict__ qr,
    const ushort* __restrict__ kh, const ushort* __restrict__ vt,
    const ushort* __restrict__ rk, ushort* __restrict__ avbf) {
  const int i0 = (gridDim.x - 1 - blockIdx.x) * 16;  // longest blocks first
  const int n = blockIdx.y, b = blockIdx.z;
  const int bn = b * NH + n;
  const int tid = threadIdx.x;
  const int wv = tid >> 6;
  const int lane = tid & 63;
  const int l16 = lane & 15, quad = lane >> 4;

  union SharedU {
    struct { float D[4][16 * 66]; ushort P[4][16 * 32]; } loop;
    struct { float O[4][16][64]; float m[4][16]; float l[4][16]; } mg;
  };
  __shared__ SharedU sh;
  float* __restrict__ Dw = sh.loop.D[wv];
  ushort* __restrict__ Pw = sh.loop.P[wv];

  const ushort* __restrict__ Kp = kh + (size_t)bn * KLEN * DH;
  const ushort* __restrict__ Vt = vt + (size_t)bn * DH * KLEN;
  const ushort* __restrict__ Rk = rk + (size_t)n * KLEN * DH;

  // A-layout Q fragments: A[m=l16][k=quad*8+jj]
  short8 aqw0, aqw1, aqr0, aqr1;
  {
    const ushort* qwp = qw + (((size_t)bn * QLEN) + i0 + l16) * DH + quad * 8;
    const ushort* qrp = qr + (((size_t)bn * QLEN) + i0 + l16) * DH + quad * 8;
    aqw0 = *(const short8*)(qwp);
    aqw1 = *(const short8*)(qwp + 32);
    aqr0 = *(const short8*)(qrp);
    aqr1 = *(const short8*)(qrp + 32);
  }

  float4_ O[4];
#pragma unroll
  for (int t = 0; t < 4; ++t) O[t] = float4_{0.f, 0.f, 0.f, 0.f};
  float mrow[4] = {-INFINITY, -INFINITY, -INFINITY, -INFINITY};
  float lpart[4] = {0.f, 0.f, 0.f, 0.f};  // per-lane partial sums
  const float SL2E = SCALE * 1.44269504088896f;  // scores in exp2 domain

  const int jmax = i0 + 15 + MLEN;  // inclusive last key for any row in tile
  // wave wv's first chunk j0 = wv*32 <= 96 < 1024 is unmasked for ALL rows,
  // so mrow becomes finite on the first iteration.
  for (int j0 = wv * 32; j0 <= jmax; j0 += 128) {
    const int tb = j0 - i0 + 1008;  // >= 0 always
    // ================= LOAD PHASE: 14 x b128, no uses =================
    short8 rf[3][2];
#pragma unroll
    for (int tt = 0; tt < 3; ++tt) {
      int t = tb + tt * 16 + l16;
      t = (t > KLEN - 1) ? (KLEN - 1) : t;  // clamped region is masked anyway
      const ushort* rp = Rk + (size_t)t * DH + quad * 8;
      rf[tt][0] = *(const short8*)rp;
      rf[tt][1] = *(const short8*)(rp + 32);
    }
    short8 kf[2][2];
#pragma unroll
    for (int half = 0; half < 2; ++half) {
      int j = j0 + half * 16 + l16;
      int jc = (j > KLEN - 1) ? (KLEN - 1) : j;
      const ushort* kp = Kp + (size_t)jc * DH + quad * 8;
      kf[half][0] = *(const short8*)kp;
      kf[half][1] = *(const short8*)(kp + 32);
    }
    short8 vf[4];
#pragma unroll
    for (int t = 0; t < 4; ++t)
      vf[t] = *(const short8*)(Vt + (size_t)(t * 16 + l16) * KLEN + j0 + quad * 8);

    // ================= COMPUTE PHASE =================
    // ---- D band (48 wide): diagonal-shifted store, stride 66 ----
#pragma unroll
    for (int tt = 0; tt < 3; ++tt) {
      float4_ d = {0.f, 0.f, 0.f, 0.f};
      d = __builtin_amdgcn_mfma_f32_16x16x32_bf16(aqr0, rf[tt][0], d, 0, 0, 0);
      d = __builtin_amdgcn_mfma_f32_16x16x32_bf16(aqr1, rf[tt][1], d, 0, 0, 0);
#pragma unroll
      for (int rg = 0; rg < 4; ++rg) {
        int row = quad * 4 + rg;
        Dw[row * 66 + tt * 16 + l16 + row] = d[rg];  // D[row][c] at col c+row
      }
    }
    // ---- AC: 2 tiles of 16 keys ----
    float4_ ac[2];
#pragma unroll
    for (int half = 0; half < 2; ++half) {
      float4_ c = {0.f, 0.f, 0.f, 0.f};
      c = __builtin_amdgcn_mfma_f32_16x16x32_bf16(aqw0, kf[half][0], c, 0, 0, 0);
      c = __builtin_amdgcn_mfma_f32_16x16x32_bf16(aqw1, kf[half][1], c, 0, 0, 0);
      ac[half] = c;
    }
    // ---- scores + rel-shift gather (2-way read = free) ----
    float s[2][4];
#pragma unroll
    for (int half = 0; half < 2; ++half) {
#pragma unroll
      for (int rg = 0; rg < 4; ++rg) {
        int row = quad * 4 + rg;
        int jloc = half * 16 + l16;
        int j = j0 + jloc;
        float bd = Dw[row * 66 + jloc + 15];  // = D[row][jloc - row + 15]
        float sv = (ac[half][rg] + bd) * SL2E;
        s[half][rg] = (j > i0 + row + MLEN) ? -INFINITY : sv;
      }
    }
    // ---- online softmax: DPP max, per-lane deferred sum ----
#pragma unroll
    for (int rg = 0; rg < 4; ++rg) {
      float mx = row_max16(fmaxf(s[0][rg], s[1][rg]));
      float mn = fmaxf(mrow[rg], mx);
      float alpha = __builtin_amdgcn_exp2f(mrow[rg] - mn);  // first iter: 0
      float p0 = __builtin_amdgcn_exp2f(s[0][rg] - mn);
      float p1 = __builtin_amdgcn_exp2f(s[1][rg] - mn);
      lpart[rg] = lpart[rg] * alpha + (p0 + p1);
      mrow[rg] = mn;
#pragma unroll
      for (int t = 0; t < 4; ++t) O[t][rg] *= alpha;
      // P in A-frag order: flat = reader_lane*8 + jj
      int row = quad * 4 + rg;
      int idx0 = (l16 >> 3) * 128 + row * 8 + (l16 & 7);  // c = l16
      Pw[idx0] = to_bf16(p0);
      Pw[idx0 + 256] = to_bf16(p1);                        // c = 16 + l16
    }
    // ---- PV: sequential 16B ds_read_b128 per lane ----
    short8 pfrag = *(const short8*)&Pw[lane * 8];
#pragma unroll
    for (int t = 0; t < 4; ++t)
      O[t] = __builtin_amdgcn_mfma_f32_16x16x32_bf16(pfrag, vf[t], O[t], 0, 0, 0);
  }

  // finalize per-wave l (single cross-lane reduction after the loop)
  float lrow[4];
#pragma unroll
  for (int rg = 0; rg < 4; ++rg) lrow[rg] = row_sum16(lpart[rg]);

  // ---- flash-combine across the 4 waves ----
  __syncthreads();  // all waves done with loop LDS (merge area aliases it)
#pragma unroll
  for (int t = 0; t < 4; ++t)
#pragma unroll
    for (int rg = 0; rg < 4; ++rg)
      sh.mg.O[wv][quad * 4 + rg][t * 16 + l16] = O[t][rg];
  if (l16 == 0) {
#pragma unroll
    for (int rg = 0; rg < 4; ++rg) {
      sh.mg.m[wv][quad * 4 + rg] = mrow[rg];
      sh.mg.l[wv][quad * 4 + rg] = lrow[rg];
    }
  }
  __syncthreads();
  {
    const int row = tid >> 4;          // 0..15
    const int c0 = (tid & 15) * 4;     // 0..60
    float m0v = sh.mg.m[0][row], m1v = sh.mg.m[1][row];
    float m2v = sh.mg.m[2][row], m3v = sh.mg.m[3][row];
    float mstar = fmaxf(fmaxf(m0v, m1v), fmaxf(m2v, m3v));
    float c0w = __builtin_amdgcn_exp2f(m0v - mstar);
    float c1w = __builtin_amdgcn_exp2f(m1v - mstar);
    float c2w = __builtin_amdgcn_exp2f(m2v - mstar);
    float c3w = __builtin_amdgcn_exp2f(m3v - mstar);
    float lstar = c0w * sh.mg.l[0][row] + c1w * sh.mg.l[1][row] +
                  c2w * sh.mg.l[2][row] + c3w * sh.mg.l[3][row];
    float inv = 1.f / lstar;
    ushort4 o4;
    ushort* op = &o4.x;
#pragma unroll
    for (int u = 0; u < 4; ++u) {
      int c = c0 + u;
      float val = (c0w * sh.mg.O[0][row][c] + c1w * sh.mg.O[1][row][c] +
                   c2w * sh.mg.O[2][row][c] + c3w * sh.mg.O[3][row][c]) * inv;
      op[u] = to_bf16(val);
    }
    *reinterpret_cast<ushort4*>(
        &avbf[((size_t)(i0 + row) * BSZ + b) * DM + n * DH + c0]) = o4;
  }
}

extern "C" void kernel_launch(void* const* d_in, const int* in_sizes, int n_in,
                              void* d_out, int out_size, void* d_ws, size_t ws_size,
                              hipStream_t stream) {
  const float* w    = (const float*)d_in[0];
  const float* r    = (const float*)d_in[1];
  const float* rwb  = (const float*)d_in[2];
  const float* rrb  = (const float*)d_in[3];
  const float* mems = (const float*)d_in[4];
  const float* Wq   = (const float*)d_in[5];
  const float* Wkv  = (const float*)d_in[6];
  const float* Wr   = (const float*)d_in[7];
  const float* Wo   = (const float*)d_in[8];
  const float* ln_g = (const float*)d_in[9];
  const float* ln_b = (const float*)d_in[10];
  float* out = (float*)d_out;

  char* p = (char*)d_ws;
  auto alloc = [&](size_t bytes) {
    char* q = p;
    p += (bytes + 255) & ~(size_t)255;
    return q;
  };
  ushort* wbf   = (ushort*)alloc((size_t)QLEN * BSZ * DM * 2);   // 4 MB
  ushort* membf = (ushort*)alloc((size_t)MLEN * BSZ * DM * 2);   // 4 MB
  ushort* rbf   = (ushort*)alloc((size_t)KLEN * DM * 2);
  ushort* WqT   = (ushort*)alloc((size_t)DM * DM * 2);
  ushort* WkvT  = (ushort*)alloc((size_t)2 * DM * DM * 2);
  ushort* WrT   = (ushort*)alloc((size_t)DM * DM * 2);
  ushort* WoT   = (ushort*)alloc((size_t)DM * DM * 2);
  ushort* qw    = (ushort*)alloc((size_t)BSZ * NH * QLEN * DH * 2);
  ushort* qr    = (ushort*)alloc((size_t)BSZ * NH * QLEN * DH * 2);
  ushort* kh    = (ushort*)alloc((size_t)BSZ * NH * KLEN * DH * 2);
  ushort* vrow  = (ushort*)alloc((size_t)BSZ * NH * KLEN * DH * 2);
  ushort* vt    = (ushort*)alloc((size_t)BSZ * NH * DH * KLEN * 2 + 4096);
  ushort* rk    = (ushort*)alloc((size_t)NH * KLEN * DH * 2);
  float*  y     = (float*)alloc((size_t)QLEN * BSZ * DM * 4);    // 8 MB
  // avbf (4 MB bf16) aliases wbf: attn_mfma writes it only after mfma_proj<0/1>
  // (stream-ordered) have consumed wbf. ln_fuse reads the original f32 `w`.
  ushort* avbf = wbf;

  // prep: bf16 activations + transposed bf16 weights
  cvt_bf16<<<dim3(QLEN * BSZ * DM / 1024), dim3(256), 0, stream>>>(w, wbf, QLEN * BSZ * DM);
  cvt_bf16<<<dim3(MLEN * BSZ * DM / 1024), dim3(256), 0, stream>>>(mems, membf, MLEN * BSZ * DM);
  cvt_bf16<<<dim3(KLEN * DM / 1024), dim3(256), 0, stream>>>(r, rbf, KLEN * DM);
  wtrans<<<dim3(16, 16), dim3(256), 0, stream>>>(Wq, WqT, DM);
  wtrans<<<dim3(16, 32), dim3(256), 0, stream>>>(Wkv, WkvT, 2 * DM);
  wtrans<<<dim3(16, 16), dim3(256), 0, stream>>>(Wr, WrT, DM);
  wtrans<<<dim3(16, 16), dim3(256), 0, stream>>>(Wo, WoT, DM);

  // projections (MFMA)
  mfma_proj<0><<<dim3(32, 4), dim3(256), 0, stream>>>(wbf, nullptr, WqT, rwb, rrb, qw, qr);
  mfma_proj<1><<<dim3(64, 8), dim3(256), 0, stream>>>(membf, wbf, WkvT, nullptr, nullptr, kh, vrow);
  mfma_proj<2><<<dim3(16, 4), dim3(256), 0, stream>>>(rbf, nullptr, WrT, nullptr, nullptr, rk, nullptr);
  vtrans<<<dim3(32, 32), dim3(256), 0, stream>>>(vrow, vt);

  attn_mfma<<<dim3(QLEN / 16, NH, BSZ), dim3(256), 0, stream>>>(qw, qr, kh, vt, rk, avbf);

  // output projection + residual LayerNorm
  mfma_out<<<dim3(32, 4), dim3(256), 0, stream>>>(avbf, WoT, y);
  ln_fuse<<<dim3(QLEN * BSZ / 4), dim3(256), 0, stream>>>(y, w, ln_g, ln_b, out);
}

// Round 9
// 272.233 us; speedup vs baseline: 15.1089x; 1.3649x over previous
//
#include <hip/hip_runtime.h>
#include <hip/hip_bf16.h>
#include <math.h>

#define QLEN 1024
#define MLEN 1024
#define KLEN 2048
#define BSZ 4
#define NH 8
#define DH 64
#define DM 512
#define SCALE 0.125f
#define LN_EPS 1e-5f

#define RK_ROWS 2112   // KLEN + 64 pad rows (t>=2048 only feeds masked scores)

typedef __attribute__((ext_vector_type(8))) short short8;   // 8 bf16 (4 VGPRs)
typedef __attribute__((ext_vector_type(4))) float float4_;  // MFMA C/D

#define GLB(p) ((const __attribute__((address_space(1))) void*)(p))
#define LDSP(p) ((__attribute__((address_space(3))) void*)(p))

__device__ inline ushort to_bf16(float x) {
  __hip_bfloat16 h = __float2bfloat16(x);
  return *reinterpret_cast<ushort*>(&h);
}

// 16-lane (row) reductions on the VALU pipe via DPP.
__device__ inline float row_max16(float v) {
  int x = __builtin_bit_cast(int, v);
  v = fmaxf(v, __builtin_bit_cast(float, __builtin_amdgcn_update_dpp(x, x, 0xB1, 0xF, 0xF, false)));
  x = __builtin_bit_cast(int, v);
  v = fmaxf(v, __builtin_bit_cast(float, __builtin_amdgcn_update_dpp(x, x, 0x4E, 0xF, 0xF, false)));
  x = __builtin_bit_cast(int, v);
  v = fmaxf(v, __builtin_bit_cast(float, __builtin_amdgcn_update_dpp(x, x, 0x124, 0xF, 0xF, false)));
  x = __builtin_bit_cast(int, v);
  v = fmaxf(v, __builtin_bit_cast(float, __builtin_amdgcn_update_dpp(x, x, 0x128, 0xF, 0xF, false)));
  return v;
}
__device__ inline float row_sum16(float v) {
  int x = __builtin_bit_cast(int, v);
  v += __builtin_bit_cast(float, __builtin_amdgcn_update_dpp(x, x, 0xB1, 0xF, 0xF, false));
  x = __builtin_bit_cast(int, v);
  v += __builtin_bit_cast(float, __builtin_amdgcn_update_dpp(x, x, 0x4E, 0xF, 0xF, false));
  x = __builtin_bit_cast(int, v);
  v += __builtin_bit_cast(float, __builtin_amdgcn_update_dpp(x, x, 0x124, 0xF, 0xF, false));
  x = __builtin_bit_cast(int, v);
  v += __builtin_bit_cast(float, __builtin_amdgcn_update_dpp(x, x, 0x128, 0xF, 0xF, false));
  return v;
}

// ---------------------------------------------------------------------------
// f32 -> bf16 flat convert.
// ---------------------------------------------------------------------------
__global__ __launch_bounds__(256) void cvt_bf16(const float* __restrict__ src,
                                                ushort* __restrict__ dst, int n) {
  int i = (blockIdx.x * 256 + threadIdx.x) * 4;
  if (i >= n) return;
  float4 v = *reinterpret_cast<const float4*>(src + i);
  ushort4 o;
  o.x = to_bf16(v.x); o.y = to_bf16(v.y); o.z = to_bf16(v.z); o.w = to_bf16(v.w);
  *reinterpret_cast<ushort4*>(dst + i) = o;
}

// ---------------------------------------------------------------------------
// Weight transpose+convert: W[512][N] f32 -> WT[N][512] bf16.
// ---------------------------------------------------------------------------
__global__ __launch_bounds__(256) void wtrans(const float* __restrict__ W,
                                              ushort* __restrict__ WT, int N) {
  __shared__ ushort tile[32][33];
  const int k0 = blockIdx.x * 32, n0 = blockIdx.y * 32;
  const int tid = threadIdx.x;
#pragma unroll
  for (int it = 0; it < 4; ++it) {
    int idx = tid + it * 256;
    int r = idx >> 5, c = idx & 31;
    tile[r][c] = to_bf16(W[(size_t)(k0 + r) * N + n0 + c]);
  }
  __syncthreads();
#pragma unroll
  for (int it = 0; it < 4; ++it) {
    int idx = tid + it * 256;
    int r = idx >> 5, c = idx & 31;
    WT[(size_t)(n0 + r) * DM + k0 + c] = tile[c][r];
  }
}

// ---------------------------------------------------------------------------
// MFMA projection GEMM (as r8). MODE 2 epilogue now writes the XOR-swizzled
// rk2[n][t][ (cb ^ (t&7))*8 + (d&7) ] with RK_ROWS rows (pad rows = poison,
// finite bf16, only ever feeds masked scores).
// ---------------------------------------------------------------------------
template <int MODE>
__global__ __launch_bounds__(256) void mfma_proj(
    const ushort* __restrict__ A0, const ushort* __restrict__ A1,
    const ushort* __restrict__ BT,
    const float* __restrict__ bias0, const float* __restrict__ bias1,
    ushort* __restrict__ O0, ushort* __restrict__ O1) {
  __shared__ ushort As[128 * 32];
  __shared__ ushort Bs[128 * 32];
  const int tid = threadIdx.x;
  const int m0 = blockIdx.x * 128, n0 = blockIdx.y * 128;
  const int wv = tid >> 6, lane = tid & 63;
  const int wm = wv >> 1, wn = wv & 1;
  const int l16 = lane & 15, quad = lane >> 4;

  const int arow = tid >> 1;
  const int acol = (tid & 1) * 16;
  const ushort* asrc;
  {
    int m = m0 + arow;
    if (MODE == 1)
      asrc = (m < QLEN * BSZ) ? A0 + (size_t)m * DM : A1 + (size_t)(m - QLEN * BSZ) * DM;
    else
      asrc = A0 + (size_t)m * DM;
    asrc += acol;
  }
  const ushort* bsrc = BT + (size_t)(n0 + arow) * DM + acol;

  float4_ acc[4][4];
#pragma unroll
  for (int a = 0; a < 4; ++a)
#pragma unroll
    for (int b = 0; b < 4; ++b) acc[a][b] = float4_{0.f, 0.f, 0.f, 0.f};

  for (int k0 = 0; k0 < DM; k0 += 32) {
    *reinterpret_cast<uint4*>(&As[arow * 32 + acol]) =
        *reinterpret_cast<const uint4*>(asrc + k0);
    *reinterpret_cast<uint4*>(&As[arow * 32 + acol + 8]) =
        *reinterpret_cast<const uint4*>(asrc + k0 + 8);
    *reinterpret_cast<uint4*>(&Bs[arow * 32 + acol]) =
        *reinterpret_cast<const uint4*>(bsrc + k0);
    *reinterpret_cast<uint4*>(&Bs[arow * 32 + acol + 8]) =
        *reinterpret_cast<const uint4*>(bsrc + k0 + 8);
    __syncthreads();
    short8 af[4], bf[4];
#pragma unroll
    for (int f = 0; f < 4; ++f) {
      af[f] = *reinterpret_cast<const short8*>(&As[(wm * 64 + f * 16 + l16) * 32 + quad * 8]);
      bf[f] = *reinterpret_cast<const short8*>(&Bs[(wn * 64 + f * 16 + l16) * 32 + quad * 8]);
    }
#pragma unroll
    for (int fm = 0; fm < 4; ++fm)
#pragma unroll
      for (int fn = 0; fn < 4; ++fn)
        acc[fm][fn] = __builtin_amdgcn_mfma_f32_16x16x32_bf16(af[fm], bf[fn], acc[fm][fn], 0, 0, 0);
    __syncthreads();
  }

#pragma unroll
  for (int fm = 0; fm < 4; ++fm) {
#pragma unroll
    for (int fn = 0; fn < 4; ++fn) {
#pragma unroll
      for (int reg = 0; reg < 4; ++reg) {
        int mm = m0 + wm * 64 + fm * 16 + quad * 4 + reg;
        int nn = n0 + wn * 64 + fn * 16 + l16;
        float v = acc[fm][fn][reg];
        if (MODE == 0) {
          int i = mm >> 2, b = mm & 3;
          int n = nn >> 6, d = nn & 63;
          size_t idx = (((size_t)(b * NH + n)) * QLEN + i) * DH + d;
          O0[idx] = to_bf16(v + bias0[nn]);
          O1[idx] = to_bf16(v + bias1[nn]);
        } else if (MODE == 1) {
          int pos = mm >> 2, b = mm & 3;
          int nn2 = nn & 511;
          int n = nn2 >> 6, d = nn2 & 63;
          size_t idx = (((size_t)(b * NH + n)) * KLEN + pos) * DH + d;
          if (nn < DM) O0[idx] = to_bf16(v);
          else         O1[idx] = to_bf16(v);
        } else {
          int n = nn >> 6, d = nn & 63;
          int cb = d >> 3;
          int dcol = ((cb ^ (mm & 7)) << 3) | (d & 7);
          O0[((size_t)n * RK_ROWS + mm) * DH + dcol] = to_bf16(v);
        }
      }
    }
  }
}

// ---------------------------------------------------------------------------
// Pack K and V into exact MFMA-fragment order for DMA staging.
// k2[bn][jb][i=h*2+c][lane]*8u = kh[bn][jb*32+h*16+(l&15)][c*32+(l>>4)*8 ..+8]
// v2[bn][jb][t][lane][u]       = vrow[bn][jb*32+(l>>4)*8+u][t*16+(l&15)]
// ---------------------------------------------------------------------------
__global__ __launch_bounds__(256) void attn_pack(
    const ushort* __restrict__ kh, const ushort* __restrict__ vrow,
    ushort* __restrict__ k2, ushort* __restrict__ v2) {
  const int jb = blockIdx.x;     // 0..63
  const int bn = blockIdx.y;     // 0..31
  const int tid = threadIdx.x;
  const int i = tid >> 6;        // tile 0..3
  const int l = tid & 63;
  if (blockIdx.z == 0) {
    int h = i >> 1, c = i & 1;
    const ushort* src = kh + ((size_t)bn * KLEN + jb * 32 + h * 16 + (l & 15)) * DH +
                        c * 32 + (l >> 4) * 8;
    ushort* dst = k2 + ((((size_t)bn * 64 + jb) * 4 + i) * 64 + l) * 8;
    *reinterpret_cast<uint4*>(dst) = *reinterpret_cast<const uint4*>(src);
  } else {
    ushort tmp[8];
    const ushort* srcb = vrow + ((size_t)bn * KLEN + jb * 32 + (l >> 4) * 8) * DH +
                         i * 16 + (l & 15);
#pragma unroll
    for (int u = 0; u < 8; ++u) tmp[u] = srcb[(size_t)u * DH];
    ushort* dst = v2 + ((((size_t)bn * 64 + jb) * 4 + i) * 64 + l) * 8;
    *reinterpret_cast<uint4*>(dst) = *reinterpret_cast<uint4*>(tmp);
  }
}

// ---------------------------------------------------------------------------
// Output GEMM: y[4096x512] = avbf @ WoT (f32 out).
// ---------------------------------------------------------------------------
__global__ __launch_bounds__(256) void mfma_out(
    const ushort* __restrict__ A, const ushort* __restrict__ BT,
    float* __restrict__ Y) {
  __shared__ ushort As[128 * 32];
  __shared__ ushort Bs[128 * 32];
  const int tid = threadIdx.x;
  const int m0 = blockIdx.x * 128, n0 = blockIdx.y * 128;
  const int wv = tid >> 6, lane = tid & 63;
  const int wm = wv >> 1, wn = wv & 1;
  const int l16 = lane & 15, quad = lane >> 4;
  const int arow = tid >> 1;
  const int acol = (tid & 1) * 16;
  const ushort* asrc = A + (size_t)(m0 + arow) * DM + acol;
  const ushort* bsrc = BT + (size_t)(n0 + arow) * DM + acol;

  float4_ acc[4][4];
#pragma unroll
  for (int a = 0; a < 4; ++a)
#pragma unroll
    for (int b = 0; b < 4; ++b) acc[a][b] = float4_{0.f, 0.f, 0.f, 0.f};

  for (int k0 = 0; k0 < DM; k0 += 32) {
    *reinterpret_cast<uint4*>(&As[arow * 32 + acol]) = *reinterpret_cast<const uint4*>(asrc + k0);
    *reinterpret_cast<uint4*>(&As[arow * 32 + acol + 8]) = *reinterpret_cast<const uint4*>(asrc + k0 + 8);
    *reinterpret_cast<uint4*>(&Bs[arow * 32 + acol]) = *reinterpret_cast<const uint4*>(bsrc + k0);
    *reinterpret_cast<uint4*>(&Bs[arow * 32 + acol + 8]) = *reinterpret_cast<const uint4*>(bsrc + k0 + 8);
    __syncthreads();
    short8 af[4], bf[4];
#pragma unroll
    for (int f = 0; f < 4; ++f) {
      af[f] = *reinterpret_cast<const short8*>(&As[(wm * 64 + f * 16 + l16) * 32 + quad * 8]);
      bf[f] = *reinterpret_cast<const short8*>(&Bs[(wn * 64 + f * 16 + l16) * 32 + quad * 8]);
    }
#pragma unroll
    for (int fm = 0; fm < 4; ++fm)
#pragma unroll
      for (int fn = 0; fn < 4; ++fn)
        acc[fm][fn] = __builtin_amdgcn_mfma_f32_16x16x32_bf16(af[fm], bf[fn], acc[fm][fn], 0, 0, 0);
    __syncthreads();
  }
#pragma unroll
  for (int fm = 0; fm < 4; ++fm)
#pragma unroll
    for (int fn = 0; fn < 4; ++fn)
#pragma unroll
      for (int reg = 0; reg < 4; ++reg) {
        int mm = m0 + wm * 64 + fm * 16 + quad * 4 + reg;
        int nn = n0 + wn * 64 + fn * 16 + l16;
        Y[(size_t)mm * DM + nn] = acc[fm][fn][reg];
      }
}

// ---------------------------------------------------------------------------
// Residual + LayerNorm: one wave per row.
// ---------------------------------------------------------------------------
__global__ __launch_bounds__(256) void ln_fuse(
    const float* __restrict__ y, const float* __restrict__ wres,
    const float* __restrict__ g, const float* __restrict__ bb,
    float* __restrict__ out) {
  const int row = blockIdx.x * 4 + (threadIdx.x >> 6);
  const int lane = threadIdx.x & 63;
  const float* yr = y + (size_t)row * DM + lane * 4;
  const float* wr = wres + (size_t)row * DM + lane * 4;
  float4 x0 = *(const float4*)yr;
  float4 x1 = *(const float4*)(yr + 256);
  float4 w0 = *(const float4*)wr;
  float4 w1 = *(const float4*)(wr + 256);
  x0.x += w0.x; x0.y += w0.y; x0.z += w0.z; x0.w += w0.w;
  x1.x += w1.x; x1.y += w1.y; x1.z += w1.z; x1.w += w1.w;
  float s = x0.x + x0.y + x0.z + x0.w + x1.x + x1.y + x1.z + x1.w;
  float ss = x0.x * x0.x + x0.y * x0.y + x0.z * x0.z + x0.w * x0.w +
             x1.x * x1.x + x1.y * x1.y + x1.z * x1.z + x1.w * x1.w;
#pragma unroll
  for (int off = 1; off <= 32; off <<= 1) {
    s += __shfl_xor(s, off, 64);
    ss += __shfl_xor(ss, off, 64);
  }
  float mu = s * (1.f / DM);
  float var = ss * (1.f / DM) - mu * mu;
  float rstd = rsqrtf(var + LN_EPS);
  float4 g0 = *(const float4*)(g + lane * 4);
  float4 g1 = *(const float4*)(g + lane * 4 + 256);
  float4 b0 = *(const float4*)(bb + lane * 4);
  float4 b1 = *(const float4*)(bb + lane * 4 + 256);
  float4 o0, o1;
  o0.x = (x0.x - mu) * rstd * g0.x + b0.x;
  o0.y = (x0.y - mu) * rstd * g0.y + b0.y;
  o0.z = (x0.z - mu) * rstd * g0.z + b0.z;
  o0.w = (x0.w - mu) * rstd * g0.w + b0.w;
  o1.x = (x1.x - mu) * rstd * g1.x + b1.x;
  o1.y = (x1.y - mu) * rstd * g1.y + b1.y;
  o1.z = (x1.z - mu) * rstd * g1.z + b1.z;
  o1.w = (x1.w - mu) * rstd * g1.w + b1.w;
  float* orow = out + (size_t)row * DM + lane * 4;
  *reinterpret_cast<float4*>(orow) = o0;
  *reinterpret_cast<float4*>(orow + 256) = o1;
}

// ---------------------------------------------------------------------------
// MFMA flash attention, restructured K-loop:
//  - block = 64 Q rows (4 waves x 16-row tiles), all waves share each 32-key
//    chunk; K/V/R staged in double-buffered LDS via global_load_lds (DMA,
//    no VGPR round trip), prefetched 2 chunks ahead.
//  - per iter: s_waitcnt vmcnt(5) (never 0) + raw s_barrier x2.
//  - K/V staged in exact frag order (CF seq ds_read_b128); R row-addressable
//    with XOR col-block swizzle (CF).
//  - no cross-wave combine: each wave owns complete rows.
// ---------------------------------------------------------------------------
__global__ __launch_bounds__(256) void attn_mfma(
    const ushort* __restrict__ qw, const ushort* __restrict__ qr,
    const ushort* __restrict__ k2, const ushort* __restrict__ v2,
    const ushort* __restrict__ rk2, ushort* __restrict__ avbf) {
  const int i0b = (gridDim.x - 1 - blockIdx.x) * 64;  // longest blocks first
  const int n = blockIdx.y, b = blockIdx.z;
  const int bn = b * NH + n;
  const int tid = threadIdx.x;
  const int wv = tid >> 6, lane = tid & 63;
  const int l16 = lane & 15, quad = lane >> 4;
  const int i0w = i0b + wv * 16;

  __shared__ ushort stage[2][20 * 512];   // K 4x512 | V 4x512 | R 96x64
  __shared__ float Dlds[4][16 * 66];
  __shared__ ushort Plds[4][16 * 32];
  float* __restrict__ Dw = Dlds[wv];
  ushort* __restrict__ Pw = Plds[wv];

  const ushort* __restrict__ k2b = k2 + (size_t)bn * (64 * 4 * 512);
  const ushort* __restrict__ v2b = v2 + (size_t)bn * (64 * 4 * 512);
  const ushort* __restrict__ rk2n = rk2 + (size_t)n * RK_ROWS * DH;

  const int nIter = (i0b + 63 + MLEN) / 32 + 1;  // jmax/32 + 1, <= 64

  // A-layout Q fragments for this wave's 16 rows
  short8 aqw0, aqw1, aqr0, aqr1;
  {
    const ushort* qwp = qw + (((size_t)bn * QLEN) + i0w + l16) * DH + quad * 8;
    const ushort* qrp = qr + (((size_t)bn * QLEN) + i0w + l16) * DH + quad * 8;
    aqw0 = *(const short8*)(qwp);
    aqw1 = *(const short8*)(qwp + 32);
    aqr0 = *(const short8*)(qrp);
    aqr1 = *(const short8*)(qrp + 32);
  }

  // DMA issue: wave wv stages instrs m = wv + 4s (5 of 20). m<4: K tile m,
  // m<8: V tile m-4, else R row-octet m-8. 1 KB per instr, lane-contiguous.
  auto issue_dma = [&](int jb, int buf) {
    const int tbase = jb * 32 - i0b + 960;  // >= 0 (i0b <= 960)
#pragma unroll
    for (int s = 0; s < 5; ++s) {
      const int m = wv + s * 4;
      const ushort* g;
      if (m < 8) {
        const ushort* base = (m < 4) ? k2b : v2b;
        g = base + ((size_t)jb * 4 + (m & 3)) * 512 + lane * 8;
      } else {
        int tr = tbase + (m - 8) * 8 + (lane >> 3);   // < RK_ROWS
        g = rk2n + (size_t)tr * DH + (lane & 7) * 8;
      }
      __builtin_amdgcn_global_load_lds(GLB(g), LDSP(&stage[buf][m * 512]), 16, 0, 0);
    }
  };

  float4_ O[4];
#pragma unroll
  for (int t = 0; t < 4; ++t) O[t] = float4_{0.f, 0.f, 0.f, 0.f};
  float mrow[4] = {-INFINITY, -INFINITY, -INFINITY, -INFINITY};
  float lpart[4] = {0.f, 0.f, 0.f, 0.f};
  const float SL2E = SCALE * 1.44269504088896f;
  const int rbase = 48 - 16 * wv;  // wave's D-band offset in staged R region
  const int sw = (l16 & 7);        // R col-block unswizzle key (t&7 == l16&7)

  issue_dma(0, 0);
  issue_dma(1 < nIter ? 1 : 0, 1);

  for (int k = 0; k < nIter; ++k) {
    __builtin_amdgcn_s_waitcnt(0x0F75);  // vmcnt<=5: chunk k landed; lgkm/exp free
    __builtin_amdgcn_sched_barrier(0);
    __builtin_amdgcn_s_barrier();
    __builtin_amdgcn_sched_barrier(0);
    const ushort* sb = stage[k & 1];
    const int j0 = k * 32;

    // ---- AC: K frags from LDS (sequential, CF) ----
    float4_ ac[2];
#pragma unroll
    for (int h = 0; h < 2; ++h) {
      short8 b0 = *(const short8*)(sb + (h * 2 + 0) * 512 + lane * 8);
      short8 b1 = *(const short8*)(sb + (h * 2 + 1) * 512 + lane * 8);
      float4_ c = {0.f, 0.f, 0.f, 0.f};
      c = __builtin_amdgcn_mfma_f32_16x16x32_bf16(aqw0, b0, c, 0, 0, 0);
      c = __builtin_amdgcn_mfma_f32_16x16x32_bf16(aqw1, b1, c, 0, 0, 0);
      ac[h] = c;
    }
    // ---- D band: R frags from swizzled LDS rows ----
#pragma unroll
    for (int tt = 0; tt < 3; ++tt) {
      int rowLoc = rbase + tt * 16 + l16;
      const ushort* rrow = sb + 4096 + rowLoc * 64;
      short8 b0 = *(const short8*)(rrow + (((0 + quad) ^ sw) << 3));
      short8 b1 = *(const short8*)(rrow + (((4 + quad) ^ sw) << 3));
      float4_ d = {0.f, 0.f, 0.f, 0.f};
      d = __builtin_amdgcn_mfma_f32_16x16x32_bf16(aqr0, b0, d, 0, 0, 0);
      d = __builtin_amdgcn_mfma_f32_16x16x32_bf16(aqr1, b1, d, 0, 0, 0);
#pragma unroll
      for (int rg = 0; rg < 4; ++rg) {
        int row = quad * 4 + rg;
        Dw[row * 66 + tt * 16 + l16 + row] = d[rg];  // diag store, CF read
      }
    }
    // ---- scores + rel-shift gather + mask ----
    float s[2][4];
#pragma unroll
    for (int half = 0; half < 2; ++half) {
#pragma unroll
      for (int rg = 0; rg < 4; ++rg) {
        int row = quad * 4 + rg;
        int jloc = half * 16 + l16;
        float bd = Dw[row * 66 + jloc + 15];  // = D[row][jloc - row + 15]
        float sv = (ac[half][rg] + bd) * SL2E;
        s[half][rg] = (j0 + jloc > i0w + row + MLEN) ? -INFINITY : sv;
      }
    }
    // ---- online softmax (DPP max, deferred l-sum) ----
#pragma unroll
    for (int rg = 0; rg < 4; ++rg) {
      float mx = row_max16(fmaxf(s[0][rg], s[1][rg]));
      float mn = fmaxf(mrow[rg], mx);          // chunk 0 unmasked -> finite
      float alpha = __builtin_amdgcn_exp2f(mrow[rg] - mn);
      float p0 = __builtin_amdgcn_exp2f(s[0][rg] - mn);
      float p1 = __builtin_amdgcn_exp2f(s[1][rg] - mn);
      lpart[rg] = lpart[rg] * alpha + (p0 + p1);
      mrow[rg] = mn;
#pragma unroll
      for (int t = 0; t < 4; ++t) O[t][rg] *= alpha;
      int row = quad * 4 + rg;
      int idx0 = (l16 >> 3) * 128 + row * 8 + (l16 & 7);
      Pw[idx0] = to_bf16(p0);
      Pw[idx0 + 256] = to_bf16(p1);
    }
    // ---- PV: P + V frags (both sequential, CF) ----
    short8 pfrag = *(const short8*)(Pw + lane * 8);
#pragma unroll
    for (int t = 0; t < 4; ++t) {
      short8 vfrag = *(const short8*)(sb + (4 + t) * 512 + lane * 8);
      O[t] = __builtin_amdgcn_mfma_f32_16x16x32_bf16(pfrag, vfrag, O[t], 0, 0, 0);
    }

    __builtin_amdgcn_sched_barrier(0);
    __builtin_amdgcn_s_barrier();     // all waves done reading stage[k&1]
    __builtin_amdgcn_sched_barrier(0);
    int jn = k + 2;
    if (jn > nIter - 1) jn = nIter - 1;
    issue_dma(jn, k & 1);
  }

  // ---- epilogue: per-wave, no combine ----
  float inv[4];
#pragma unroll
  for (int rg = 0; rg < 4; ++rg) inv[rg] = 1.f / row_sum16(lpart[rg]);
#pragma unroll
  for (int t = 0; t < 4; ++t)
#pragma unroll
    for (int rg = 0; rg < 4; ++rg) {
      int row = quad * 4 + rg;
      avbf[((size_t)(i0w + row) * BSZ + b) * DM + n * DH + t * 16 + l16] =
          to_bf16(O[t][rg] * inv[rg]);
    }
}

extern "C" void kernel_launch(void* const* d_in, const int* in_sizes, int n_in,
                              void* d_out, int out_size, void* d_ws, size_t ws_size,
                              hipStream_t stream) {
  const float* w    = (const float*)d_in[0];
  const float* r    = (const float*)d_in[1];
  const float* rwb  = (const float*)d_in[2];
  const float* rrb  = (const float*)d_in[3];
  const float* mems = (const float*)d_in[4];
  const float* Wq   = (const float*)d_in[5];
  const float* Wkv  = (const float*)d_in[6];
  const float* Wr   = (const float*)d_in[7];
  const float* Wo   = (const float*)d_in[8];
  const float* ln_g = (const float*)d_in[9];
  const float* ln_b = (const float*)d_in[10];
  float* out = (float*)d_out;

  char* p = (char*)d_ws;
  auto alloc = [&](size_t bytes) {
    char* q = p;
    p += (bytes + 255) & ~(size_t)255;
    return q;
  };
  ushort* wbf   = (ushort*)alloc((size_t)QLEN * BSZ * DM * 2);    // 4 MB
  ushort* membf = (ushort*)alloc((size_t)MLEN * BSZ * DM * 2);    // 4 MB
  ushort* rbf   = (ushort*)alloc((size_t)KLEN * DM * 2);          // 2 MB
  ushort* WqT   = (ushort*)alloc((size_t)DM * DM * 2);
  ushort* WkvT  = (ushort*)alloc((size_t)2 * DM * DM * 2);
  ushort* WrT   = (ushort*)alloc((size_t)DM * DM * 2);
  ushort* WoT   = (ushort*)alloc((size_t)DM * DM * 2);
  ushort* qw    = (ushort*)alloc((size_t)BSZ * NH * QLEN * DH * 2);  // 4 MB
  ushort* qr    = (ushort*)alloc((size_t)BSZ * NH * QLEN * DH * 2);  // 4 MB
  ushort* kh    = (ushort*)alloc((size_t)BSZ * NH * KLEN * DH * 2);  // 8 MB
  ushort* vrow  = (ushort*)alloc((size_t)BSZ * NH * KLEN * DH * 2);  // 8 MB
  ushort* k2    = (ushort*)alloc((size_t)BSZ * NH * 64 * 4 * 512 * 2);  // 8 MB
  ushort* v2    = (ushort*)alloc((size_t)BSZ * NH * 64 * 4 * 512 * 2);  // 8 MB
  ushort* rk2   = (ushort*)alloc((size_t)NH * RK_ROWS * DH * 2);        // ~2.1 MB
  // aliases (stream-ordered reuse):
  //  y (8 MB f32) over kh: kh consumed by attn_pack before mfma_out writes y.
  //  avbf (4 MB) over wbf: wbf consumed by proj<0>/<1> before attn writes it.
  float*  y    = (float*)kh;
  ushort* avbf = wbf;

  cvt_bf16<<<dim3(QLEN * BSZ * DM / 1024), dim3(256), 0, stream>>>(w, wbf, QLEN * BSZ * DM);
  cvt_bf16<<<dim3(MLEN * BSZ * DM / 1024), dim3(256), 0, stream>>>(mems, membf, MLEN * BSZ * DM);
  cvt_bf16<<<dim3(KLEN * DM / 1024), dim3(256), 0, stream>>>(r, rbf, KLEN * DM);
  wtrans<<<dim3(16, 16), dim3(256), 0, stream>>>(Wq, WqT, DM);
  wtrans<<<dim3(16, 32), dim3(256), 0, stream>>>(Wkv, WkvT, 2 * DM);
  wtrans<<<dim3(16, 16), dim3(256), 0, stream>>>(Wr, WrT, DM);
  wtrans<<<dim3(16, 16), dim3(256), 0, stream>>>(Wo, WoT, DM);

  mfma_proj<0><<<dim3(32, 4), dim3(256), 0, stream>>>(wbf, nullptr, WqT, rwb, rrb, qw, qr);
  mfma_proj<1><<<dim3(64, 8), dim3(256), 0, stream>>>(membf, wbf, WkvT, nullptr, nullptr, kh, vrow);
  mfma_proj<2><<<dim3(16, 4), dim3(256), 0, stream>>>(rbf, nullptr, WrT, nullptr, nullptr, rk2, nullptr);
  attn_pack<<<dim3(64, 32, 2), dim3(256), 0, stream>>>(kh, vrow, k2, v2);

  attn_mfma<<<dim3(QLEN / 64, NH, BSZ), dim3(256), 0, stream>>>(qw, qr, k2, v2, rk2, avbf);

  mfma_out<<<dim3(32, 4), dim3(256), 0, stream>>>(avbf, WoT, y);
  ln_fuse<<<dim3(QLEN * BSZ / 4), dim3(256), 0, stream>>>(y, w, ln_g, ln_b, out);
}

// Round 10
// 262.649 us; speedup vs baseline: 15.6602x; 1.0365x over previous
//
#include <hip/hip_runtime.h>
#include <hip/hip_bf16.h>
#include <math.h>

#define QLEN 1024
#define MLEN 1024
#define KLEN 2048
#define BSZ 4
#define NH 8
#define DH 64
#define DM 512
#define SCALE 0.125f
#define LN_EPS 1e-5f

#define RK_ROWS 2112   // KLEN + 64 pad rows (t>=2048 only feeds masked scores)

typedef __attribute__((ext_vector_type(8))) short short8;   // 8 bf16 (4 VGPRs)
typedef __attribute__((ext_vector_type(4))) float float4_;  // MFMA C/D

#define GLB(p) ((const __attribute__((address_space(1))) void*)(p))
#define LDSP(p) ((__attribute__((address_space(3))) void*)(p))

__device__ inline ushort to_bf16(float x) {
  __hip_bfloat16 h = __float2bfloat16(x);
  return *reinterpret_cast<ushort*>(&h);
}

// 16-lane (row) reductions on the VALU pipe via DPP.
__device__ inline float row_max16(float v) {
  int x = __builtin_bit_cast(int, v);
  v = fmaxf(v, __builtin_bit_cast(float, __builtin_amdgcn_update_dpp(x, x, 0xB1, 0xF, 0xF, false)));
  x = __builtin_bit_cast(int, v);
  v = fmaxf(v, __builtin_bit_cast(float, __builtin_amdgcn_update_dpp(x, x, 0x4E, 0xF, 0xF, false)));
  x = __builtin_bit_cast(int, v);
  v = fmaxf(v, __builtin_bit_cast(float, __builtin_amdgcn_update_dpp(x, x, 0x124, 0xF, 0xF, false)));
  x = __builtin_bit_cast(int, v);
  v = fmaxf(v, __builtin_bit_cast(float, __builtin_amdgcn_update_dpp(x, x, 0x128, 0xF, 0xF, false)));
  return v;
}
__device__ inline float row_sum16(float v) {
  int x = __builtin_bit_cast(int, v);
  v += __builtin_bit_cast(float, __builtin_amdgcn_update_dpp(x, x, 0xB1, 0xF, 0xF, false));
  x = __builtin_bit_cast(int, v);
  v += __builtin_bit_cast(float, __builtin_amdgcn_update_dpp(x, x, 0x4E, 0xF, 0xF, false));
  x = __builtin_bit_cast(int, v);
  v += __builtin_bit_cast(float, __builtin_amdgcn_update_dpp(x, x, 0x124, 0xF, 0xF, false));
  x = __builtin_bit_cast(int, v);
  v += __builtin_bit_cast(float, __builtin_amdgcn_update_dpp(x, x, 0x128, 0xF, 0xF, false));
  return v;
}

// ---------------------------------------------------------------------------
// Fused f32 -> bf16 convert of w (2M), mems (2M), r (1M). 4 elem/thread.
// ---------------------------------------------------------------------------
#define W_ELEMS   (QLEN * BSZ * DM)        // 2097152
#define MEM_ELEMS (MLEN * BSZ * DM)        // 2097152
#define R_ELEMS   (KLEN * DM)              // 1048576
__global__ __launch_bounds__(256) void prep_cvt(
    const float* __restrict__ w, const float* __restrict__ mems,
    const float* __restrict__ r, ushort* __restrict__ wbf,
    ushort* __restrict__ membf, ushort* __restrict__ rbf) {
  size_t i = ((size_t)blockIdx.x * 256 + threadIdx.x) * 4;
  const float* src;
  ushort* dst;
  if (i < W_ELEMS) {
    src = w + i; dst = wbf + i;
  } else if (i < W_ELEMS + MEM_ELEMS) {
    src = mems + (i - W_ELEMS); dst = membf + (i - W_ELEMS);
  } else {
    src = r + (i - W_ELEMS - MEM_ELEMS); dst = rbf + (i - W_ELEMS - MEM_ELEMS);
  }
  float4 v = *reinterpret_cast<const float4*>(src);
  ushort4 o;
  o.x = to_bf16(v.x); o.y = to_bf16(v.y); o.z = to_bf16(v.z); o.w = to_bf16(v.w);
  *reinterpret_cast<ushort4*>(dst) = o;
}

// ---------------------------------------------------------------------------
// Fused weight transpose+convert: z selects {Wq, Wkv, Wr, Wo}.
// ---------------------------------------------------------------------------
__global__ __launch_bounds__(256) void wtrans_all(
    const float* __restrict__ Wq, const float* __restrict__ Wkv,
    const float* __restrict__ Wr, const float* __restrict__ Wo,
    ushort* __restrict__ WqT, ushort* __restrict__ WkvT,
    ushort* __restrict__ WrT, ushort* __restrict__ WoT) {
  __shared__ ushort tile[32][33];
  const int z = blockIdx.z;
  const float* W;
  ushort* WT;
  int N;
  if (z == 0)      { W = Wq;  WT = WqT;  N = DM; }
  else if (z == 1) { W = Wkv; WT = WkvT; N = 2 * DM; }
  else if (z == 2) { W = Wr;  WT = WrT;  N = DM; }
  else             { W = Wo;  WT = WoT;  N = DM; }
  const int k0 = blockIdx.x * 32, n0 = blockIdx.y * 32;
  if (n0 >= N) return;
  const int tid = threadIdx.x;
#pragma unroll
  for (int it = 0; it < 4; ++it) {
    int idx = tid + it * 256;
    int r = idx >> 5, c = idx & 31;
    tile[r][c] = to_bf16(W[(size_t)(k0 + r) * N + n0 + c]);
  }
  __syncthreads();
#pragma unroll
  for (int it = 0; it < 4; ++it) {
    int idx = tid + it * 256;
    int r = idx >> 5, c = idx & 31;
    WT[(size_t)(n0 + r) * DM + k0 + c] = tile[c][r];
  }
}

// ---------------------------------------------------------------------------
// MFMA projection GEMM. C[M,N] = A[M,512] @ W[512,N] with WT[N][512] bf16.
// Block tile 128x128, 4 waves (2x2) x 64x64 wave tile, BK=32, 16x16x32 bf16.
// MODE 0: -> qw/qr [bn][i][d] (+biases)
// MODE 1: -> k2/v2 DIRECTLY in packed MFMA-fragment order (no attn_pack):
//   K: k2[((bn*64+jb)*4 + (jj>>4)*2+(d>>5))*64 + ((d>>3)&3)*16+(jj&15)]*8+(d&7)
//   V: v2[((bn*64+jb)*4 + (d>>4))*64 + (jj>>3)*16+(d&15)]*8+(jj&7)
// MODE 2: -> rk2 XOR-col-block swizzled, RK_ROWS rows.
// ---------------------------------------------------------------------------
template <int MODE>
__global__ __launch_bounds__(256) void mfma_proj(
    const ushort* __restrict__ A0, const ushort* __restrict__ A1,
    const ushort* __restrict__ BT,
    const float* __restrict__ bias0, const float* __restrict__ bias1,
    ushort* __restrict__ O0, ushort* __restrict__ O1) {
  __shared__ ushort As[128 * 32];
  __shared__ ushort Bs[128 * 32];
  const int tid = threadIdx.x;
  const int m0 = blockIdx.x * 128, n0 = blockIdx.y * 128;
  const int wv = tid >> 6, lane = tid & 63;
  const int wm = wv >> 1, wn = wv & 1;
  const int l16 = lane & 15, quad = lane >> 4;

  const int arow = tid >> 1;
  const int acol = (tid & 1) * 16;
  const ushort* asrc;
  {
    int m = m0 + arow;
    if (MODE == 1)
      asrc = (m < QLEN * BSZ) ? A0 + (size_t)m * DM : A1 + (size_t)(m - QLEN * BSZ) * DM;
    else
      asrc = A0 + (size_t)m * DM;
    asrc += acol;
  }
  const ushort* bsrc = BT + (size_t)(n0 + arow) * DM + acol;

  float4_ acc[4][4];
#pragma unroll
  for (int a = 0; a < 4; ++a)
#pragma unroll
    for (int b = 0; b < 4; ++b) acc[a][b] = float4_{0.f, 0.f, 0.f, 0.f};

  for (int k0 = 0; k0 < DM; k0 += 32) {
    *reinterpret_cast<uint4*>(&As[arow * 32 + acol]) =
        *reinterpret_cast<const uint4*>(asrc + k0);
    *reinterpret_cast<uint4*>(&As[arow * 32 + acol + 8]) =
        *reinterpret_cast<const uint4*>(asrc + k0 + 8);
    *reinterpret_cast<uint4*>(&Bs[arow * 32 + acol]) =
        *reinterpret_cast<const uint4*>(bsrc + k0);
    *reinterpret_cast<uint4*>(&Bs[arow * 32 + acol + 8]) =
        *reinterpret_cast<const uint4*>(bsrc + k0 + 8);
    __syncthreads();
    short8 af[4], bf[4];
#pragma unroll
    for (int f = 0; f < 4; ++f) {
      af[f] = *reinterpret_cast<const short8*>(&As[(wm * 64 + f * 16 + l16) * 32 + quad * 8]);
      bf[f] = *reinterpret_cast<const short8*>(&Bs[(wn * 64 + f * 16 + l16) * 32 + quad * 8]);
    }
#pragma unroll
    for (int fm = 0; fm < 4; ++fm)
#pragma unroll
      for (int fn = 0; fn < 4; ++fn)
        acc[fm][fn] = __builtin_amdgcn_mfma_f32_16x16x32_bf16(af[fm], bf[fn], acc[fm][fn], 0, 0, 0);
    __syncthreads();
  }

#pragma unroll
  for (int fm = 0; fm < 4; ++fm) {
#pragma unroll
    for (int fn = 0; fn < 4; ++fn) {
#pragma unroll
      for (int reg = 0; reg < 4; ++reg) {
        int mm = m0 + wm * 64 + fm * 16 + quad * 4 + reg;
        int nn = n0 + wn * 64 + fn * 16 + l16;
        float v = acc[fm][fn][reg];
        if (MODE == 0) {
          int i = mm >> 2, b = mm & 3;
          int n = nn >> 6, d = nn & 63;
          size_t idx = (((size_t)(b * NH + n)) * QLEN + i) * DH + d;
          O0[idx] = to_bf16(v + bias0[nn]);
          O1[idx] = to_bf16(v + bias1[nn]);
        } else if (MODE == 1) {
          int pos = mm >> 2, b = mm & 3;
          int nn2 = nn & 511;
          int n = nn2 >> 6, d = nn2 & 63;
          int bn = b * NH + n;
          int jb = pos >> 5, jj = pos & 31;
          if (nn < DM) {
            int tile = ((jj >> 4) << 1) | (d >> 5);
            int lane2 = (((d >> 3) & 3) << 4) | (jj & 15);
            O0[((((size_t)bn * 64 + jb) * 4 + tile) * 64 + lane2) * 8 + (d & 7)] =
                to_bf16(v);
          } else {
            int tile = d >> 4;
            int lane2 = ((jj >> 3) << 4) | (d & 15);
            O1[((((size_t)bn * 64 + jb) * 4 + tile) * 64 + lane2) * 8 + (jj & 7)] =
                to_bf16(v);
          }
        } else {
          int n = nn >> 6, d = nn & 63;
          int cb = d >> 3;
          int dcol = ((cb ^ (mm & 7)) << 3) | (d & 7);
          O0[((size_t)n * RK_ROWS + mm) * DH + dcol] = to_bf16(v);
        }
      }
    }
  }
}

// ---------------------------------------------------------------------------
// Output GEMM: y[4096x512] = avbf @ WoT (f32 out).
// ---------------------------------------------------------------------------
__global__ __launch_bounds__(256) void mfma_out(
    const ushort* __restrict__ A, const ushort* __restrict__ BT,
    float* __restrict__ Y) {
  __shared__ ushort As[128 * 32];
  __shared__ ushort Bs[128 * 32];
  const int tid = threadIdx.x;
  const int m0 = blockIdx.x * 128, n0 = blockIdx.y * 128;
  const int wv = tid >> 6, lane = tid & 63;
  const int wm = wv >> 1, wn = wv & 1;
  const int l16 = lane & 15, quad = lane >> 4;
  const int arow = tid >> 1;
  const int acol = (tid & 1) * 16;
  const ushort* asrc = A + (size_t)(m0 + arow) * DM + acol;
  const ushort* bsrc = BT + (size_t)(n0 + arow) * DM + acol;

  float4_ acc[4][4];
#pragma unroll
  for (int a = 0; a < 4; ++a)
#pragma unroll
    for (int b = 0; b < 4; ++b) acc[a][b] = float4_{0.f, 0.f, 0.f, 0.f};

  for (int k0 = 0; k0 < DM; k0 += 32) {
    *reinterpret_cast<uint4*>(&As[arow * 32 + acol]) = *reinterpret_cast<const uint4*>(asrc + k0);
    *reinterpret_cast<uint4*>(&As[arow * 32 + acol + 8]) = *reinterpret_cast<const uint4*>(asrc + k0 + 8);
    *reinterpret_cast<uint4*>(&Bs[arow * 32 + acol]) = *reinterpret_cast<const uint4*>(bsrc + k0);
    *reinterpret_cast<uint4*>(&Bs[arow * 32 + acol + 8]) = *reinterpret_cast<const uint4*>(bsrc + k0 + 8);
    __syncthreads();
    short8 af[4], bf[4];
#pragma unroll
    for (int f = 0; f < 4; ++f) {
      af[f] = *reinterpret_cast<const short8*>(&As[(wm * 64 + f * 16 + l16) * 32 + quad * 8]);
      bf[f] = *reinterpret_cast<const short8*>(&Bs[(wn * 64 + f * 16 + l16) * 32 + quad * 8]);
    }
#pragma unroll
    for (int fm = 0; fm < 4; ++fm)
#pragma unroll
      for (int fn = 0; fn < 4; ++fn)
        acc[fm][fn] = __builtin_amdgcn_mfma_f32_16x16x32_bf16(af[fm], bf[fn], acc[fm][fn], 0, 0, 0);
    __syncthreads();
  }
#pragma unroll
  for (int fm = 0; fm < 4; ++fm)
#pragma unroll
    for (int fn = 0; fn < 4; ++fn)
#pragma unroll
      for (int reg = 0; reg < 4; ++reg) {
        int mm = m0 + wm * 64 + fm * 16 + quad * 4 + reg;
        int nn = n0 + wn * 64 + fn * 16 + l16;
        Y[(size_t)mm * DM + nn] = acc[fm][fn][reg];
      }
}

// ---------------------------------------------------------------------------
// Residual + LayerNorm: one wave per row.
// ---------------------------------------------------------------------------
__global__ __launch_bounds__(256) void ln_fuse(
    const float* __restrict__ y, const float* __restrict__ wres,
    const float* __restrict__ g, const float* __restrict__ bb,
    float* __restrict__ out) {
  const int row = blockIdx.x * 4 + (threadIdx.x >> 6);
  const int lane = threadIdx.x & 63;
  const float* yr = y + (size_t)row * DM + lane * 4;
  const float* wr = wres + (size_t)row * DM + lane * 4;
  float4 x0 = *(const float4*)yr;
  float4 x1 = *(const float4*)(yr + 256);
  float4 w0 = *(const float4*)wr;
  float4 w1 = *(const float4*)(wr + 256);
  x0.x += w0.x; x0.y += w0.y; x0.z += w0.z; x0.w += w0.w;
  x1.x += w1.x; x1.y += w1.y; x1.z += w1.z; x1.w += w1.w;
  float s = x0.x + x0.y + x0.z + x0.w + x1.x + x1.y + x1.z + x1.w;
  float ss = x0.x * x0.x + x0.y * x0.y + x0.z * x0.z + x0.w * x0.w +
             x1.x * x1.x + x1.y * x1.y + x1.z * x1.z + x1.w * x1.w;
#pragma unroll
  for (int off = 1; off <= 32; off <<= 1) {
    s += __shfl_xor(s, off, 64);
    ss += __shfl_xor(ss, off, 64);
  }
  float mu = s * (1.f / DM);
  float var = ss * (1.f / DM) - mu * mu;
  float rstd = rsqrtf(var + LN_EPS);
  float4 g0 = *(const float4*)(g + lane * 4);
  float4 g1 = *(const float4*)(g + lane * 4 + 256);
  float4 b0 = *(const float4*)(bb + lane * 4);
  float4 b1 = *(const float4*)(bb + lane * 4 + 256);
  float4 o0, o1;
  o0.x = (x0.x - mu) * rstd * g0.x + b0.x;
  o0.y = (x0.y - mu) * rstd * g0.y + b0.y;
  o0.z = (x0.z - mu) * rstd * g0.z + b0.z;
  o0.w = (x0.w - mu) * rstd * g0.w + b0.w;
  o1.x = (x1.x - mu) * rstd * g1.x + b1.x;
  o1.y = (x1.y - mu) * rstd * g1.y + b1.y;
  o1.z = (x1.z - mu) * rstd * g1.z + b1.z;
  o1.w = (x1.w - mu) * rstd * g1.w + b1.w;
  float* orow = out + (size_t)row * DM + lane * 4;
  *reinterpret_cast<float4*>(orow) = o0;
  *reinterpret_cast<float4*>(orow + 256) = o1;
}

// ---------------------------------------------------------------------------
// MFMA flash attention (unchanged from r9 — it matched prediction):
//  - 64 Q rows/block (4 waves), shared 32-key chunks, double-buffered
//    global_load_lds staging, vmcnt(5), raw barriers, no cross-wave combine.
// ---------------------------------------------------------------------------
__global__ __launch_bounds__(256) void attn_mfma(
    const ushort* __restrict__ qw, const ushort* __restrict__ qr,
    const ushort* __restrict__ k2, const ushort* __restrict__ v2,
    const ushort* __restrict__ rk2, ushort* __restrict__ avbf) {
  const int i0b = (gridDim.x - 1 - blockIdx.x) * 64;  // longest blocks first
  const int n = blockIdx.y, b = blockIdx.z;
  const int bn = b * NH + n;
  const int tid = threadIdx.x;
  const int wv = tid >> 6, lane = tid & 63;
  const int l16 = lane & 15, quad = lane >> 4;
  const int i0w = i0b + wv * 16;

  __shared__ ushort stage[2][20 * 512];   // K 4x512 | V 4x512 | R 96x64
  __shared__ float Dlds[4][16 * 66];
  __shared__ ushort Plds[4][16 * 32];
  float* __restrict__ Dw = Dlds[wv];
  ushort* __restrict__ Pw = Plds[wv];

  const ushort* __restrict__ k2b = k2 + (size_t)bn * (64 * 4 * 512);
  const ushort* __restrict__ v2b = v2 + (size_t)bn * (64 * 4 * 512);
  const ushort* __restrict__ rk2n = rk2 + (size_t)n * RK_ROWS * DH;

  const int nIter = (i0b + 63 + MLEN) / 32 + 1;

  short8 aqw0, aqw1, aqr0, aqr1;
  {
    const ushort* qwp = qw + (((size_t)bn * QLEN) + i0w + l16) * DH + quad * 8;
    const ushort* qrp = qr + (((size_t)bn * QLEN) + i0w + l16) * DH + quad * 8;
    aqw0 = *(const short8*)(qwp);
    aqw1 = *(const short8*)(qwp + 32);
    aqr0 = *(const short8*)(qrp);
    aqr1 = *(const short8*)(qrp + 32);
  }

  auto issue_dma = [&](int jb, int buf) {
    const int tbase = jb * 32 - i0b + 960;
#pragma unroll
    for (int s = 0; s < 5; ++s) {
      const int m = wv + s * 4;
      const ushort* g;
      if (m < 8) {
        const ushort* base = (m < 4) ? k2b : v2b;
        g = base + ((size_t)jb * 4 + (m & 3)) * 512 + lane * 8;
      } else {
        int tr = tbase + (m - 8) * 8 + (lane >> 3);
        g = rk2n + (size_t)tr * DH + (lane & 7) * 8;
      }
      __builtin_amdgcn_global_load_lds(GLB(g), LDSP(&stage[buf][m * 512]), 16, 0, 0);
    }
  };

  float4_ O[4];
#pragma unroll
  for (int t = 0; t < 4; ++t) O[t] = float4_{0.f, 0.f, 0.f, 0.f};
  float mrow[4] = {-INFINITY, -INFINITY, -INFINITY, -INFINITY};
  float lpart[4] = {0.f, 0.f, 0.f, 0.f};
  const float SL2E = SCALE * 1.44269504088896f;
  const int rbase = 48 - 16 * wv;
  const int sw = (l16 & 7);

  issue_dma(0, 0);
  issue_dma(1 < nIter ? 1 : 0, 1);

  for (int k = 0; k < nIter; ++k) {
    __builtin_amdgcn_s_waitcnt(0x0F75);  // vmcnt<=5
    __builtin_amdgcn_sched_barrier(0);
    __builtin_amdgcn_s_barrier();
    __builtin_amdgcn_sched_barrier(0);
    const ushort* sb = stage[k & 1];
    const int j0 = k * 32;

    float4_ ac[2];
#pragma unroll
    for (int h = 0; h < 2; ++h) {
      short8 b0 = *(const short8*)(sb + (h * 2 + 0) * 512 + lane * 8);
      short8 b1 = *(const short8*)(sb + (h * 2 + 1) * 512 + lane * 8);
      float4_ c = {0.f, 0.f, 0.f, 0.f};
      c = __builtin_amdgcn_mfma_f32_16x16x32_bf16(aqw0, b0, c, 0, 0, 0);
      c = __builtin_amdgcn_mfma_f32_16x16x32_bf16(aqw1, b1, c, 0, 0, 0);
      ac[h] = c;
    }
#pragma unroll
    for (int tt = 0; tt < 3; ++tt) {
      int rowLoc = rbase + tt * 16 + l16;
      const ushort* rrow = sb + 4096 + rowLoc * 64;
      short8 b0 = *(const short8*)(rrow + (((0 + quad) ^ sw) << 3));
      short8 b1 = *(const short8*)(rrow + (((4 + quad) ^ sw) << 3));
      float4_ d = {0.f, 0.f, 0.f, 0.f};
      d = __builtin_amdgcn_mfma_f32_16x16x32_bf16(aqr0, b0, d, 0, 0, 0);
      d = __builtin_amdgcn_mfma_f32_16x16x32_bf16(aqr1, b1, d, 0, 0, 0);
#pragma unroll
      for (int rg = 0; rg < 4; ++rg) {
        int row = quad * 4 + rg;
        Dw[row * 66 + tt * 16 + l16 + row] = d[rg];
      }
    }
    float s[2][4];
#pragma unroll
    for (int half = 0; half < 2; ++half) {
#pragma unroll
      for (int rg = 0; rg < 4; ++rg) {
        int row = quad * 4 + rg;
        int jloc = half * 16 + l16;
        float bd = Dw[row * 66 + jloc + 15];
        float sv = (ac[half][rg] + bd) * SL2E;
        s[half][rg] = (j0 + jloc > i0w + row + MLEN) ? -INFINITY : sv;
      }
    }
#pragma unroll
    for (int rg = 0; rg < 4; ++rg) {
      float mx = row_max16(fmaxf(s[0][rg], s[1][rg]));
      float mn = fmaxf(mrow[rg], mx);
      float alpha = __builtin_amdgcn_exp2f(mrow[rg] - mn);
      float p0 = __builtin_amdgcn_exp2f(s[0][rg] - mn);
      float p1 = __builtin_amdgcn_exp2f(s[1][rg] - mn);
      lpart[rg] = lpart[rg] * alpha + (p0 + p1);
      mrow[rg] = mn;
#pragma unroll
      for (int t = 0; t < 4; ++t) O[t][rg] *= alpha;
      int row = quad * 4 + rg;
      int idx0 = (l16 >> 3) * 128 + row * 8 + (l16 & 7);
      Pw[idx0] = to_bf16(p0);
      Pw[idx0 + 256] = to_bf16(p1);
    }
    short8 pfrag = *(const short8*)(Pw + lane * 8);
#pragma unroll
    for (int t = 0; t < 4; ++t) {
      short8 vfrag = *(const short8*)(sb + (4 + t) * 512 + lane * 8);
      O[t] = __builtin_amdgcn_mfma_f32_16x16x32_bf16(pfrag, vfrag, O[t], 0, 0, 0);
    }

    __builtin_amdgcn_sched_barrier(0);
    __builtin_amdgcn_s_barrier();
    __builtin_amdgcn_sched_barrier(0);
    int jn = k + 2;
    if (jn > nIter - 1) jn = nIter - 1;
    issue_dma(jn, k & 1);
  }

  float inv[4];
#pragma unroll
  for (int rg = 0; rg < 4; ++rg) inv[rg] = 1.f / row_sum16(lpart[rg]);
#pragma unroll
  for (int t = 0; t < 4; ++t)
#pragma unroll
    for (int rg = 0; rg < 4; ++rg) {
      int row = quad * 4 + rg;
      avbf[((size_t)(i0w + row) * BSZ + b) * DM + n * DH + t * 16 + l16] =
          to_bf16(O[t][rg] * inv[rg]);
    }
}

extern "C" void kernel_launch(void* const* d_in, const int* in_sizes, int n_in,
                              void* d_out, int out_size, void* d_ws, size_t ws_size,
                              hipStream_t stream) {
  const float* w    = (const float*)d_in[0];
  const float* r    = (const float*)d_in[1];
  const float* rwb  = (const float*)d_in[2];
  const float* rrb  = (const float*)d_in[3];
  const float* mems = (const float*)d_in[4];
  const float* Wq   = (const float*)d_in[5];
  const float* Wkv  = (const float*)d_in[6];
  const float* Wr   = (const float*)d_in[7];
  const float* Wo   = (const float*)d_in[8];
  const float* ln_g = (const float*)d_in[9];
  const float* ln_b = (const float*)d_in[10];
  float* out = (float*)d_out;

  char* p = (char*)d_ws;
  auto alloc = [&](size_t bytes) {
    char* q = p;
    p += (bytes + 255) & ~(size_t)255;
    return q;
  };
  ushort* wbf   = (ushort*)alloc((size_t)W_ELEMS * 2);              // 4 MB
  ushort* membf = (ushort*)alloc((size_t)MEM_ELEMS * 2);            // 4 MB
  ushort* rbf   = (ushort*)alloc((size_t)R_ELEMS * 2);              // 2 MB
  ushort* WqT   = (ushort*)alloc((size_t)DM * DM * 2);
  ushort* WkvT  = (ushort*)alloc((size_t)2 * DM * DM * 2);
  ushort* WrT   = (ushort*)alloc((size_t)DM * DM * 2);
  ushort* WoT   = (ushort*)alloc((size_t)DM * DM * 2);
  ushort* qw    = (ushort*)alloc((size_t)BSZ * NH * QLEN * DH * 2); // 4 MB
  ushort* qr    = (ushort*)alloc((size_t)BSZ * NH * QLEN * DH * 2); // 4 MB
  ushort* k2    = (ushort*)alloc((size_t)BSZ * NH * 64 * 4 * 512 * 2);  // 8 MB
  ushort* v2    = (ushort*)alloc((size_t)BSZ * NH * 64 * 4 * 512 * 2);  // 8 MB
  ushort* rk2   = (ushort*)alloc((size_t)NH * RK_ROWS * DH * 2);        // ~2.1 MB
  // aliases (stream-ordered reuse):
  //  avbf (4 MB) over wbf: wbf consumed by proj<0>/<1> before attn writes it.
  //  y (8 MB f32) over k2: k2 consumed by attn before mfma_out writes y.
  ushort* avbf = wbf;
  float*  y    = (float*)k2;

  prep_cvt<<<dim3((W_ELEMS + MEM_ELEMS + R_ELEMS) / 1024), dim3(256), 0, stream>>>(
      w, mems, r, wbf, membf, rbf);
  wtrans_all<<<dim3(16, 32, 4), dim3(256), 0, stream>>>(
      Wq, Wkv, Wr, Wo, WqT, WkvT, WrT, WoT);

  mfma_proj<0><<<dim3(32, 4), dim3(256), 0, stream>>>(wbf, nullptr, WqT, rwb, rrb, qw, qr);
  mfma_proj<1><<<dim3(64, 8), dim3(256), 0, stream>>>(membf, wbf, WkvT, nullptr, nullptr, k2, v2);
  mfma_proj<2><<<dim3(16, 4), dim3(256), 0, stream>>>(rbf, nullptr, WrT, nullptr, nullptr, rk2, nullptr);

  attn_mfma<<<dim3(QLEN / 64, NH, BSZ), dim3(256), 0, stream>>>(qw, qr, k2, v2, rk2, avbf);

  mfma_out<<<dim3(32, 4), dim3(256), 0, stream>>>(avbf, WoT, y);
  ln_fuse<<<dim3(QLEN * BSZ / 4), dim3(256), 0, stream>>>(y, w, ln_g, ln_b, out);
}

// Round 11
// 252.437 us; speedup vs baseline: 16.2937x; 1.0405x over previous
//
#include <hip/hip_runtime.h>
#include <hip/hip_bf16.h>
#include <math.h>

#define QLEN 1024
#define MLEN 1024
#define KLEN 2048
#define BSZ 4
#define NH 8
#define DH 64
#define DM 512
#define SCALE 0.125f
#define LN_EPS 1e-5f

#define RK_ROWS 2112   // KLEN + 64 pad rows (pad = harness poison, finite bf16, masked)

typedef __attribute__((ext_vector_type(8))) short short8;   // 8 bf16 (4 VGPRs)
typedef __attribute__((ext_vector_type(4))) float float4_;  // MFMA C/D

#define GLB(p) ((const __attribute__((address_space(1))) void*)(p))
#define LDSP(p) ((__attribute__((address_space(3))) void*)(p))

__device__ inline ushort to_bf16(float x) {
  __hip_bfloat16 h = __float2bfloat16(x);
  return *reinterpret_cast<ushort*>(&h);
}

// 16-lane (row) reductions on the VALU pipe via DPP.
__device__ inline float row_max16(float v) {
  int x = __builtin_bit_cast(int, v);
  v = fmaxf(v, __builtin_bit_cast(float, __builtin_amdgcn_update_dpp(x, x, 0xB1, 0xF, 0xF, false)));
  x = __builtin_bit_cast(int, v);
  v = fmaxf(v, __builtin_bit_cast(float, __builtin_amdgcn_update_dpp(x, x, 0x4E, 0xF, 0xF, false)));
  x = __builtin_bit_cast(int, v);
  v = fmaxf(v, __builtin_bit_cast(float, __builtin_amdgcn_update_dpp(x, x, 0x124, 0xF, 0xF, false)));
  x = __builtin_bit_cast(int, v);
  v = fmaxf(v, __builtin_bit_cast(float, __builtin_amdgcn_update_dpp(x, x, 0x128, 0xF, 0xF, false)));
  return v;
}
__device__ inline float row_sum16(float v) {
  int x = __builtin_bit_cast(int, v);
  v += __builtin_bit_cast(float, __builtin_amdgcn_update_dpp(x, x, 0xB1, 0xF, 0xF, false));
  x = __builtin_bit_cast(int, v);
  v += __builtin_bit_cast(float, __builtin_amdgcn_update_dpp(x, x, 0x4E, 0xF, 0xF, false));
  x = __builtin_bit_cast(int, v);
  v += __builtin_bit_cast(float, __builtin_amdgcn_update_dpp(x, x, 0x124, 0xF, 0xF, false));
  x = __builtin_bit_cast(int, v);
  v += __builtin_bit_cast(float, __builtin_amdgcn_update_dpp(x, x, 0x128, 0xF, 0xF, false));
  return v;
}

// ---------------------------------------------------------------------------
// Fused weight transpose+convert: z selects {Wq, Wkv, Wr, Wo}.
// ---------------------------------------------------------------------------
__global__ __launch_bounds__(256) void wtrans_all(
    const float* __restrict__ Wq, const float* __restrict__ Wkv,
    const float* __restrict__ Wr, const float* __restrict__ Wo,
    ushort* __restrict__ WqT, ushort* __restrict__ WkvT,
    ushort* __restrict__ WrT, ushort* __restrict__ WoT) {
  __shared__ ushort tile[32][33];
  const int z = blockIdx.z;
  const float* W;
  ushort* WT;
  int N;
  if (z == 0)      { W = Wq;  WT = WqT;  N = DM; }
  else if (z == 1) { W = Wkv; WT = WkvT; N = 2 * DM; }
  else if (z == 2) { W = Wr;  WT = WrT;  N = DM; }
  else             { W = Wo;  WT = WoT;  N = DM; }
  const int k0 = blockIdx.x * 32, n0 = blockIdx.y * 32;
  if (n0 >= N) return;
  const int tid = threadIdx.x;
#pragma unroll
  for (int it = 0; it < 4; ++it) {
    int idx = tid + it * 256;
    int r = idx >> 5, c = idx & 31;
    tile[r][c] = to_bf16(W[(size_t)(k0 + r) * N + n0 + c]);
  }
  __syncthreads();
#pragma unroll
  for (int it = 0; it < 4; ++it) {
    int idx = tid + it * 256;
    int r = idx >> 5, c = idx & 31;
    WT[(size_t)(n0 + r) * DM + k0 + c] = tile[c][r];
  }
}

// ---------------------------------------------------------------------------
// Merged MFMA projection GEMM (single dispatch, 704 blocks, 1D decode).
// A staged from f32 with convert-in-staging (prep_cvt deleted).
// MFMA operands SWAPPED: acc = mfma(bf, af, acc) so reg-dim = n (cols) ->
// 4 consecutive output elements per lane -> ushort4 (8B) stores for Q/K/R.
//  mode 0 (128 blk): w @ Wq       -> qw/qr [bn][i][d] (+biases)
//  mode 1 (512 blk): cat @ Wkv    -> k2/v2 packed MFMA-frag order
//  mode 2 ( 64 blk): r @ Wr       -> rk2 XOR-swizzled
// ---------------------------------------------------------------------------
__global__ __launch_bounds__(256) void proj_all(
    const float* __restrict__ w, const float* __restrict__ mems,
    const float* __restrict__ r,
    const ushort* __restrict__ WqT, const ushort* __restrict__ WkvT,
    const ushort* __restrict__ WrT,
    const float* __restrict__ bias0, const float* __restrict__ bias1,
    ushort* __restrict__ qw, ushort* __restrict__ qr,
    ushort* __restrict__ k2, ushort* __restrict__ v2,
    ushort* __restrict__ rk2) {
  __shared__ ushort As[128 * 32];
  __shared__ ushort Bs[128 * 32];
  const int tid = threadIdx.x;
  int mode, bx, by;
  {
    int id = blockIdx.x;
    if (id < 128)      { mode = 0; bx = id >> 2;         by = id & 3; }
    else if (id < 640) { mode = 1; bx = (id - 128) >> 3; by = (id - 128) & 7; }
    else               { mode = 2; bx = (id - 640) >> 2; by = (id - 640) & 3; }
  }
  const int m0 = bx * 128, n0 = by * 128;
  const int wv = tid >> 6, lane = tid & 63;
  const int wm = wv >> 1, wn = wv & 1;
  const int l16 = lane & 15, quad = lane >> 4;

  const int arow = tid >> 1;
  const int acol = (tid & 1) * 16;
  const float* asrc;
  {
    int m = m0 + arow;
    if (mode == 2) asrc = r + (size_t)m * DM;
    else asrc = (m < QLEN * BSZ) ? w + (size_t)m * DM
                                 : mems + (size_t)(m - QLEN * BSZ) * DM;
    asrc += acol;
  }
  const ushort* BT = (mode == 0) ? WqT : (mode == 1) ? WkvT : WrT;
  const ushort* bsrc = BT + (size_t)(n0 + arow) * DM + acol;

  float4_ acc[4][4];
#pragma unroll
  for (int a = 0; a < 4; ++a)
#pragma unroll
    for (int b = 0; b < 4; ++b) acc[a][b] = float4_{0.f, 0.f, 0.f, 0.f};

  for (int k0 = 0; k0 < DM; k0 += 32) {
    // A: 16 f32 -> 16 bf16 convert-in-staging
    float4 a0 = *reinterpret_cast<const float4*>(asrc + k0);
    float4 a1 = *reinterpret_cast<const float4*>(asrc + k0 + 4);
    float4 a2 = *reinterpret_cast<const float4*>(asrc + k0 + 8);
    float4 a3 = *reinterpret_cast<const float4*>(asrc + k0 + 12);
    ushort4 u0, u1, u2, u3;
    u0.x = to_bf16(a0.x); u0.y = to_bf16(a0.y); u0.z = to_bf16(a0.z); u0.w = to_bf16(a0.w);
    u1.x = to_bf16(a1.x); u1.y = to_bf16(a1.y); u1.z = to_bf16(a1.z); u1.w = to_bf16(a1.w);
    u2.x = to_bf16(a2.x); u2.y = to_bf16(a2.y); u2.z = to_bf16(a2.z); u2.w = to_bf16(a2.w);
    u3.x = to_bf16(a3.x); u3.y = to_bf16(a3.y); u3.z = to_bf16(a3.z); u3.w = to_bf16(a3.w);
    *reinterpret_cast<ushort4*>(&As[arow * 32 + acol]) = u0;
    *reinterpret_cast<ushort4*>(&As[arow * 32 + acol + 4]) = u1;
    *reinterpret_cast<ushort4*>(&As[arow * 32 + acol + 8]) = u2;
    *reinterpret_cast<ushort4*>(&As[arow * 32 + acol + 12]) = u3;
    *reinterpret_cast<uint4*>(&Bs[arow * 32 + acol]) =
        *reinterpret_cast<const uint4*>(bsrc + k0);
    *reinterpret_cast<uint4*>(&Bs[arow * 32 + acol + 8]) =
        *reinterpret_cast<const uint4*>(bsrc + k0 + 8);
    __syncthreads();
    short8 af[4], bf[4];
#pragma unroll
    for (int f = 0; f < 4; ++f) {
      af[f] = *reinterpret_cast<const short8*>(&As[(wm * 64 + f * 16 + l16) * 32 + quad * 8]);
      bf[f] = *reinterpret_cast<const short8*>(&Bs[(wn * 64 + f * 16 + l16) * 32 + quad * 8]);
    }
#pragma unroll
    for (int fm = 0; fm < 4; ++fm)
#pragma unroll
      for (int fn = 0; fn < 4; ++fn)  // SWAPPED: reg-dim = n
        acc[fm][fn] = __builtin_amdgcn_mfma_f32_16x16x32_bf16(bf[fn], af[fm], acc[fm][fn], 0, 0, 0);
    __syncthreads();
  }

  // Epilogues: lane (l16,quad) holds C[mm = mtile+l16][nn = ntile+quad*4 + reg]
#pragma unroll
  for (int fm = 0; fm < 4; ++fm) {
#pragma unroll
    for (int fn = 0; fn < 4; ++fn) {
      const int mm = m0 + wm * 64 + fm * 16 + l16;
      const int nnb = n0 + wn * 64 + fn * 16 + quad * 4;
      const float4_ a = acc[fm][fn];
      if (mode == 0) {
        float4 b0v = *reinterpret_cast<const float4*>(bias0 + nnb);
        float4 b1v = *reinterpret_cast<const float4*>(bias1 + nnb);
        int i = mm >> 2, b = mm & 3;
        int hd = nnb >> 6, d0 = nnb & 63;
        size_t idx = (((size_t)(b * NH + hd)) * QLEN + i) * DH + d0;
        ushort4 o0, o1;
        o0.x = to_bf16(a[0] + b0v.x); o0.y = to_bf16(a[1] + b0v.y);
        o0.z = to_bf16(a[2] + b0v.z); o0.w = to_bf16(a[3] + b0v.w);
        o1.x = to_bf16(a[0] + b1v.x); o1.y = to_bf16(a[1] + b1v.y);
        o1.z = to_bf16(a[2] + b1v.z); o1.w = to_bf16(a[3] + b1v.w);
        *reinterpret_cast<ushort4*>(qw + idx) = o0;
        *reinterpret_cast<ushort4*>(qr + idx) = o1;
      } else if (mode == 1) {
        int pos = mm >> 2, b = mm & 3;
        int jb = pos >> 5, jj = pos & 31;
        if (nnb < DM) {
          int hd = nnb >> 6, d = nnb & 63;
          int bn = b * NH + hd;
          int tile = ((jj >> 4) << 1) | (d >> 5);
          int lane2 = (((d >> 3) & 3) << 4) | (jj & 15);
          ushort4 o;
          o.x = to_bf16(a[0]); o.y = to_bf16(a[1]);
          o.z = to_bf16(a[2]); o.w = to_bf16(a[3]);
          *reinterpret_cast<ushort4*>(
              k2 + ((((size_t)bn * 64 + jb) * 4 + tile) * 64 + lane2) * 8 + (d & 7)) = o;
        } else {
          int nn2 = nnb - DM;
          int hd = nn2 >> 6, d = nn2 & 63;
          int bn = b * NH + hd;
          int tile = d >> 4;
          size_t base = ((((size_t)bn * 64 + jb) * 4 + tile) * 64 +
                         ((jj >> 3) << 4)) * 8 + (jj & 7);
#pragma unroll
          for (int reg = 0; reg < 4; ++reg)
            v2[base + (size_t)((d & 15) + reg) * 8] = to_bf16(a[reg]);
        }
      } else {
        int t = mm;  // < 2048
        int hd = nnb >> 6, d = nnb & 63;
        int cb = d >> 3;
        int dcol = ((cb ^ (t & 7)) << 3) | (d & 7);
        ushort4 o;
        o.x = to_bf16(a[0]); o.y = to_bf16(a[1]);
        o.z = to_bf16(a[2]); o.w = to_bf16(a[3]);
        *reinterpret_cast<ushort4*>(
            rk2 + ((size_t)hd * RK_ROWS + t) * DH + dcol) = o;
      }
    }
  }
}

// ---------------------------------------------------------------------------
// Output GEMM: y[4096x512] = avbf @ WoT (f32 out). Swapped operands ->
// float4 (16B) stores.
// ---------------------------------------------------------------------------
__global__ __launch_bounds__(256) void mfma_out(
    const ushort* __restrict__ A, const ushort* __restrict__ BT,
    float* __restrict__ Y) {
  __shared__ ushort As[128 * 32];
  __shared__ ushort Bs[128 * 32];
  const int tid = threadIdx.x;
  const int m0 = blockIdx.x * 128, n0 = blockIdx.y * 128;
  const int wv = tid >> 6, lane = tid & 63;
  const int wm = wv >> 1, wn = wv & 1;
  const int l16 = lane & 15, quad = lane >> 4;
  const int arow = tid >> 1;
  const int acol = (tid & 1) * 16;
  const ushort* asrc = A + (size_t)(m0 + arow) * DM + acol;
  const ushort* bsrc = BT + (size_t)(n0 + arow) * DM + acol;

  float4_ acc[4][4];
#pragma unroll
  for (int a = 0; a < 4; ++a)
#pragma unroll
    for (int b = 0; b < 4; ++b) acc[a][b] = float4_{0.f, 0.f, 0.f, 0.f};

  for (int k0 = 0; k0 < DM; k0 += 32) {
    *reinterpret_cast<uint4*>(&As[arow * 32 + acol]) = *reinterpret_cast<const uint4*>(asrc + k0);
    *reinterpret_cast<uint4*>(&As[arow * 32 + acol + 8]) = *reinterpret_cast<const uint4*>(asrc + k0 + 8);
    *reinterpret_cast<uint4*>(&Bs[arow * 32 + acol]) = *reinterpret_cast<const uint4*>(bsrc + k0);
    *reinterpret_cast<uint4*>(&Bs[arow * 32 + acol + 8]) = *reinterpret_cast<const uint4*>(bsrc + k0 + 8);
    __syncthreads();
    short8 af[4], bf[4];
#pragma unroll
    for (int f = 0; f < 4; ++f) {
      af[f] = *reinterpret_cast<const short8*>(&As[(wm * 64 + f * 16 + l16) * 32 + quad * 8]);
      bf[f] = *reinterpret_cast<const short8*>(&Bs[(wn * 64 + f * 16 + l16) * 32 + quad * 8]);
    }
#pragma unroll
    for (int fm = 0; fm < 4; ++fm)
#pragma unroll
      for (int fn = 0; fn < 4; ++fn)  // SWAPPED
        acc[fm][fn] = __builtin_amdgcn_mfma_f32_16x16x32_bf16(bf[fn], af[fm], acc[fm][fn], 0, 0, 0);
    __syncthreads();
  }
#pragma unroll
  for (int fm = 0; fm < 4; ++fm)
#pragma unroll
    for (int fn = 0; fn < 4; ++fn) {
      int mm = m0 + wm * 64 + fm * 16 + l16;
      int nnb = n0 + wn * 64 + fn * 16 + quad * 4;
      float4 o;
      o.x = acc[fm][fn][0]; o.y = acc[fm][fn][1];
      o.z = acc[fm][fn][2]; o.w = acc[fm][fn][3];
      *reinterpret_cast<float4*>(Y + (size_t)mm * DM + nnb) = o;
    }
}

// ---------------------------------------------------------------------------
// Residual + LayerNorm: one wave per row.
// ---------------------------------------------------------------------------
__global__ __launch_bounds__(256) void ln_fuse(
    const float* __restrict__ y, const float* __restrict__ wres,
    const float* __restrict__ g, const float* __restrict__ bb,
    float* __restrict__ out) {
  const int row = blockIdx.x * 4 + (threadIdx.x >> 6);
  const int lane = threadIdx.x & 63;
  const float* yr = y + (size_t)row * DM + lane * 4;
  const float* wr = wres + (size_t)row * DM + lane * 4;
  float4 x0 = *(const float4*)yr;
  float4 x1 = *(const float4*)(yr + 256);
  float4 w0 = *(const float4*)wr;
  float4 w1 = *(const float4*)(wr + 256);
  x0.x += w0.x; x0.y += w0.y; x0.z += w0.z; x0.w += w0.w;
  x1.x += w1.x; x1.y += w1.y; x1.z += w1.z; x1.w += w1.w;
  float s = x0.x + x0.y + x0.z + x0.w + x1.x + x1.y + x1.z + x1.w;
  float ss = x0.x * x0.x + x0.y * x0.y + x0.z * x0.z + x0.w * x0.w +
             x1.x * x1.x + x1.y * x1.y + x1.z * x1.z + x1.w * x1.w;
#pragma unroll
  for (int off = 1; off <= 32; off <<= 1) {
    s += __shfl_xor(s, off, 64);
    ss += __shfl_xor(ss, off, 64);
  }
  float mu = s * (1.f / DM);
  float var = ss * (1.f / DM) - mu * mu;
  float rstd = rsqrtf(var + LN_EPS);
  float4 g0 = *(const float4*)(g + lane * 4);
  float4 g1 = *(const float4*)(g + lane * 4 + 256);
  float4 b0 = *(const float4*)(bb + lane * 4);
  float4 b1 = *(const float4*)(bb + lane * 4 + 256);
  float4 o0, o1;
  o0.x = (x0.x - mu) * rstd * g0.x + b0.x;
  o0.y = (x0.y - mu) * rstd * g0.y + b0.y;
  o0.z = (x0.z - mu) * rstd * g0.z + b0.z;
  o0.w = (x0.w - mu) * rstd * g0.w + b0.w;
  o1.x = (x1.x - mu) * rstd * g1.x + b1.x;
  o1.y = (x1.y - mu) * rstd * g1.y + b1.y;
  o1.z = (x1.z - mu) * rstd * g1.z + b1.z;
  o1.w = (x1.w - mu) * rstd * g1.w + b1.w;
  float* orow = out + (size_t)row * DM + lane * 4;
  *reinterpret_cast<float4*>(orow) = o0;
  *reinterpret_cast<float4*>(orow + 256) = o1;
}

// ---------------------------------------------------------------------------
// MFMA flash attention (FROZEN from r9/r10 — matched prediction):
//  64 Q rows/block (4 waves), shared 32-key chunks, double-buffered
//  global_load_lds staging, vmcnt(5), raw barriers, no cross-wave combine.
// ---------------------------------------------------------------------------
__global__ __launch_bounds__(256) void attn_mfma(
    const ushort* __restrict__ qw, const ushort* __restrict__ qr,
    const ushort* __restrict__ k2, const ushort* __restrict__ v2,
    const ushort* __restrict__ rk2, ushort* __restrict__ avbf) {
  const int i0b = (gridDim.x - 1 - blockIdx.x) * 64;  // longest blocks first
  const int n = blockIdx.y, b = blockIdx.z;
  const int bn = b * NH + n;
  const int tid = threadIdx.x;
  const int wv = tid >> 6, lane = tid & 63;
  const int l16 = lane & 15, quad = lane >> 4;
  const int i0w = i0b + wv * 16;

  __shared__ ushort stage[2][20 * 512];   // K 4x512 | V 4x512 | R 96x64
  __shared__ float Dlds[4][16 * 66];
  __shared__ ushort Plds[4][16 * 32];
  float* __restrict__ Dw = Dlds[wv];
  ushort* __restrict__ Pw = Plds[wv];

  const ushort* __restrict__ k2b = k2 + (size_t)bn * (64 * 4 * 512);
  const ushort* __restrict__ v2b = v2 + (size_t)bn * (64 * 4 * 512);
  const ushort* __restrict__ rk2n = rk2 + (size_t)n * RK_ROWS * DH;

  const int nIter = (i0b + 63 + MLEN) / 32 + 1;

  short8 aqw0, aqw1, aqr0, aqr1;
  {
    const ushort* qwp = qw + (((size_t)bn * QLEN) + i0w + l16) * DH + quad * 8;
    const ushort* qrp = qr + (((size_t)bn * QLEN) + i0w + l16) * DH + quad * 8;
    aqw0 = *(const short8*)(qwp);
    aqw1 = *(const short8*)(qwp + 32);
    aqr0 = *(const short8*)(qrp);
    aqr1 = *(const short8*)(qrp + 32);
  }

  auto issue_dma = [&](int jb, int buf) {
    const int tbase = jb * 32 - i0b + 960;
#pragma unroll
    for (int s = 0; s < 5; ++s) {
      const int m = wv + s * 4;
      const ushort* g;
      if (m < 8) {
        const ushort* base = (m < 4) ? k2b : v2b;
        g = base + ((size_t)jb * 4 + (m & 3)) * 512 + lane * 8;
      } else {
        int tr = tbase + (m - 8) * 8 + (lane >> 3);
        g = rk2n + (size_t)tr * DH + (lane & 7) * 8;
      }
      __builtin_amdgcn_global_load_lds(GLB(g), LDSP(&stage[buf][m * 512]), 16, 0, 0);
    }
  };

  float4_ O[4];
#pragma unroll
  for (int t = 0; t < 4; ++t) O[t] = float4_{0.f, 0.f, 0.f, 0.f};
  float mrow[4] = {-INFINITY, -INFINITY, -INFINITY, -INFINITY};
  float lpart[4] = {0.f, 0.f, 0.f, 0.f};
  const float SL2E = SCALE * 1.44269504088896f;
  const int rbase = 48 - 16 * wv;
  const int sw = (l16 & 7);

  issue_dma(0, 0);
  issue_dma(1 < nIter ? 1 : 0, 1);

  for (int k = 0; k < nIter; ++k) {
    __builtin_amdgcn_s_waitcnt(0x0F75);  // vmcnt<=5
    __builtin_amdgcn_sched_barrier(0);
    __builtin_amdgcn_s_barrier();
    __builtin_amdgcn_sched_barrier(0);
    const ushort* sb = stage[k & 1];
    const int j0 = k * 32;

    float4_ ac[2];
#pragma unroll
    for (int h = 0; h < 2; ++h) {
      short8 b0 = *(const short8*)(sb + (h * 2 + 0) * 512 + lane * 8);
      short8 b1 = *(const short8*)(sb + (h * 2 + 1) * 512 + lane * 8);
      float4_ c = {0.f, 0.f, 0.f, 0.f};
      c = __builtin_amdgcn_mfma_f32_16x16x32_bf16(aqw0, b0, c, 0, 0, 0);
      c = __builtin_amdgcn_mfma_f32_16x16x32_bf16(aqw1, b1, c, 0, 0, 0);
      ac[h] = c;
    }
#pragma unroll
    for (int tt = 0; tt < 3; ++tt) {
      int rowLoc = rbase + tt * 16 + l16;
      const ushort* rrow = sb + 4096 + rowLoc * 64;
      short8 b0 = *(const short8*)(rrow + (((0 + quad) ^ sw) << 3));
      short8 b1 = *(const short8*)(rrow + (((4 + quad) ^ sw) << 3));
      float4_ d = {0.f, 0.f, 0.f, 0.f};
      d = __builtin_amdgcn_mfma_f32_16x16x32_bf16(aqr0, b0, d, 0, 0, 0);
      d = __builtin_amdgcn_mfma_f32_16x16x32_bf16(aqr1, b1, d, 0, 0, 0);
#pragma unroll
      for (int rg = 0; rg < 4; ++rg) {
        int row = quad * 4 + rg;
        Dw[row * 66 + tt * 16 + l16 + row] = d[rg];
      }
    }
    float s[2][4];
#pragma unroll
    for (int half = 0; half < 2; ++half) {
#pragma unroll
      for (int rg = 0; rg < 4; ++rg) {
        int row = quad * 4 + rg;
        int jloc = half * 16 + l16;
        float bd = Dw[row * 66 + jloc + 15];
        float sv = (ac[half][rg] + bd) * SL2E;
        s[half][rg] = (j0 + jloc > i0w + row + MLEN) ? -INFINITY : sv;
      }
    }
#pragma unroll
    for (int rg = 0; rg < 4; ++rg) {
      float mx = row_max16(fmaxf(s[0][rg], s[1][rg]));
      float mn = fmaxf(mrow[rg], mx);
      float alpha = __builtin_amdgcn_exp2f(mrow[rg] - mn);
      float p0 = __builtin_amdgcn_exp2f(s[0][rg] - mn);
      float p1 = __builtin_amdgcn_exp2f(s[1][rg] - mn);
      lpart[rg] = lpart[rg] * alpha + (p0 + p1);
      mrow[rg] = mn;
#pragma unroll
      for (int t = 0; t < 4; ++t) O[t][rg] *= alpha;
      int row = quad * 4 + rg;
      int idx0 = (l16 >> 3) * 128 + row * 8 + (l16 & 7);
      Pw[idx0] = to_bf16(p0);
      Pw[idx0 + 256] = to_bf16(p1);
    }
    short8 pfrag = *(const short8*)(Pw + lane * 8);
#pragma unroll
    for (int t = 0; t < 4; ++t) {
      short8 vfrag = *(const short8*)(sb + (4 + t) * 512 + lane * 8);
      O[t] = __builtin_amdgcn_mfma_f32_16x16x32_bf16(pfrag, vfrag, O[t], 0, 0, 0);
    }

    __builtin_amdgcn_sched_barrier(0);
    __builtin_amdgcn_s_barrier();
    __builtin_amdgcn_sched_barrier(0);
    int jn = k + 2;
    if (jn > nIter - 1) jn = nIter - 1;
    issue_dma(jn, k & 1);
  }

  float inv[4];
#pragma unroll
  for (int rg = 0; rg < 4; ++rg) inv[rg] = 1.f / row_sum16(lpart[rg]);
#pragma unroll
  for (int t = 0; t < 4; ++t)
#pragma unroll
    for (int rg = 0; rg < 4; ++rg) {
      int row = quad * 4 + rg;
      avbf[((size_t)(i0w + row) * BSZ + b) * DM + n * DH + t * 16 + l16] =
          to_bf16(O[t][rg] * inv[rg]);
    }
}

extern "C" void kernel_launch(void* const* d_in, const int* in_sizes, int n_in,
                              void* d_out, int out_size, void* d_ws, size_t ws_size,
                              hipStream_t stream) {
  const float* w    = (const float*)d_in[0];
  const float* r    = (const float*)d_in[1];
  const float* rwb  = (const float*)d_in[2];
  const float* rrb  = (const float*)d_in[3];
  const float* mems = (const float*)d_in[4];
  const float* Wq   = (const float*)d_in[5];
  const float* Wkv  = (const float*)d_in[6];
  const float* Wr   = (const float*)d_in[7];
  const float* Wo   = (const float*)d_in[8];
  const float* ln_g = (const float*)d_in[9];
  const float* ln_b = (const float*)d_in[10];
  float* out = (float*)d_out;

  char* p = (char*)d_ws;
  auto alloc = [&](size_t bytes) {
    char* q = p;
    p += (bytes + 255) & ~(size_t)255;
    return q;
  };
  ushort* WqT   = (ushort*)alloc((size_t)DM * DM * 2);
  ushort* WkvT  = (ushort*)alloc((size_t)2 * DM * DM * 2);
  ushort* WrT   = (ushort*)alloc((size_t)DM * DM * 2);
  ushort* WoT   = (ushort*)alloc((size_t)DM * DM * 2);
  ushort* qw    = (ushort*)alloc((size_t)BSZ * NH * QLEN * DH * 2);     // 4 MB
  ushort* qr    = (ushort*)alloc((size_t)BSZ * NH * QLEN * DH * 2);     // 4 MB
  ushort* k2    = (ushort*)alloc((size_t)BSZ * NH * 64 * 4 * 512 * 2);  // 8 MB
  ushort* v2    = (ushort*)alloc((size_t)BSZ * NH * 64 * 4 * 512 * 2);  // 8 MB
  ushort* rk2   = (ushort*)alloc((size_t)NH * RK_ROWS * DH * 2);        // ~2.1 MB
  ushort* avbf  = (ushort*)alloc((size_t)QLEN * BSZ * DM * 2);          // 4 MB
  // y (8 MB f32) aliases k2: k2 fully consumed by attn before mfma_out runs.
  float* y = (float*)k2;

  wtrans_all<<<dim3(16, 32, 4), dim3(256), 0, stream>>>(
      Wq, Wkv, Wr, Wo, WqT, WkvT, WrT, WoT);
  proj_all<<<dim3(704), dim3(256), 0, stream>>>(
      w, mems, r, WqT, WkvT, WrT, rwb, rrb, qw, qr, k2, v2, rk2);
  attn_mfma<<<dim3(QLEN / 64, NH, BSZ), dim3(256), 0, stream>>>(qw, qr, k2, v2, rk2, avbf);
  mfma_out<<<dim3(32, 4), dim3(256), 0, stream>>>(avbf, WoT, y);
  ln_fuse<<<dim3(QLEN * BSZ / 4), dim3(256), 0, stream>>>(y, w, ln_g, ln_b, out);
}